// Round 1
// baseline (760.089 us; speedup 1.0000x reference)
//
#include <hip/hip_runtime.h>
#include <hip/hip_bf16.h>

#define DI __device__ __forceinline__

typedef __attribute__((ext_vector_type(4))) float f32x4;
typedef __attribute__((ext_vector_type(8))) short bf16x8;

static constexpr int CB = 16;        // batch
static constexpr int CC = 384;       // channels
static constexpr int CH = 28, CW = 28;
static constexpr int CD = 48;        // head dim
static constexpr int CN = 785;       // 1 + 28*28
static constexpr int CM = CB * CN;   // 12560 rows
static constexpr int C3 = 3 * CC;    // 1152
static constexpr int CF = 4 * CC;    // 1536
static constexpr int HW = CH * CW;   // 784

DI short f2b(float f) {
  __hip_bfloat16 h = __float2bfloat16(f);
  return *reinterpret_cast<short*>(&h);
}
DI float b2f(short s) {
  union { unsigned u; float f; } x;
  x.u = ((unsigned)(unsigned short)s) << 16;
  return x.f;
}

// ---------------------------------------------------------------------------
// K1: depthwise conv3x3 posenc + residual -> xc (B,N,C) fp32; zero global_attn
// ---------------------------------------------------------------------------
__global__ void k_build_xc(const float* __restrict__ cls, const float* __restrict__ x,
                           const float* __restrict__ cw, const float* __restrict__ cb,
                           float* __restrict__ xc, float* __restrict__ ga, int ga_elems) {
  const int gid = blockIdx.x * blockDim.x + threadIdx.x;
  if (gid < ga_elems) ga[gid] = 0.f;
  if (gid >= CB * CN * CC) return;
  const int c = gid % CC;
  const int n = (gid / CC) % CN;
  const int b = gid / (CC * CN);
  float v;
  if (n == 0) {
    v = cls[b * CC + c];
  } else {
    const int hw = n - 1;
    const int yy = hw / CW, xx = hw % CW;
    const float* xp = x + ((size_t)(b * CC + c)) * HW;
    float acc = cb[c];
#pragma unroll
    for (int ky = 0; ky < 3; ky++) {
      const int iy = yy + ky - 1;
      if (iy < 0 || iy >= CH) continue;
#pragma unroll
      for (int kx = 0; kx < 3; kx++) {
        const int ix = xx + kx - 1;
        if (ix < 0 || ix >= CW) continue;
        acc += cw[(c * 3 + ky) * 3 + kx] * xp[iy * CW + ix];
      }
    }
    v = xp[yy * CW + xx] + acc;
  }
  xc[gid] = v;
}

// ---------------------------------------------------------------------------
// K2: LayerNorm over last dim (384), fp32 in -> fp32 out. 1 wave per row.
// ---------------------------------------------------------------------------
__global__ __launch_bounds__(256) void k_ln(const float* __restrict__ xin,
                                            const float* __restrict__ g,
                                            const float* __restrict__ bta,
                                            float* __restrict__ y, int Mtot) {
  const int row = blockIdx.x * 4 + (threadIdx.x >> 6);
  const int l = threadIdx.x & 63;
  if (row >= Mtot) return;
  const float* xr = xin + (size_t)row * CC;
  float v[6], s = 0.f, ss = 0.f;
#pragma unroll
  for (int i = 0; i < 6; i++) {
    v[i] = xr[l + i * 64];
    s += v[i];
    ss += v[i] * v[i];
  }
#pragma unroll
  for (int m = 1; m < 64; m <<= 1) { s += __shfl_xor(s, m); ss += __shfl_xor(ss, m); }
  const float mu = s * (1.f / CC);
  const float var = ss * (1.f / CC) - mu * mu;
  const float r = rsqrtf(var + 1e-5f);
#pragma unroll
  for (int i = 0; i < 6; i++) {
    const int c = l + i * 64;
    y[(size_t)row * CC + c] = (v[i] - mu) * r * g[c] + bta[c];
  }
}

// ---------------------------------------------------------------------------
// K3: GEMM  C[M,N] = A[M,K] @ W[N,K]^T (+bias)(+gelu)(+resid), MFMA bf16
//     A dtype: float (converted in staging) or short (bf16 pass-through)
// ---------------------------------------------------------------------------
template <typename AT, int OUTBF, int DOGELU, int DORES, int DOBIAS>
__global__ __launch_bounds__(256) void k_gemm(const AT* __restrict__ A,
                                              const float* __restrict__ W,
                                              const float* __restrict__ bias,
                                              const float* __restrict__ resid,
                                              void* __restrict__ out_,
                                              int M, int N, int K) {
  __shared__ short As[64][40];
  __shared__ short Bs[64][40];
  const int bm = blockIdx.x * 64;
  const int bn = blockIdx.y * 64;
  const int t = threadIdx.x;
  const int w = t >> 6, l = t & 63, g = l >> 4, li = l & 15;
  const int wm = (w >> 1) * 32, wn = (w & 1) * 32;

  f32x4 acc[2][2] = {};
  const int srow = t >> 2, scg = (t & 3) * 8;
  int ar = bm + srow; if (ar > M - 1) ar = M - 1;
  const int nkt = K / 32;

  for (int kt = 0; kt < nkt; kt++) {
    const int k0 = kt * 32;
    __syncthreads();
    { // stage A (convert to bf16 if fp32)
      bf16x8 pk;
      if constexpr (sizeof(AT) == 4) {
        const float* src = (const float*)A + (size_t)ar * K + k0 + scg;
        f32x4 p0 = *(const f32x4*)src;
        f32x4 p1 = *(const f32x4*)(src + 4);
#pragma unroll
        for (int i = 0; i < 4; i++) { pk[i] = f2b(p0[i]); pk[4 + i] = f2b(p1[i]); }
      } else {
        pk = *(const bf16x8*)((const short*)A + (size_t)ar * K + k0 + scg);
      }
      *(bf16x8*)&As[srow][scg] = pk;
    }
    { // stage W (N is always a multiple of 64 here)
      const float* src = W + (size_t)(bn + srow) * K + k0 + scg;
      f32x4 p0 = *(const f32x4*)src;
      f32x4 p1 = *(const f32x4*)(src + 4);
      bf16x8 pk;
#pragma unroll
      for (int i = 0; i < 4; i++) { pk[i] = f2b(p0[i]); pk[4 + i] = f2b(p1[i]); }
      *(bf16x8*)&Bs[srow][scg] = pk;
    }
    __syncthreads();
    bf16x8 a0 = *(bf16x8*)&As[wm + li][g * 8];
    bf16x8 a1 = *(bf16x8*)&As[wm + 16 + li][g * 8];
    bf16x8 b0 = *(bf16x8*)&Bs[wn + li][g * 8];
    bf16x8 b1 = *(bf16x8*)&Bs[wn + 16 + li][g * 8];
    acc[0][0] = __builtin_amdgcn_mfma_f32_16x16x32_bf16(a0, b0, acc[0][0], 0, 0, 0);
    acc[0][1] = __builtin_amdgcn_mfma_f32_16x16x32_bf16(a0, b1, acc[0][1], 0, 0, 0);
    acc[1][0] = __builtin_amdgcn_mfma_f32_16x16x32_bf16(a1, b0, acc[1][0], 0, 0, 0);
    acc[1][1] = __builtin_amdgcn_mfma_f32_16x16x32_bf16(a1, b1, acc[1][1], 0, 0, 0);
  }

#pragma unroll
  for (int mi = 0; mi < 2; mi++)
#pragma unroll
    for (int ni = 0; ni < 2; ni++) {
      const int col = bn + wn + ni * 16 + li;
      float bv = 0.f;
      if constexpr (DOBIAS) bv = bias[col];
#pragma unroll
      for (int r = 0; r < 4; r++) {
        const int row = bm + wm + mi * 16 + g * 4 + r;
        if (row < M) {
          float v = acc[mi][ni][r] + bv;
          if constexpr (DOGELU) v = 0.5f * v * (1.f + erff(v * 0.7071067811865475f));
          if constexpr (DORES) v += resid[(size_t)row * N + col];
          if constexpr (OUTBF)
            ((short*)out_)[(size_t)row * N + col] = f2b(v);
          else
            ((float*)out_)[(size_t)row * N + col] = v;
        }
      }
    }
}

// ---------------------------------------------------------------------------
// K4: flash attention.  grid = (qtiles=13, B*H=128), 256 thr (4 waves x 16 q)
// qkv layout: [b][n][which*384 + h*48 + d] bf16
// ---------------------------------------------------------------------------
__global__ __launch_bounds__(256) void k_attn(const short* __restrict__ qkv,
                                              float* __restrict__ o) {
  __shared__ short Vt[48][40];
  __shared__ short Pw[4][16][40];
  const int bh = blockIdx.y, b = bh >> 3, h = bh & 7;
  const int q0 = blockIdx.x * 64;
  const int t = threadIdx.x, w = t >> 6, l = t & 63, g = l >> 4, li = l & 15;
  const size_t bbase = (size_t)b * CN;

  const int qrow = q0 + w * 16 + li;
  const int qr = qrow > CN - 1 ? CN - 1 : qrow;
  const short* qb = qkv + (bbase + qr) * C3 + h * CD;
  bf16x8 qf0 = *(const bf16x8*)(qb + g * 8);
  bf16x8 qf1 = {};
  if (g < 2) qf1 = *(const bf16x8*)(qb + 32 + g * 8);

  float mr[4], ls[4];
  f32x4 oa[3] = {};
#pragma unroll
  for (int r = 0; r < 4; r++) { mr[r] = -1e30f; ls[r] = 0.f; }
  const float scale = 0.14433756729740643f; // 1/sqrt(48)

  const int nkt = (CN + 31) / 32; // 25
  for (int kt = 0; kt < nkt; kt++) {
    const int kv0 = kt * 32;
    __syncthreads();
    { // stage V transposed: Vt[d][kv]
      const int kv2 = (t & 15) * 2, dg = t >> 4;
      const int kr0 = min(kv0 + kv2, CN - 1), kr1 = min(kv0 + kv2 + 1, CN - 1);
      const short* v0 = qkv + (bbase + kr0) * C3 + 2 * CC + h * CD;
      const short* v1 = qkv + (bbase + kr1) * C3 + 2 * CC + h * CD;
#pragma unroll
      for (int i = 0; i < 3; i++) {
        const int d = dg * 3 + i;
        unsigned pk = (unsigned)(unsigned short)v0[d] |
                      ((unsigned)(unsigned short)v1[d] << 16);
        *(unsigned*)&Vt[d][kv2] = pk;
      }
    }
    __syncthreads();

    // S = Q K^T (16x32 per wave)
    f32x4 s[2];
#pragma unroll
    for (int ni = 0; ni < 2; ni++) {
      const int krow = kv0 + ni * 16 + li;
      const int kr = krow > CN - 1 ? CN - 1 : krow;
      const short* kb = qkv + (bbase + kr) * C3 + CC + h * CD;
      bf16x8 kf0 = *(const bf16x8*)(kb + g * 8);
      bf16x8 kf1 = {};
      if (g < 2) kf1 = *(const bf16x8*)(kb + 32 + g * 8);
      f32x4 acc = {};
      acc = __builtin_amdgcn_mfma_f32_16x16x32_bf16(qf0, kf0, acc, 0, 0, 0);
      acc = __builtin_amdgcn_mfma_f32_16x16x32_bf16(qf1, kf1, acc, 0, 0, 0);
      const bool oob = krow >= CN;
#pragma unroll
      for (int r = 0; r < 4; r++) acc[r] = oob ? -1e30f : acc[r] * scale;
      s[ni] = acc;
    }

    // online softmax (rows live in 16-lane groups)
    float mx[4], al[4], ps[4];
#pragma unroll
    for (int r = 0; r < 4; r++) mx[r] = fmaxf(s[0][r], s[1][r]);
#pragma unroll
    for (int msk = 1; msk < 16; msk <<= 1)
#pragma unroll
      for (int r = 0; r < 4; r++) mx[r] = fmaxf(mx[r], __shfl_xor(mx[r], msk));
#pragma unroll
    for (int r = 0; r < 4; r++) {
      const float mn = fmaxf(mr[r], mx[r]);
      al[r] = __expf(mr[r] - mn);
      mr[r] = mn;
    }
#pragma unroll
    for (int ni = 0; ni < 2; ni++)
#pragma unroll
      for (int r = 0; r < 4; r++) s[ni][r] = __expf(s[ni][r] - mr[r]);
#pragma unroll
    for (int r = 0; r < 4; r++) ps[r] = s[0][r] + s[1][r];
#pragma unroll
    for (int msk = 1; msk < 16; msk <<= 1)
#pragma unroll
      for (int r = 0; r < 4; r++) ps[r] += __shfl_xor(ps[r], msk);
#pragma unroll
    for (int r = 0; r < 4; r++) ls[r] = ls[r] * al[r] + ps[r];
#pragma unroll
    for (int ni = 0; ni < 3; ni++)
#pragma unroll
      for (int r = 0; r < 4; r++) oa[ni][r] *= al[r];

    // P -> LDS (bf16), wave-local
#pragma unroll
    for (int ni = 0; ni < 2; ni++)
#pragma unroll
      for (int r = 0; r < 4; r++) Pw[w][g * 4 + r][ni * 16 + li] = f2b(s[ni][r]);
    asm volatile("s_waitcnt lgkmcnt(0)" ::: "memory");
    __builtin_amdgcn_sched_barrier(0);

    // O += P V
    bf16x8 pa = *(bf16x8*)&Pw[w][li][g * 8];
#pragma unroll
    for (int ni = 0; ni < 3; ni++) {
      bf16x8 vb = *(bf16x8*)&Vt[ni * 16 + li][g * 8];
      oa[ni] = __builtin_amdgcn_mfma_f32_16x16x32_bf16(pa, vb, oa[ni], 0, 0, 0);
    }
  }

#pragma unroll
  for (int ni = 0; ni < 3; ni++)
#pragma unroll
    for (int r = 0; r < 4; r++) {
      const int n = q0 + w * 16 + g * 4 + r;
      if (n < CN)
        o[(bbase + n) * CC + h * CD + ni * 16 + li] = oa[ni][r] / ls[r];
    }
}

// ---------------------------------------------------------------------------
// K5: global_attn = mean over heads of softmax(q0 . k)[1:]. grid = B*H blocks.
// ---------------------------------------------------------------------------
__global__ __launch_bounds__(256) void k_gattn(const short* __restrict__ qkv,
                                               float* __restrict__ ga) {
  const int b = blockIdx.x >> 3, h = blockIdx.x & 7;
  __shared__ float red[4];
  const int t = threadIdx.x;
  const size_t bbase = (size_t)b * CN;
  const short* q0 = qkv + bbase * C3 + h * CD;
  float qv[CD];
#pragma unroll
  for (int i = 0; i < CD; i++) qv[i] = b2f(q0[i]);
  float lg[4], ev[4];
  float lmax = -1e30f;
#pragma unroll
  for (int j = 0; j < 4; j++) {
    const int m = t + j * 256;
    if (m < CN) {
      const short* kr = qkv + (bbase + m) * C3 + CC + h * CD;
      float acc = 0.f;
#pragma unroll
      for (int i = 0; i < CD; i++) acc += qv[i] * b2f(kr[i]);
      lg[j] = acc * 0.14433756729740643f;
      lmax = fmaxf(lmax, lg[j]);
    } else lg[j] = -1e30f;
  }
  for (int msk = 1; msk < 64; msk <<= 1) lmax = fmaxf(lmax, __shfl_xor(lmax, msk));
  if ((t & 63) == 0) red[t >> 6] = lmax;
  __syncthreads();
  lmax = fmaxf(fmaxf(red[0], red[1]), fmaxf(red[2], red[3]));
  __syncthreads();
  float es = 0.f;
#pragma unroll
  for (int j = 0; j < 4; j++) {
    ev[j] = (t + j * 256 < CN) ? __expf(lg[j] - lmax) : 0.f;
    es += ev[j];
  }
  for (int msk = 1; msk < 64; msk <<= 1) es += __shfl_xor(es, msk);
  if ((t & 63) == 0) red[t >> 6] = es;
  __syncthreads();
  es = red[0] + red[1] + red[2] + red[3];
  const float inv = 0.125f / es;
#pragma unroll
  for (int j = 0; j < 4; j++) {
    const int m = t + j * 256;
    if (m >= 1 && m < CN) atomicAdd(&ga[b * HW + m - 1], ev[j] * inv);
  }
}

// ---------------------------------------------------------------------------
// K6: output assembly: cls_out then x_out (transpose back to NCHW)
// ---------------------------------------------------------------------------
__global__ void k_out(const float* __restrict__ xc, float* __restrict__ outp) {
  const int gid = blockIdx.x * blockDim.x + threadIdx.x;
  if (gid < CB * CC) { // cls_out
    const int b = gid / CC, c = gid % CC;
    outp[gid] = xc[((size_t)b * CN) * CC + c];
    return;
  }
  const int g2 = gid - CB * CC;
  if (g2 >= CB * CC * HW) return;
  const int hw = g2 % HW;
  const int c = (g2 / HW) % CC;
  const int b = g2 / (HW * CC);
  outp[CB * CC + g2] = xc[((size_t)b * CN + 1 + hw) * CC + c];
}

// ---------------------------------------------------------------------------
extern "C" void kernel_launch(void* const* d_in, const int* in_sizes, int n_in,
                              void* d_out, int out_size, void* d_ws, size_t ws_size,
                              hipStream_t stream) {
  const float* cls    = (const float*)d_in[0];
  const float* x      = (const float*)d_in[1];
  const float* conv_w = (const float*)d_in[2];
  const float* conv_b = (const float*)d_in[3];
  const float* ln1_g  = (const float*)d_in[4];
  const float* ln1_b  = (const float*)d_in[5];
  const float* qkv_w  = (const float*)d_in[6];
  const float* proj_w = (const float*)d_in[7];
  const float* proj_b = (const float*)d_in[8];
  const float* ln2_g  = (const float*)d_in[9];
  const float* ln2_b  = (const float*)d_in[10];
  const float* fc1_w  = (const float*)d_in[11];
  const float* fc1_b  = (const float*)d_in[12];
  const float* fc2_w  = (const float*)d_in[13];
  const float* fc2_b  = (const float*)d_in[14];

  float* outf = (float*)d_out;
  float* ga = outf + (size_t)CB * CC + (size_t)CB * CC * HW; // 4,823,040 offset

  char* ws = (char*)d_ws;
  float* xc   = (float*)ws;                            // 19,292,160 B
  float* y    = (float*)(ws + 19292160);               // 19,292,160 B
  short* qkvb = (short*)(ws + 2 * 19292160ULL);        // 28,938,240 B
  float* o    = (float*)(ws + 2 * 19292160ULL + 28938240ULL); // 19,292,160 B
  short* m1   = (short*)(ws + 2 * 19292160ULL);        // aliases qkvb+o (38.6 MB, safe: used after both dead)

  const int thr = 256;
  const int totalK1 = CB * CN * CC; // 4,823,040

  k_build_xc<<<(totalK1 + thr - 1) / thr, thr, 0, stream>>>(cls, x, conv_w, conv_b, xc, ga, CB * HW);
  k_ln<<<CM / 4, thr, 0, stream>>>(xc, ln1_g, ln1_b, y, CM);
  k_gemm<float, 1, 0, 0, 0><<<dim3((CM + 63) / 64, C3 / 64), thr, 0, stream>>>(
      y, qkv_w, nullptr, nullptr, qkvb, CM, C3, CC);
  k_attn<<<dim3((CN + 63) / 64, CB * 8), thr, 0, stream>>>(qkvb, o);
  k_gattn<<<CB * 8, thr, 0, stream>>>(qkvb, ga);
  k_gemm<float, 0, 0, 1, 1><<<dim3((CM + 63) / 64, CC / 64), thr, 0, stream>>>(
      o, proj_w, proj_b, xc, xc, CM, CC, CC);
  k_ln<<<CM / 4, thr, 0, stream>>>(xc, ln2_g, ln2_b, y, CM);
  k_gemm<float, 1, 1, 0, 1><<<dim3((CM + 63) / 64, CF / 64), thr, 0, stream>>>(
      y, fc1_w, fc1_b, nullptr, m1, CM, CF, CC);
  k_gemm<short, 0, 0, 1, 1><<<dim3((CM + 63) / 64, CC / 64), thr, 0, stream>>>(
      m1, fc2_w, fc2_b, xc, xc, CM, CC, CF);
  k_out<<<(totalK1 + thr - 1) / thr, thr, 0, stream>>>(xc, outf);
}

// Round 2
// 647.981 us; speedup vs baseline: 1.1730x; 1.1730x over previous
//
#include <hip/hip_runtime.h>
#include <hip/hip_bf16.h>

#define DI __device__ __forceinline__

typedef __attribute__((ext_vector_type(4))) float f32x4;
typedef __attribute__((ext_vector_type(8))) short bf16x8;
typedef __attribute__((ext_vector_type(4))) short bf16x4;

static constexpr int CB = 16;        // batch
static constexpr int CC = 384;       // channels
static constexpr int CH = 28, CW = 28;
static constexpr int CD = 48;        // head dim
static constexpr int CN = 785;       // 1 + 28*28
static constexpr int CM = CB * CN;   // 12560 rows
static constexpr int C3 = 3 * CC;    // 1152
static constexpr int CF = 4 * CC;    // 1536
static constexpr int HW = CH * CW;   // 784

DI short f2b(float f) {
  __hip_bfloat16 h = __float2bfloat16(f);
  return *reinterpret_cast<short*>(&h);
}
DI float b2f(short s) {
  union { unsigned u; float f; } x;
  x.u = ((unsigned)(unsigned short)s) << 16;
  return x.f;
}

DI void gload16(const short* g, short* l) {
  __builtin_amdgcn_global_load_lds((const __attribute__((address_space(1))) void*)g,
                                   (__attribute__((address_space(3))) void*)l, 16, 0, 0);
}

// ---------------------------------------------------------------------------
// K0: zero global_attn, write cls row of xc
// ---------------------------------------------------------------------------
__global__ void k_misc(const float* __restrict__ cls, float* __restrict__ xc,
                       float* __restrict__ ga) {
  const int gid = blockIdx.x * 256 + threadIdx.x;
  if (gid < CB * HW) ga[gid] = 0.f;
  if (gid < CB * CC) {
    const int b = gid / CC, c = gid % CC;
    xc[((size_t)b * CN) * CC + c] = cls[gid];
  }
}

// ---------------------------------------------------------------------------
// K0b: convert the four weight matrices fp32 -> bf16 (contiguous in wbuf)
// ---------------------------------------------------------------------------
__global__ void k_wconv(const float* __restrict__ s0, const float* __restrict__ s1,
                        const float* __restrict__ s2, const float* __restrict__ s3,
                        short* __restrict__ dst) {
  const int gid = (blockIdx.x * 256 + threadIdx.x) * 4;
  if (gid >= 1769472) return;
  const float* s; int off;
  if (gid < 442368)       { s = s0; off = gid; }
  else if (gid < 589824)  { s = s1; off = gid - 442368; }
  else if (gid < 1179648) { s = s2; off = gid - 589824; }
  else                    { s = s3; off = gid - 1179648; }
  f32x4 v = *(const f32x4*)(s + off);
  bf16x4 o;
#pragma unroll
  for (int i = 0; i < 4; i++) o[i] = f2b(v[i]);
  *(bf16x4*)(dst + gid) = o;
}

// ---------------------------------------------------------------------------
// K1: depthwise conv3x3 + residual, coalesced along hw, LDS-transposed write
//     to xc (B,N,C).  grid (13 hw-tiles, B), 256 thr.
// ---------------------------------------------------------------------------
__global__ __launch_bounds__(256) void k_conv_t(const float* __restrict__ x,
                                                const float* __restrict__ cw,
                                                const float* __restrict__ cb,
                                                float* __restrict__ xc) {
  __shared__ float T[64][65];
  __shared__ float Wc[64 * 9];
  __shared__ float Cbs[64];
  const int b = blockIdx.y;
  const int hw0 = blockIdx.x * 64;
  const int t = threadIdx.x;
  const int hwi = t & 63, ci0 = t >> 6;   // conv phase: lane = hw (coalesced)
  const int hw = hw0 + hwi;
  const int yy = hw / CW, xx = hw % CW;
  const int ci2 = t & 63, hb2 = t >> 6;   // write phase: lane = c (coalesced)

  for (int cc = 0; cc < CC; cc += 64) {
    for (int i = t; i < 64 * 9; i += 256) Wc[i] = cw[cc * 9 + i];
    if (t < 64) Cbs[t] = cb[cc + t];
    __syncthreads();
    if (hw < HW) {
      for (int j = 0; j < 16; j++) {
        const int cl = ci0 * 16 + j;               // wave-uniform channel
        const float* xp = x + ((size_t)(b * CC + cc + cl)) * HW;
        float acc = Cbs[cl];
        const float center = xp[yy * CW + xx];
#pragma unroll
        for (int ky = 0; ky < 3; ky++) {
          const int iy = yy + ky - 1;
          if (iy < 0 || iy >= CH) continue;
#pragma unroll
          for (int kx = 0; kx < 3; kx++) {
            const int ix = xx + kx - 1;
            if (ix < 0 || ix >= CW) continue;
            acc += Wc[cl * 9 + ky * 3 + kx] * xp[iy * CW + ix];
          }
        }
        T[cl][hwi] = center + acc;
      }
    }
    __syncthreads();
    for (int j = 0; j < 16; j++) {
      const int hwl = hb2 + j * 4;
      if (hw0 + hwl < HW)
        xc[((size_t)b * CN + 1 + hw0 + hwl) * CC + cc + ci2] = T[ci2][hwl];
    }
    __syncthreads();
  }
}

// ---------------------------------------------------------------------------
// K2: LayerNorm over last dim (384), fp32 in -> bf16 out. 1 wave per row.
// ---------------------------------------------------------------------------
__global__ __launch_bounds__(256) void k_ln(const float* __restrict__ xin,
                                            const float* __restrict__ g,
                                            const float* __restrict__ bta,
                                            short* __restrict__ y, int Mtot) {
  const int row = blockIdx.x * 4 + (threadIdx.x >> 6);
  const int l = threadIdx.x & 63;
  if (row >= Mtot) return;
  const float* xr = xin + (size_t)row * CC;
  float v[6], s = 0.f, ss = 0.f;
#pragma unroll
  for (int i = 0; i < 6; i++) {
    v[i] = xr[l + i * 64];
    s += v[i];
    ss += v[i] * v[i];
  }
#pragma unroll
  for (int m = 1; m < 64; m <<= 1) { s += __shfl_xor(s, m); ss += __shfl_xor(ss, m); }
  const float mu = s * (1.f / CC);
  const float var = ss * (1.f / CC) - mu * mu;
  const float r = rsqrtf(var + 1e-5f);
#pragma unroll
  for (int i = 0; i < 6; i++) {
    const int c = l + i * 64;
    y[(size_t)row * CC + c] = f2b((v[i] - mu) * r * g[c] + bta[c]);
  }
}

// ---------------------------------------------------------------------------
// K3: GEMM  C[M,N] = A[M,K] @ W[N,K]^T (+bias)(+gelu)(+resid)
//     m97 structure: 128x128 tile, 4 waves, BK=32, global_load_lds width 16.
//     A and W are bf16; N % 128 == 0, K % 32 == 0; M ragged (row-clamped).
// ---------------------------------------------------------------------------
template <int DOGELU, int DORES, int DOBIAS, int OUTBF>
__global__ __launch_bounds__(256) void k_gemm(const short* __restrict__ A,
                                              const short* __restrict__ W,
                                              const float* __restrict__ bias,
                                              const float* __restrict__ resid,
                                              void* __restrict__ out_,
                                              int M, int N, int K) {
  __shared__ short As[128 * 32];
  __shared__ short Bs[128 * 32];
  const int bm = blockIdx.x * 128, bn = blockIdx.y * 128;
  const int t = threadIdx.x, w = t >> 6, l = t & 63, g = l >> 4, li = l & 15;
  const int wm = (w >> 1) * 64, wn = (w & 1) * 64;

  // staging: wave w covers rows [w*32, w*32+32) of each tile, 2 loads each
  const int srow = l >> 2;          // 0..15 row within 16-row group
  const int scol = (l & 3) * 8;     // element offset within row (16B granules)
  const short* aSrc[2]; const short* bSrc[2];
  short* aDst[2]; short* bDst[2];
#pragma unroll
  for (int j = 0; j < 2; j++) {
    int arow = bm + w * 32 + j * 16 + srow; if (arow > M - 1) arow = M - 1;
    aSrc[j] = A + (size_t)arow * K + scol;
    aDst[j] = &As[(w * 32 + j * 16) * 32];
    const int brow = bn + w * 32 + j * 16 + srow;
    bSrc[j] = W + (size_t)brow * K + scol;
    bDst[j] = &Bs[(w * 32 + j * 16) * 32];
  }

  f32x4 acc[4][4] = {};
  const int nkt = K / 32;
  for (int kt = 0; kt < nkt; kt++) {
#pragma unroll
    for (int j = 0; j < 2; j++) {
      gload16(aSrc[j], aDst[j]);
      gload16(bSrc[j], bDst[j]);
      aSrc[j] += 32; bSrc[j] += 32;
    }
    __syncthreads();                 // drains vmcnt -> LDS valid
    bf16x8 af[4], bf[4];
#pragma unroll
    for (int mi = 0; mi < 4; mi++)
      af[mi] = *(const bf16x8*)&As[(wm + mi * 16 + li) * 32 + g * 8];
#pragma unroll
    for (int ni = 0; ni < 4; ni++)
      bf[ni] = *(const bf16x8*)&Bs[(wn + ni * 16 + li) * 32 + g * 8];
#pragma unroll
    for (int mi = 0; mi < 4; mi++)
#pragma unroll
      for (int ni = 0; ni < 4; ni++)
        acc[mi][ni] = __builtin_amdgcn_mfma_f32_16x16x32_bf16(af[mi], bf[ni], acc[mi][ni], 0, 0, 0);
    __syncthreads();                 // all reads done before next stage
  }

#pragma unroll
  for (int mi = 0; mi < 4; mi++)
#pragma unroll
    for (int ni = 0; ni < 4; ni++) {
      const int col = bn + wn + ni * 16 + li;
      float bv = 0.f;
      if constexpr (DOBIAS) bv = bias[col];
#pragma unroll
      for (int r = 0; r < 4; r++) {
        const int row = bm + wm + mi * 16 + g * 4 + r;
        if (row < M) {
          float v = acc[mi][ni][r] + bv;
          if constexpr (DOGELU) v = 0.5f * v * (1.f + erff(v * 0.7071067811865475f));
          if constexpr (DORES) v += resid[(size_t)row * N + col];
          if constexpr (OUTBF)
            ((short*)out_)[(size_t)row * N + col] = f2b(v);
          else
            ((float*)out_)[(size_t)row * N + col] = v;
        }
      }
    }
}

// ---------------------------------------------------------------------------
// K4: flash attention.  grid = (qtiles=13, B*H=128), 256 thr (4 waves x 16 q)
// qkv layout: [b][n][which*384 + h*48 + d] bf16.  o output bf16.
// ---------------------------------------------------------------------------
__global__ __launch_bounds__(256) void k_attn(const short* __restrict__ qkv,
                                              short* __restrict__ o) {
  __shared__ short Vt[48][40];
  __shared__ short Pw[4][16][40];
  const int bh = blockIdx.y, b = bh >> 3, h = bh & 7;
  const int q0 = blockIdx.x * 64;
  const int t = threadIdx.x, w = t >> 6, l = t & 63, g = l >> 4, li = l & 15;
  const size_t bbase = (size_t)b * CN;

  const int qrow = q0 + w * 16 + li;
  const int qr = qrow > CN - 1 ? CN - 1 : qrow;
  const short* qb = qkv + (bbase + qr) * C3 + h * CD;
  bf16x8 qf0 = *(const bf16x8*)(qb + g * 8);
  bf16x8 qf1 = {};
  if (g < 2) qf1 = *(const bf16x8*)(qb + 32 + g * 8);

  float mr[4], ls[4];
  f32x4 oa[3] = {};
#pragma unroll
  for (int r = 0; r < 4; r++) { mr[r] = -1e30f; ls[r] = 0.f; }
  const float scale = 0.14433756729740643f; // 1/sqrt(48)

  const int nkt = (CN + 31) / 32; // 25
  for (int kt = 0; kt < nkt; kt++) {
    const int kv0 = kt * 32;
    __syncthreads();
    { // stage V transposed: Vt[d][kv]
      const int kv2 = (t & 15) * 2, dg = t >> 4;
      const int kr0 = min(kv0 + kv2, CN - 1), kr1 = min(kv0 + kv2 + 1, CN - 1);
      const short* v0 = qkv + (bbase + kr0) * C3 + 2 * CC + h * CD;
      const short* v1 = qkv + (bbase + kr1) * C3 + 2 * CC + h * CD;
#pragma unroll
      for (int i = 0; i < 3; i++) {
        const int d = dg * 3 + i;
        unsigned pk = (unsigned)(unsigned short)v0[d] |
                      ((unsigned)(unsigned short)v1[d] << 16);
        *(unsigned*)&Vt[d][kv2] = pk;
      }
    }
    __syncthreads();

    // S = Q K^T (16x32 per wave)
    f32x4 s[2];
#pragma unroll
    for (int ni = 0; ni < 2; ni++) {
      const int krow = kv0 + ni * 16 + li;
      const int kr = krow > CN - 1 ? CN - 1 : krow;
      const short* kb = qkv + (bbase + kr) * C3 + CC + h * CD;
      bf16x8 kf0 = *(const bf16x8*)(kb + g * 8);
      bf16x8 kf1 = {};
      if (g < 2) kf1 = *(const bf16x8*)(kb + 32 + g * 8);
      f32x4 acc = {};
      acc = __builtin_amdgcn_mfma_f32_16x16x32_bf16(qf0, kf0, acc, 0, 0, 0);
      acc = __builtin_amdgcn_mfma_f32_16x16x32_bf16(qf1, kf1, acc, 0, 0, 0);
      const bool oob = krow >= CN;
#pragma unroll
      for (int r = 0; r < 4; r++) acc[r] = oob ? -1e30f : acc[r] * scale;
      s[ni] = acc;
    }

    // online softmax (rows live in 16-lane groups)
    float mx[4], al[4], ps[4];
#pragma unroll
    for (int r = 0; r < 4; r++) mx[r] = fmaxf(s[0][r], s[1][r]);
#pragma unroll
    for (int msk = 1; msk < 16; msk <<= 1)
#pragma unroll
      for (int r = 0; r < 4; r++) mx[r] = fmaxf(mx[r], __shfl_xor(mx[r], msk));
#pragma unroll
    for (int r = 0; r < 4; r++) {
      const float mn = fmaxf(mr[r], mx[r]);
      al[r] = __expf(mr[r] - mn);
      mr[r] = mn;
    }
#pragma unroll
    for (int ni = 0; ni < 2; ni++)
#pragma unroll
      for (int r = 0; r < 4; r++) s[ni][r] = __expf(s[ni][r] - mr[r]);
#pragma unroll
    for (int r = 0; r < 4; r++) ps[r] = s[0][r] + s[1][r];
#pragma unroll
    for (int msk = 1; msk < 16; msk <<= 1)
#pragma unroll
      for (int r = 0; r < 4; r++) ps[r] += __shfl_xor(ps[r], msk);
#pragma unroll
    for (int r = 0; r < 4; r++) ls[r] = ls[r] * al[r] + ps[r];
#pragma unroll
    for (int ni = 0; ni < 3; ni++)
#pragma unroll
      for (int r = 0; r < 4; r++) oa[ni][r] *= al[r];

    // P -> LDS (bf16), wave-local
#pragma unroll
    for (int ni = 0; ni < 2; ni++)
#pragma unroll
      for (int r = 0; r < 4; r++) Pw[w][g * 4 + r][ni * 16 + li] = f2b(s[ni][r]);
    asm volatile("s_waitcnt lgkmcnt(0)" ::: "memory");
    __builtin_amdgcn_sched_barrier(0);

    // O += P V
    bf16x8 pa = *(bf16x8*)&Pw[w][li][g * 8];
#pragma unroll
    for (int ni = 0; ni < 3; ni++) {
      bf16x8 vb = *(bf16x8*)&Vt[ni * 16 + li][g * 8];
      oa[ni] = __builtin_amdgcn_mfma_f32_16x16x32_bf16(pa, vb, oa[ni], 0, 0, 0);
    }
  }

#pragma unroll
  for (int ni = 0; ni < 3; ni++)
#pragma unroll
    for (int r = 0; r < 4; r++) {
      const int n = q0 + w * 16 + g * 4 + r;
      if (n < CN)
        o[(bbase + n) * CC + h * CD + ni * 16 + li] = f2b(oa[ni][r] / ls[r]);
    }
}

// ---------------------------------------------------------------------------
// K5: global_attn = mean over heads of softmax(q0 . k)[1:]. grid = B*H blocks.
// ---------------------------------------------------------------------------
__global__ __launch_bounds__(256) void k_gattn(const short* __restrict__ qkv,
                                               float* __restrict__ ga) {
  const int b = blockIdx.x >> 3, h = blockIdx.x & 7;
  __shared__ float red[4];
  const int t = threadIdx.x;
  const size_t bbase = (size_t)b * CN;
  const short* q0 = qkv + bbase * C3 + h * CD;
  float qv[CD];
#pragma unroll
  for (int i = 0; i < CD; i++) qv[i] = b2f(q0[i]);
  float lg[4], ev[4];
  float lmax = -1e30f;
#pragma unroll
  for (int j = 0; j < 4; j++) {
    const int m = t + j * 256;
    if (m < CN) {
      const short* kr = qkv + (bbase + m) * C3 + CC + h * CD;
      float acc = 0.f;
#pragma unroll
      for (int i = 0; i < CD; i++) acc += qv[i] * b2f(kr[i]);
      lg[j] = acc * 0.14433756729740643f;
      lmax = fmaxf(lmax, lg[j]);
    } else lg[j] = -1e30f;
  }
  for (int msk = 1; msk < 64; msk <<= 1) lmax = fmaxf(lmax, __shfl_xor(lmax, msk));
  if ((t & 63) == 0) red[t >> 6] = lmax;
  __syncthreads();
  lmax = fmaxf(fmaxf(red[0], red[1]), fmaxf(red[2], red[3]));
  __syncthreads();
  float es = 0.f;
#pragma unroll
  for (int j = 0; j < 4; j++) {
    ev[j] = (t + j * 256 < CN) ? __expf(lg[j] - lmax) : 0.f;
    es += ev[j];
  }
  for (int msk = 1; msk < 64; msk <<= 1) es += __shfl_xor(es, msk);
  if ((t & 63) == 0) red[t >> 6] = es;
  __syncthreads();
  es = red[0] + red[1] + red[2] + red[3];
  const float inv = 0.125f / es;
#pragma unroll
  for (int j = 0; j < 4; j++) {
    const int m = t + j * 256;
    if (m >= 1 && m < CN) atomicAdd(&ga[b * HW + m - 1], ev[j] * inv);
  }
}

// ---------------------------------------------------------------------------
// K6: output: x_out via LDS-tiled transpose (both sides coalesced) + cls_out
//     grid (79, B): tiles 0..77 = (ct 0..5) x (ht 0..12); tile 78 = cls row
// ---------------------------------------------------------------------------
__global__ __launch_bounds__(256) void k_out(const float* __restrict__ xc,
                                             float* __restrict__ outp) {
  const int b = blockIdx.y, tile = blockIdx.x, t = threadIdx.x;
  if (tile == 78) {
    for (int i = t; i < CC; i += 256)
      outp[b * CC + i] = xc[((size_t)b * CN) * CC + i];
    return;
  }
  __shared__ float T[64][65];
  const int ct = tile / 13, ht = tile % 13;
  const int c0 = ct * 64, hw0 = ht * 64;
  const int ci = t & 63, hb = t >> 6;
  for (int j = 0; j < 16; j++) {
    const int hwl = hb + j * 4;
    if (hw0 + hwl < HW)
      T[ci][hwl] = xc[((size_t)b * CN + 1 + hw0 + hwl) * CC + c0 + ci];
  }
  __syncthreads();
  const int hi = t & 63, cb2 = t >> 6;
  float* xo = outp + CB * CC;
  for (int j = 0; j < 16; j++) {
    const int cl = cb2 + j * 4;
    if (hw0 + hi < HW)
      xo[((size_t)(b * CC + c0 + cl)) * HW + hw0 + hi] = T[cl][hi];
  }
}

// ---------------------------------------------------------------------------
extern "C" void kernel_launch(void* const* d_in, const int* in_sizes, int n_in,
                              void* d_out, int out_size, void* d_ws, size_t ws_size,
                              hipStream_t stream) {
  const float* cls    = (const float*)d_in[0];
  const float* x      = (const float*)d_in[1];
  const float* conv_w = (const float*)d_in[2];
  const float* conv_b = (const float*)d_in[3];
  const float* ln1_g  = (const float*)d_in[4];
  const float* ln1_b  = (const float*)d_in[5];
  const float* qkv_w  = (const float*)d_in[6];
  const float* proj_w = (const float*)d_in[7];
  const float* proj_b = (const float*)d_in[8];
  const float* ln2_g  = (const float*)d_in[9];
  const float* ln2_b  = (const float*)d_in[10];
  const float* fc1_w  = (const float*)d_in[11];
  const float* fc1_b  = (const float*)d_in[12];
  const float* fc2_w  = (const float*)d_in[13];
  const float* fc2_b  = (const float*)d_in[14];

  float* outf = (float*)d_out;
  float* ga = outf + (size_t)CB * CC + (size_t)CB * CC * HW; // offset 4,823,040

  // ws layout (bytes):
  //   xc   fp32  @ 0          19,292,160
  //   y    bf16  @ 19,292,160  9,646,080
  //   qkvb bf16  @ 28,938,240 28,938,240
  //   o    bf16  @ 57,876,480  9,646,080
  //   m1   bf16  @ 28,938,240 38,584,320  (aliases qkvb+o, both dead by then)
  //   wbuf bf16  @ 67,522,560  3,538,944   -> total 71,061,504
  char* ws = (char*)d_ws;
  float* xc   = (float*)ws;
  short* y    = (short*)(ws + 19292160ULL);
  short* qkvb = (short*)(ws + 28938240ULL);
  short* o    = (short*)(ws + 57876480ULL);
  short* m1   = (short*)(ws + 28938240ULL);
  short* wbuf = (short*)(ws + 67522560ULL);
  short* qkv_wb = wbuf;            // 442,368 elems (1152x384)
  short* proj_wb = wbuf + 442368;  // 147,456 (384x384)
  short* fc1_wb  = wbuf + 589824;  // 589,824 (1536x384)
  short* fc2_wb  = wbuf + 1179648; // 589,824 (384x1536)

  const int thr = 256;
  k_misc<<<49, thr, 0, stream>>>(cls, xc, ga);
  k_wconv<<<1728, thr, 0, stream>>>(qkv_w, proj_w, fc1_w, fc2_w, wbuf);
  k_conv_t<<<dim3(13, CB), thr, 0, stream>>>(x, conv_w, conv_b, xc);
  k_ln<<<CM / 4, thr, 0, stream>>>(xc, ln1_g, ln1_b, y, CM);
  k_gemm<0, 0, 0, 1><<<dim3(99, C3 / 128), thr, 0, stream>>>(
      y, qkv_wb, nullptr, nullptr, qkvb, CM, C3, CC);
  k_attn<<<dim3(13, CB * 8), thr, 0, stream>>>(qkvb, o);
  k_gattn<<<CB * 8, thr, 0, stream>>>(qkvb, ga);
  k_gemm<0, 1, 1, 0><<<dim3(99, CC / 128), thr, 0, stream>>>(
      o, proj_wb, proj_b, xc, xc, CM, CC, CC);
  k_ln<<<CM / 4, thr, 0, stream>>>(xc, ln2_g, ln2_b, y, CM);
  k_gemm<1, 0, 1, 1><<<dim3(99, CF / 128), thr, 0, stream>>>(
      y, fc1_wb, fc1_b, nullptr, m1, CM, CF, CC);
  k_gemm<0, 1, 1, 0><<<dim3(99, CC / 128), thr, 0, stream>>>(
      m1, fc2_wb, fc2_b, xc, xc, CM, CC, CF);
  k_out<<<dim3(79, CB), thr, 0, stream>>>(xc, outf);
}

// Round 5
// 565.741 us; speedup vs baseline: 1.3435x; 1.1454x over previous
//
#include <hip/hip_runtime.h>
#include <hip/hip_bf16.h>

#define DI __device__ __forceinline__

typedef __attribute__((ext_vector_type(4))) float f32x4;
typedef __attribute__((ext_vector_type(8))) short bf16x8;
typedef __attribute__((ext_vector_type(4))) short bf16x4;

static constexpr int CB = 16;        // batch
static constexpr int CC = 384;       // channels
static constexpr int CH = 28, CW = 28;
static constexpr int CD = 48;        // head dim
static constexpr int CN = 785;       // 1 + 28*28
static constexpr int CM = CB * CN;   // 12560 rows
static constexpr int C3 = 3 * CC;    // 1152
static constexpr int CF = 4 * CC;    // 1536
static constexpr int HW = CH * CW;   // 784

DI short f2b(float f) {
  __hip_bfloat16 h = __float2bfloat16(f);
  return *reinterpret_cast<short*>(&h);
}
DI float b2f(short s) {
  union { unsigned u; float f; } x;
  x.u = ((unsigned)(unsigned short)s) << 16;
  return x.f;
}

DI void gload16(const short* g, short* l) {
  __builtin_amdgcn_global_load_lds((const __attribute__((address_space(1))) void*)g,
                                   (__attribute__((address_space(3))) void*)l, 16, 0, 0);
}

// ---------------------------------------------------------------------------
// K0: zero global_attn, write cls row of xc
// ---------------------------------------------------------------------------
__global__ void k_misc(const float* __restrict__ cls, float* __restrict__ xc,
                       float* __restrict__ ga) {
  const int gid = blockIdx.x * 256 + threadIdx.x;
  if (gid < CB * HW) ga[gid] = 0.f;
  if (gid < CB * CC) {
    const int b = gid / CC, c = gid % CC;
    xc[((size_t)b * CN) * CC + c] = cls[gid];
  }
}

// ---------------------------------------------------------------------------
// K0b: convert the four weight matrices fp32 -> bf16 (contiguous in wbuf)
// ---------------------------------------------------------------------------
__global__ void k_wconv(const float* __restrict__ s0, const float* __restrict__ s1,
                        const float* __restrict__ s2, const float* __restrict__ s3,
                        short* __restrict__ dst) {
  const int gid = (blockIdx.x * 256 + threadIdx.x) * 4;
  if (gid >= 1769472) return;
  const float* s; int off;
  if (gid < 442368)       { s = s0; off = gid; }
  else if (gid < 589824)  { s = s1; off = gid - 442368; }
  else if (gid < 1179648) { s = s2; off = gid - 589824; }
  else                    { s = s3; off = gid - 1179648; }
  f32x4 v = *(const f32x4*)(s + off);
  bf16x4 o;
#pragma unroll
  for (int i = 0; i < 4; i++) o[i] = f2b(v[i]);
  *(bf16x4*)(dst + gid) = o;
}

// ---------------------------------------------------------------------------
// K1: depthwise conv3x3 + residual, coalesced along hw, LDS-transposed write
// ---------------------------------------------------------------------------
__global__ __launch_bounds__(256) void k_conv_t(const float* __restrict__ x,
                                                const float* __restrict__ cw,
                                                const float* __restrict__ cb,
                                                float* __restrict__ xc) {
  __shared__ float T[64][65];
  __shared__ float Wc[64 * 9];
  __shared__ float Cbs[64];
  const int b = blockIdx.y;
  const int hw0 = blockIdx.x * 64;
  const int t = threadIdx.x;
  const int hwi = t & 63, ci0 = t >> 6;
  const int hw = hw0 + hwi;
  const int yy = hw / CW, xx = hw % CW;
  const int ci2 = t & 63, hb2 = t >> 6;

  for (int cc = 0; cc < CC; cc += 64) {
    for (int i = t; i < 64 * 9; i += 256) Wc[i] = cw[cc * 9 + i];
    if (t < 64) Cbs[t] = cb[cc + t];
    __syncthreads();
    if (hw < HW) {
      for (int j = 0; j < 16; j++) {
        const int cl = ci0 * 16 + j;
        const float* xp = x + ((size_t)(b * CC + cc + cl)) * HW;
        float acc = Cbs[cl];
        const float center = xp[yy * CW + xx];
#pragma unroll
        for (int ky = 0; ky < 3; ky++) {
          const int iy = yy + ky - 1;
          if (iy < 0 || iy >= CH) continue;
#pragma unroll
          for (int kx = 0; kx < 3; kx++) {
            const int ix = xx + kx - 1;
            if (ix < 0 || ix >= CW) continue;
            acc += Wc[cl * 9 + ky * 3 + kx] * xp[iy * CW + ix];
          }
        }
        T[cl][hwi] = center + acc;
      }
    }
    __syncthreads();
    for (int j = 0; j < 16; j++) {
      const int hwl = hb2 + j * 4;
      if (hw0 + hwl < HW)
        xc[((size_t)b * CN + 1 + hw0 + hwl) * CC + cc + ci2] = T[ci2][hwl];
    }
    __syncthreads();
  }
}

// ---------------------------------------------------------------------------
// K2: LayerNorm over last dim (384), fp32 in -> bf16 out. 1 wave per row.
// ---------------------------------------------------------------------------
__global__ __launch_bounds__(256) void k_ln(const float* __restrict__ xin,
                                            const float* __restrict__ g,
                                            const float* __restrict__ bta,
                                            short* __restrict__ y, int Mtot) {
  const int row = blockIdx.x * 4 + (threadIdx.x >> 6);
  const int l = threadIdx.x & 63;
  if (row >= Mtot) return;
  const float* xr = xin + (size_t)row * CC;
  float v[6], s = 0.f, ss = 0.f;
#pragma unroll
  for (int i = 0; i < 6; i++) {
    v[i] = xr[l + i * 64];
    s += v[i];
    ss += v[i] * v[i];
  }
#pragma unroll
  for (int m = 1; m < 64; m <<= 1) { s += __shfl_xor(s, m); ss += __shfl_xor(ss, m); }
  const float mu = s * (1.f / CC);
  const float var = ss * (1.f / CC) - mu * mu;
  const float r = rsqrtf(var + 1e-5f);
#pragma unroll
  for (int i = 0; i < 6; i++) {
    const int c = l + i * 64;
    y[(size_t)row * CC + c] = f2b((v[i] - mu) * r * g[c] + bta[c]);
  }
}

// ---------------------------------------------------------------------------
// K3: GEMM  C[M,N] = A[M,K] @ W[N,K]^T (+bias)(+gelu)(+resid)
//     m97 structure: 128x128 tile, 4 waves, BK=32, global_load_lds width 16.
// ---------------------------------------------------------------------------
template <int DOGELU, int DORES, int DOBIAS, int OUTBF>
__global__ __launch_bounds__(256) void k_gemm(const short* __restrict__ A,
                                              const short* __restrict__ W,
                                              const float* __restrict__ bias,
                                              const float* __restrict__ resid,
                                              void* __restrict__ out_,
                                              int M, int N, int K) {
  __shared__ short As[128 * 32];
  __shared__ short Bs[128 * 32];
  const int bm = blockIdx.x * 128, bn = blockIdx.y * 128;
  const int t = threadIdx.x, w = t >> 6, l = t & 63, g = l >> 4, li = l & 15;
  const int wm = (w >> 1) * 64, wn = (w & 1) * 64;

  const int srow = l >> 2;
  const int scol = (l & 3) * 8;
  const short* aSrc[2]; const short* bSrc[2];
  short* aDst[2]; short* bDst[2];
#pragma unroll
  for (int j = 0; j < 2; j++) {
    int arow = bm + w * 32 + j * 16 + srow; if (arow > M - 1) arow = M - 1;
    aSrc[j] = A + (size_t)arow * K + scol;
    aDst[j] = &As[(w * 32 + j * 16) * 32];
    const int brow = bn + w * 32 + j * 16 + srow;
    bSrc[j] = W + (size_t)brow * K + scol;
    bDst[j] = &Bs[(w * 32 + j * 16) * 32];
  }

  f32x4 acc[4][4] = {};
  const int nkt = K / 32;
  for (int kt = 0; kt < nkt; kt++) {
#pragma unroll
    for (int j = 0; j < 2; j++) {
      gload16(aSrc[j], aDst[j]);
      gload16(bSrc[j], bDst[j]);
      aSrc[j] += 32; bSrc[j] += 32;
    }
    __syncthreads();
    bf16x8 af[4], bf[4];
#pragma unroll
    for (int mi = 0; mi < 4; mi++)
      af[mi] = *(const bf16x8*)&As[(wm + mi * 16 + li) * 32 + g * 8];
#pragma unroll
    for (int ni = 0; ni < 4; ni++)
      bf[ni] = *(const bf16x8*)&Bs[(wn + ni * 16 + li) * 32 + g * 8];
#pragma unroll
    for (int mi = 0; mi < 4; mi++)
#pragma unroll
      for (int ni = 0; ni < 4; ni++)
        acc[mi][ni] = __builtin_amdgcn_mfma_f32_16x16x32_bf16(af[mi], bf[ni], acc[mi][ni], 0, 0, 0);
    __syncthreads();
  }

#pragma unroll
  for (int mi = 0; mi < 4; mi++)
#pragma unroll
    for (int ni = 0; ni < 4; ni++) {
      const int col = bn + wn + ni * 16 + li;
      float bv = 0.f;
      if constexpr (DOBIAS) bv = bias[col];
#pragma unroll
      for (int r = 0; r < 4; r++) {
        const int row = bm + wm + mi * 16 + g * 4 + r;
        if (row < M) {
          float v = acc[mi][ni][r] + bv;
          if constexpr (DOGELU) v = 0.5f * v * (1.f + erff(v * 0.7071067811865475f));
          if constexpr (DORES) v += resid[(size_t)row * N + col];
          if constexpr (OUTBF)
            ((short*)out_)[(size_t)row * N + col] = f2b(v);
          else
            ((float*)out_)[(size_t)row * N + col] = v;
        }
      }
    }
}

// ---------------------------------------------------------------------------
// K4: flash attention, LDS-staged K/V shared by 4 waves, KVBLK=64.
//     flat grid 1664 = 8 xcd-slots x 16 bh-per-slot x 13 q-tiles; the 13
//     q-tiles of one (b,h) share an XCD slot -> K/V stays in that L2.
//     XOR-swizzled LDS (byte ^= (row&7)<<4) -> conflict-free ds_read_b128.
// ---------------------------------------------------------------------------
__global__ __launch_bounds__(256) void k_attn(const short* __restrict__ qkv,
                                              short* __restrict__ o) {
  __shared__ short Ks[64 * 48];       // [kv][d]   row stride 96 B, swizzled
  __shared__ short Vt[48 * 64];       // [d][kv]   row stride 128 B, swizzled
  __shared__ short Pw[4 * 16 * 64];   // per-wave [q][kv], row stride 128 B, swizzled
  const int f = blockIdx.x;
  const int xslot = f & 7, grp = f >> 3;
  const int bh = xslot + 8 * (grp & 15);
  const int qt = grp >> 4;                 // 0..12
  const int b = bh >> 3, h = bh & 7;
  const int q0 = qt * 64;
  const int t = threadIdx.x, w = t >> 6, l = t & 63, g = l >> 4, li = l & 15;
  const size_t bbase = (size_t)b * CN;

  // Q fragments (held in regs for the whole kernel)
  const int qrow = q0 + w * 16 + li;
  const int qr = qrow > CN - 1 ? CN - 1 : qrow;
  const short* qb = qkv + (bbase + qr) * C3 + h * CD;
  bf16x8 qf0 = *(const bf16x8*)(qb + g * 8);
  bf16x8 qf1 = {};
  if (g < 2) qf1 = *(const bf16x8*)(qb + 32 + g * 8);

  float mr[4], ls[4];
  f32x4 oa[3] = {};
#pragma unroll
  for (int r = 0; r < 4; r++) { mr[r] = -1e30f; ls[r] = 0.f; }
  const float scale = 0.14433756729740643f; // 1/sqrt(48)
  short* PwW = &Pw[w * 16 * 64];

  const int nkt = (CN + 63) / 64; // 13
  for (int kt = 0; kt < nkt; kt++) {
    const int kv0 = kt * 64;
    __syncthreads();
    // ---- stage K tile: 64 rows x 6 x 16B granules, coalesced
#pragma unroll
    for (int it = 0; it < 2; it++) {
      const int gi = t + it * 256;
      if (gi < 384) {
        const int row = gi / 6, cg = gi % 6;
        const int kr = min(kv0 + row, CN - 1);
        bf16x8 val = *(const bf16x8*)(qkv + (bbase + kr) * C3 + CC + h * CD + cg * 8);
        const int byte = (row * 96 + cg * 16) ^ ((row & 7) << 4);
        *(bf16x8*)((char*)Ks + byte) = val;
      }
    }
    // ---- stage V tile transposed: 64 rows x 6 x 16B granule reads,
    //      8 swizzled 2B scatter-stores each (full 48 d coverage)
#pragma unroll
    for (int it = 0; it < 2; it++) {
      const int gi = t + it * 256;
      if (gi < 384) {
        const int row = gi / 6, cg = gi % 6;
        const int kr = min(kv0 + row, CN - 1);
        bf16x8 val = *(const bf16x8*)(qkv + (bbase + kr) * C3 + 2 * CC + h * CD + cg * 8);
#pragma unroll
        for (int i = 0; i < 8; i++) {
          const int d = cg * 8 + i;
          const int byte = (d * 128 + row * 2) ^ ((d & 7) << 4);
          *(short*)((char*)Vt + byte) = val[i];
        }
      }
    }
    __syncthreads();

    // ---- S = Q K^T : 16 q x 64 kv per wave
    f32x4 s[4];
    __builtin_amdgcn_s_setprio(1);
#pragma unroll
    for (int ni = 0; ni < 4; ni++) {
      const int krow = ni * 16 + li;
      bf16x8 kf0 = *(const bf16x8*)((char*)Ks + ((krow * 96 + g * 16) ^ ((krow & 7) << 4)));
      bf16x8 kf1 = {};
      if (g < 2)
        kf1 = *(const bf16x8*)((char*)Ks + ((krow * 96 + 64 + g * 16) ^ ((krow & 7) << 4)));
      f32x4 acc = {};
      acc = __builtin_amdgcn_mfma_f32_16x16x32_bf16(qf0, kf0, acc, 0, 0, 0);
      acc = __builtin_amdgcn_mfma_f32_16x16x32_bf16(qf1, kf1, acc, 0, 0, 0);
      const bool oob = kv0 + krow >= CN;
#pragma unroll
      for (int r = 0; r < 4; r++) acc[r] = oob ? -1e30f : acc[r] * scale;
      s[ni] = acc;
    }
    __builtin_amdgcn_s_setprio(0);

    // ---- online softmax (rows live in 16-lane groups)
    float mx[4], al[4], ps[4];
#pragma unroll
    for (int r = 0; r < 4; r++)
      mx[r] = fmaxf(fmaxf(s[0][r], s[1][r]), fmaxf(s[2][r], s[3][r]));
#pragma unroll
    for (int msk = 1; msk < 16; msk <<= 1)
#pragma unroll
      for (int r = 0; r < 4; r++) mx[r] = fmaxf(mx[r], __shfl_xor(mx[r], msk));
#pragma unroll
    for (int r = 0; r < 4; r++) {
      const float mn = fmaxf(mr[r], mx[r]);
      al[r] = __expf(mr[r] - mn);
      mr[r] = mn;
    }
#pragma unroll
    for (int ni = 0; ni < 4; ni++)
#pragma unroll
      for (int r = 0; r < 4; r++) s[ni][r] = __expf(s[ni][r] - mr[r]);
#pragma unroll
    for (int r = 0; r < 4; r++)
      ps[r] = (s[0][r] + s[1][r]) + (s[2][r] + s[3][r]);
#pragma unroll
    for (int msk = 1; msk < 16; msk <<= 1)
#pragma unroll
      for (int r = 0; r < 4; r++) ps[r] += __shfl_xor(ps[r], msk);
#pragma unroll
    for (int r = 0; r < 4; r++) ls[r] = ls[r] * al[r] + ps[r];
#pragma unroll
    for (int ni = 0; ni < 3; ni++)
#pragma unroll
      for (int r = 0; r < 4; r++) oa[ni][r] *= al[r];

    // ---- P -> LDS (bf16), per-wave region, swizzled
#pragma unroll
    for (int ni = 0; ni < 4; ni++)
#pragma unroll
      for (int r = 0; r < 4; r++) {
        const int row = g * 4 + r, col = ni * 16 + li;
        const int byte = (row * 128 + col * 2) ^ ((row & 7) << 4);
        *(short*)((char*)PwW + byte) = f2b(s[ni][r]);
      }
    asm volatile("s_waitcnt lgkmcnt(0)" ::: "memory");
    __builtin_amdgcn_sched_barrier(0);

    // ---- O += P V  (2 k-chunks of 32 kv each)
    bf16x8 pa[2];
#pragma unroll
    for (int ks = 0; ks < 2; ks++)
      pa[ks] = *(const bf16x8*)((char*)PwW + ((li * 128 + (ks * 32 + g * 8) * 2) ^ ((li & 7) << 4)));
    __builtin_amdgcn_s_setprio(1);
#pragma unroll
    for (int ni = 0; ni < 3; ni++) {
      const int vrow = ni * 16 + li;
#pragma unroll
      for (int ks = 0; ks < 2; ks++) {
        bf16x8 vb = *(const bf16x8*)((char*)Vt + ((vrow * 128 + (ks * 32 + g * 8) * 2) ^ ((vrow & 7) << 4)));
        oa[ni] = __builtin_amdgcn_mfma_f32_16x16x32_bf16(pa[ks], vb, oa[ni], 0, 0, 0);
      }
    }
    __builtin_amdgcn_s_setprio(0);
  }

#pragma unroll
  for (int ni = 0; ni < 3; ni++)
#pragma unroll
    for (int r = 0; r < 4; r++) {
      const int n = q0 + w * 16 + g * 4 + r;
      if (n < CN)
        o[(bbase + n) * CC + h * CD + ni * 16 + li] = f2b(oa[ni][r] / ls[r]);
    }
}

// ---------------------------------------------------------------------------
// K5: global_attn = mean over heads of softmax(q0 . k)[1:]. grid = B*H blocks.
// ---------------------------------------------------------------------------
__global__ __launch_bounds__(256) void k_gattn(const short* __restrict__ qkv,
                                               float* __restrict__ ga) {
  const int b = blockIdx.x >> 3, h = blockIdx.x & 7;
  __shared__ float red[4];
  const int t = threadIdx.x;
  const size_t bbase = (size_t)b * CN;
  const short* q0 = qkv + bbase * C3 + h * CD;
  float qv[CD];
#pragma unroll
  for (int i = 0; i < CD; i++) qv[i] = b2f(q0[i]);
  float lg[4], ev[4];
  float lmax = -1e30f;
#pragma unroll
  for (int j = 0; j < 4; j++) {
    const int m = t + j * 256;
    if (m < CN) {
      const short* kr = qkv + (bbase + m) * C3 + CC + h * CD;
      float acc = 0.f;
#pragma unroll
      for (int i = 0; i < CD; i++) acc += qv[i] * b2f(kr[i]);
      lg[j] = acc * 0.14433756729740643f;
      lmax = fmaxf(lmax, lg[j]);
    } else lg[j] = -1e30f;
  }
  for (int msk = 1; msk < 64; msk <<= 1) lmax = fmaxf(lmax, __shfl_xor(lmax, msk));
  if ((t & 63) == 0) red[t >> 6] = lmax;
  __syncthreads();
  lmax = fmaxf(fmaxf(red[0], red[1]), fmaxf(red[2], red[3]));
  __syncthreads();
  float es = 0.f;
#pragma unroll
  for (int j = 0; j < 4; j++) {
    ev[j] = (t + j * 256 < CN) ? __expf(lg[j] - lmax) : 0.f;
    es += ev[j];
  }
  for (int msk = 1; msk < 64; msk <<= 1) es += __shfl_xor(es, msk);
  if ((t & 63) == 0) red[t >> 6] = es;
  __syncthreads();
  es = red[0] + red[1] + red[2] + red[3];
  const float inv = 0.125f / es;
#pragma unroll
  for (int j = 0; j < 4; j++) {
    const int m = t + j * 256;
    if (m >= 1 && m < CN) atomicAdd(&ga[b * HW + m - 1], ev[j] * inv);
  }
}

// ---------------------------------------------------------------------------
// K6: output: x_out via LDS-tiled transpose (both sides coalesced) + cls_out
// ---------------------------------------------------------------------------
__global__ __launch_bounds__(256) void k_out(const float* __restrict__ xc,
                                             float* __restrict__ outp) {
  const int b = blockIdx.y, tile = blockIdx.x, t = threadIdx.x;
  if (tile == 78) {
    for (int i = t; i < CC; i += 256)
      outp[b * CC + i] = xc[((size_t)b * CN) * CC + i];
    return;
  }
  __shared__ float T[64][65];
  const int ct = tile / 13, ht = tile % 13;
  const int c0 = ct * 64, hw0 = ht * 64;
  const int ci = t & 63, hb = t >> 6;
  for (int j = 0; j < 16; j++) {
    const int hwl = hb + j * 4;
    if (hw0 + hwl < HW)
      T[ci][hwl] = xc[((size_t)b * CN + 1 + hw0 + hwl) * CC + c0 + ci];
  }
  __syncthreads();
  const int hi = t & 63, cb2 = t >> 6;
  float* xo = outp + CB * CC;
  for (int j = 0; j < 16; j++) {
    const int cl = cb2 + j * 4;
    if (hw0 + hi < HW)
      xo[((size_t)(b * CC + c0 + cl)) * HW + hw0 + hi] = T[cl][hi];
  }
}

// ---------------------------------------------------------------------------
extern "C" void kernel_launch(void* const* d_in, const int* in_sizes, int n_in,
                              void* d_out, int out_size, void* d_ws, size_t ws_size,
                              hipStream_t stream) {
  const float* cls    = (const float*)d_in[0];
  const float* x      = (const float*)d_in[1];
  const float* conv_w = (const float*)d_in[2];
  const float* conv_b = (const float*)d_in[3];
  const float* ln1_g  = (const float*)d_in[4];
  const float* ln1_b  = (const float*)d_in[5];
  const float* qkv_w  = (const float*)d_in[6];
  const float* proj_w = (const float*)d_in[7];
  const float* proj_b = (const float*)d_in[8];
  const float* ln2_g  = (const float*)d_in[9];
  const float* ln2_b  = (const float*)d_in[10];
  const float* fc1_w  = (const float*)d_in[11];
  const float* fc1_b  = (const float*)d_in[12];
  const float* fc2_w  = (const float*)d_in[13];
  const float* fc2_b  = (const float*)d_in[14];

  float* outf = (float*)d_out;
  float* ga = outf + (size_t)CB * CC + (size_t)CB * CC * HW;

  char* ws = (char*)d_ws;
  float* xc   = (float*)ws;
  short* y    = (short*)(ws + 19292160ULL);
  short* qkvb = (short*)(ws + 28938240ULL);
  short* o    = (short*)(ws + 57876480ULL);
  short* m1   = (short*)(ws + 28938240ULL);
  short* wbuf = (short*)(ws + 67522560ULL);
  short* qkv_wb = wbuf;
  short* proj_wb = wbuf + 442368;
  short* fc1_wb  = wbuf + 589824;
  short* fc2_wb  = wbuf + 1179648;

  const int thr = 256;
  k_misc<<<49, thr, 0, stream>>>(cls, xc, ga);
  k_wconv<<<1728, thr, 0, stream>>>(qkv_w, proj_w, fc1_w, fc2_w, wbuf);
  k_conv_t<<<dim3(13, CB), thr, 0, stream>>>(x, conv_w, conv_b, xc);
  k_ln<<<CM / 4, thr, 0, stream>>>(xc, ln1_g, ln1_b, y, CM);
  k_gemm<0, 0, 0, 1><<<dim3(99, C3 / 128), thr, 0, stream>>>(
      y, qkv_wb, nullptr, nullptr, qkvb, CM, C3, CC);
  k_attn<<<1664, thr, 0, stream>>>(qkvb, o);
  k_gattn<<<CB * 8, thr, 0, stream>>>(qkvb, ga);
  k_gemm<0, 1, 1, 0><<<dim3(99, CC / 128), thr, 0, stream>>>(
      o, proj_wb, proj_b, xc, xc, CM, CC, CC);
  k_ln<<<CM / 4, thr, 0, stream>>>(xc, ln2_g, ln2_b, y, CM);
  k_gemm<1, 0, 1, 1><<<dim3(99, CF / 128), thr, 0, stream>>>(
      y, fc1_wb, fc1_b, nullptr, m1, CM, CF, CC);
  k_gemm<0, 1, 1, 0><<<dim3(99, CC / 128), thr, 0, stream>>>(
      m1, fc2_wb, fc2_b, xc, xc, CM, CC, CF);
  k_out<<<dim3(79, CB), thr, 0, stream>>>(xc, outf);
}

// Round 6
// 470.598 us; speedup vs baseline: 1.6152x; 1.2022x over previous
//
#include <hip/hip_runtime.h>
#include <hip/hip_bf16.h>

#define DI __device__ __forceinline__

typedef __attribute__((ext_vector_type(4))) float f32x4;
typedef __attribute__((ext_vector_type(8))) short bf16x8;
typedef __attribute__((ext_vector_type(4))) short bf16x4;

static constexpr int CB = 16;        // batch
static constexpr int CC = 384;       // channels
static constexpr int CH = 28, CW = 28;
static constexpr int CD = 48;        // head dim
static constexpr int CN = 785;       // 1 + 28*28
static constexpr int CM = CB * CN;   // 12560 rows
static constexpr int C3 = 3 * CC;    // 1152
static constexpr int CF = 4 * CC;    // 1536
static constexpr int HW = CH * CW;   // 784

DI short f2b(float f) {
  __hip_bfloat16 h = __float2bfloat16(f);
  return *reinterpret_cast<short*>(&h);
}
DI float b2f(short s) {
  union { unsigned u; float f; } x;
  x.u = ((unsigned)(unsigned short)s) << 16;
  return x.f;
}

DI void gload16(const short* g, short* l) {
  __builtin_amdgcn_global_load_lds((const __attribute__((address_space(1))) void*)g,
                                   (__attribute__((address_space(3))) void*)l, 16, 0, 0);
}

// ---------------------------------------------------------------------------
// K0: zero global_attn, write cls row of xc
// ---------------------------------------------------------------------------
__global__ void k_misc(const float* __restrict__ cls, float* __restrict__ xc,
                       float* __restrict__ ga) {
  const int gid = blockIdx.x * 256 + threadIdx.x;
  if (gid < CB * HW) ga[gid] = 0.f;
  if (gid < CB * CC) {
    const int b = gid / CC, c = gid % CC;
    xc[((size_t)b * CN) * CC + c] = cls[gid];
  }
}

// ---------------------------------------------------------------------------
// K0b: convert the four weight matrices fp32 -> bf16 (contiguous in wbuf)
// ---------------------------------------------------------------------------
__global__ void k_wconv(const float* __restrict__ s0, const float* __restrict__ s1,
                        const float* __restrict__ s2, const float* __restrict__ s3,
                        short* __restrict__ dst) {
  const int gid = (blockIdx.x * 256 + threadIdx.x) * 4;
  if (gid >= 1769472) return;
  const float* s; int off;
  if (gid < 442368)       { s = s0; off = gid; }
  else if (gid < 589824)  { s = s1; off = gid - 442368; }
  else if (gid < 1179648) { s = s2; off = gid - 589824; }
  else                    { s = s3; off = gid - 1179648; }
  f32x4 v = *(const f32x4*)(s + off);
  bf16x4 o;
#pragma unroll
  for (int i = 0; i < 4; i++) o[i] = f2b(v[i]);
  *(bf16x4*)(dst + gid) = o;
}

// ---------------------------------------------------------------------------
// K1: depthwise conv3x3 + residual, coalesced along hw, LDS-transposed write.
//     grid (13 hw-tiles, 6 c-chunks, B) = 1248 blocks (occupancy fix: the
//     per-block serial cc-loop was 8% occupancy / 156us at grid 208).
// ---------------------------------------------------------------------------
__global__ __launch_bounds__(256) void k_conv_t(const float* __restrict__ x,
                                                const float* __restrict__ cw,
                                                const float* __restrict__ cb,
                                                float* __restrict__ xc) {
  __shared__ float T[64][65];
  __shared__ float Wc[64 * 9];
  __shared__ float Cbs[64];
  const int b = blockIdx.z;
  const int cc = blockIdx.y * 64;
  const int hw0 = blockIdx.x * 64;
  const int t = threadIdx.x;
  const int hwi = t & 63, ci0 = t >> 6;   // conv phase: lane = hw (coalesced)
  const int hw = hw0 + hwi;
  const int yy = hw / CW, xx = hw % CW;
  const int ci2 = t & 63, hb2 = t >> 6;   // write phase: lane = c (coalesced)

  for (int i = t; i < 64 * 9; i += 256) Wc[i] = cw[cc * 9 + i];
  if (t < 64) Cbs[t] = cb[cc + t];
  __syncthreads();
  if (hw < HW) {
#pragma unroll
    for (int j = 0; j < 16; j++) {
      const int cl = ci0 * 16 + j;               // wave-uniform channel
      const float* xp = x + ((size_t)(b * CC + cc + cl)) * HW;
      float acc = Cbs[cl];
      const float center = xp[yy * CW + xx];
#pragma unroll
      for (int ky = 0; ky < 3; ky++) {
        const int iy = yy + ky - 1;
        if (iy < 0 || iy >= CH) continue;
#pragma unroll
        for (int kx = 0; kx < 3; kx++) {
          const int ix = xx + kx - 1;
          if (ix < 0 || ix >= CW) continue;
          acc += Wc[cl * 9 + ky * 3 + kx] * xp[iy * CW + ix];
        }
      }
      T[cl][hwi] = center + acc;
    }
  }
  __syncthreads();
#pragma unroll
  for (int j = 0; j < 16; j++) {
    const int hwl = hb2 + j * 4;
    if (hw0 + hwl < HW)
      xc[((size_t)b * CN + 1 + hw0 + hwl) * CC + cc + ci2] = T[ci2][hwl];
  }
}

// ---------------------------------------------------------------------------
// K2: LayerNorm over last dim (384), fp32 in -> bf16 out. 1 wave per row.
// ---------------------------------------------------------------------------
__global__ __launch_bounds__(256) void k_ln(const float* __restrict__ xin,
                                            const float* __restrict__ g,
                                            const float* __restrict__ bta,
                                            short* __restrict__ y, int Mtot) {
  const int row = blockIdx.x * 4 + (threadIdx.x >> 6);
  const int l = threadIdx.x & 63;
  if (row >= Mtot) return;
  const float* xr = xin + (size_t)row * CC;
  float v[6], s = 0.f, ss = 0.f;
#pragma unroll
  for (int i = 0; i < 6; i++) {
    v[i] = xr[l + i * 64];
    s += v[i];
    ss += v[i] * v[i];
  }
#pragma unroll
  for (int m = 1; m < 64; m <<= 1) { s += __shfl_xor(s, m); ss += __shfl_xor(ss, m); }
  const float mu = s * (1.f / CC);
  const float var = ss * (1.f / CC) - mu * mu;
  const float r = rsqrtf(var + 1e-5f);
#pragma unroll
  for (int i = 0; i < 6; i++) {
    const int c = l + i * 64;
    y[(size_t)row * CC + c] = f2b((v[i] - mu) * r * g[c] + bta[c]);
  }
}

// ---------------------------------------------------------------------------
// K3: GEMM  C[M,N] = A[M,K] @ W[N,K]^T (+bias)(+gelu)(+resid)
//     m97 structure: 128x128 tile, 4 waves, BK=32, global_load_lds width 16.
// ---------------------------------------------------------------------------
template <int DOGELU, int DORES, int DOBIAS, int OUTBF>
__global__ __launch_bounds__(256) void k_gemm(const short* __restrict__ A,
                                              const short* __restrict__ W,
                                              const float* __restrict__ bias,
                                              const float* __restrict__ resid,
                                              void* __restrict__ out_,
                                              int M, int N, int K) {
  __shared__ short As[128 * 32];
  __shared__ short Bs[128 * 32];
  const int bm = blockIdx.x * 128, bn = blockIdx.y * 128;
  const int t = threadIdx.x, w = t >> 6, l = t & 63, g = l >> 4, li = l & 15;
  const int wm = (w >> 1) * 64, wn = (w & 1) * 64;

  const int srow = l >> 2;
  const int scol = (l & 3) * 8;
  const short* aSrc[2]; const short* bSrc[2];
  short* aDst[2]; short* bDst[2];
#pragma unroll
  for (int j = 0; j < 2; j++) {
    int arow = bm + w * 32 + j * 16 + srow; if (arow > M - 1) arow = M - 1;
    aSrc[j] = A + (size_t)arow * K + scol;
    aDst[j] = &As[(w * 32 + j * 16) * 32];
    const int brow = bn + w * 32 + j * 16 + srow;
    bSrc[j] = W + (size_t)brow * K + scol;
    bDst[j] = &Bs[(w * 32 + j * 16) * 32];
  }

  f32x4 acc[4][4] = {};
  const int nkt = K / 32;
  for (int kt = 0; kt < nkt; kt++) {
#pragma unroll
    for (int j = 0; j < 2; j++) {
      gload16(aSrc[j], aDst[j]);
      gload16(bSrc[j], bDst[j]);
      aSrc[j] += 32; bSrc[j] += 32;
    }
    __syncthreads();
    bf16x8 af[4], bf[4];
#pragma unroll
    for (int mi = 0; mi < 4; mi++)
      af[mi] = *(const bf16x8*)&As[(wm + mi * 16 + li) * 32 + g * 8];
#pragma unroll
    for (int ni = 0; ni < 4; ni++)
      bf[ni] = *(const bf16x8*)&Bs[(wn + ni * 16 + li) * 32 + g * 8];
#pragma unroll
    for (int mi = 0; mi < 4; mi++)
#pragma unroll
      for (int ni = 0; ni < 4; ni++)
        acc[mi][ni] = __builtin_amdgcn_mfma_f32_16x16x32_bf16(af[mi], bf[ni], acc[mi][ni], 0, 0, 0);
    __syncthreads();
  }

#pragma unroll
  for (int mi = 0; mi < 4; mi++)
#pragma unroll
    for (int ni = 0; ni < 4; ni++) {
      const int col = bn + wn + ni * 16 + li;
      float bv = 0.f;
      if constexpr (DOBIAS) bv = bias[col];
#pragma unroll
      for (int r = 0; r < 4; r++) {
        const int row = bm + wm + mi * 16 + g * 4 + r;
        if (row < M) {
          float v = acc[mi][ni][r] + bv;
          if constexpr (DOGELU) v = 0.5f * v * (1.f + erff(v * 0.7071067811865475f));
          if constexpr (DORES) v += resid[(size_t)row * N + col];
          if constexpr (OUTBF)
            ((short*)out_)[(size_t)row * N + col] = f2b(v);
          else
            ((float*)out_)[(size_t)row * N + col] = v;
        }
      }
    }
}

// ---------------------------------------------------------------------------
// K4: flash attention, LDS-staged K/V shared by 4 waves, KVBLK=64.
//     flat grid 1664 = 8 xcd-slots x 16 bh-per-slot x 13 q-tiles; the 13
//     q-tiles of one (b,h) share an XCD slot -> K/V stays in that L2.
//     XOR-swizzled LDS (byte ^= (row&7)<<4) -> conflict-free ds_read_b128.
// ---------------------------------------------------------------------------
__global__ __launch_bounds__(256) void k_attn(const short* __restrict__ qkv,
                                              short* __restrict__ o) {
  __shared__ short Ks[64 * 48];       // [kv][d]   row stride 96 B, swizzled
  __shared__ short Vt[48 * 64];       // [d][kv]   row stride 128 B, swizzled
  __shared__ short Pw[4 * 16 * 64];   // per-wave [q][kv], row stride 128 B, swizzled
  const int f = blockIdx.x;
  const int xslot = f & 7, grp = f >> 3;
  const int bh = xslot + 8 * (grp & 15);
  const int qt = grp >> 4;                 // 0..12
  const int b = bh >> 3, h = bh & 7;
  const int q0 = qt * 64;
  const int t = threadIdx.x, w = t >> 6, l = t & 63, g = l >> 4, li = l & 15;
  const size_t bbase = (size_t)b * CN;

  // Q fragments (held in regs for the whole kernel)
  const int qrow = q0 + w * 16 + li;
  const int qr = qrow > CN - 1 ? CN - 1 : qrow;
  const short* qb = qkv + (bbase + qr) * C3 + h * CD;
  bf16x8 qf0 = *(const bf16x8*)(qb + g * 8);
  bf16x8 qf1 = {};
  if (g < 2) qf1 = *(const bf16x8*)(qb + 32 + g * 8);

  float mr[4], ls[4];
  f32x4 oa[3] = {};
#pragma unroll
  for (int r = 0; r < 4; r++) { mr[r] = -1e30f; ls[r] = 0.f; }
  const float scale = 0.14433756729740643f; // 1/sqrt(48)
  short* PwW = &Pw[w * 16 * 64];

  const int nkt = (CN + 63) / 64; // 13
  for (int kt = 0; kt < nkt; kt++) {
    const int kv0 = kt * 64;
    __syncthreads();
    // ---- stage K tile: 64 rows x 6 x 16B granules, coalesced
#pragma unroll
    for (int it = 0; it < 2; it++) {
      const int gi = t + it * 256;
      if (gi < 384) {
        const int row = gi / 6, cg = gi % 6;
        const int kr = min(kv0 + row, CN - 1);
        bf16x8 val = *(const bf16x8*)(qkv + (bbase + kr) * C3 + CC + h * CD + cg * 8);
        const int byte = (row * 96 + cg * 16) ^ ((row & 7) << 4);
        *(bf16x8*)((char*)Ks + byte) = val;
      }
    }
    // ---- stage V tile transposed: 64 rows x 6 x 16B granule reads,
    //      8 swizzled 2B scatter-stores each (full 48 d coverage)
#pragma unroll
    for (int it = 0; it < 2; it++) {
      const int gi = t + it * 256;
      if (gi < 384) {
        const int row = gi / 6, cg = gi % 6;
        const int kr = min(kv0 + row, CN - 1);
        bf16x8 val = *(const bf16x8*)(qkv + (bbase + kr) * C3 + 2 * CC + h * CD + cg * 8);
#pragma unroll
        for (int i = 0; i < 8; i++) {
          const int d = cg * 8 + i;
          const int byte = (d * 128 + row * 2) ^ ((d & 7) << 4);
          *(short*)((char*)Vt + byte) = val[i];
        }
      }
    }
    __syncthreads();

    // ---- S = Q K^T : 16 q x 64 kv per wave
    f32x4 s[4];
    __builtin_amdgcn_s_setprio(1);
#pragma unroll
    for (int ni = 0; ni < 4; ni++) {
      const int krow = ni * 16 + li;
      bf16x8 kf0 = *(const bf16x8*)((char*)Ks + ((krow * 96 + g * 16) ^ ((krow & 7) << 4)));
      bf16x8 kf1 = {};
      if (g < 2)
        kf1 = *(const bf16x8*)((char*)Ks + ((krow * 96 + 64 + g * 16) ^ ((krow & 7) << 4)));
      f32x4 acc = {};
      acc = __builtin_amdgcn_mfma_f32_16x16x32_bf16(qf0, kf0, acc, 0, 0, 0);
      acc = __builtin_amdgcn_mfma_f32_16x16x32_bf16(qf1, kf1, acc, 0, 0, 0);
      const bool oob = kv0 + krow >= CN;
#pragma unroll
      for (int r = 0; r < 4; r++) acc[r] = oob ? -1e30f : acc[r] * scale;
      s[ni] = acc;
    }
    __builtin_amdgcn_s_setprio(0);

    // ---- online softmax (rows live in 16-lane groups)
    float mx[4], al[4], ps[4];
#pragma unroll
    for (int r = 0; r < 4; r++)
      mx[r] = fmaxf(fmaxf(s[0][r], s[1][r]), fmaxf(s[2][r], s[3][r]));
#pragma unroll
    for (int msk = 1; msk < 16; msk <<= 1)
#pragma unroll
      for (int r = 0; r < 4; r++) mx[r] = fmaxf(mx[r], __shfl_xor(mx[r], msk));
#pragma unroll
    for (int r = 0; r < 4; r++) {
      const float mn = fmaxf(mr[r], mx[r]);
      al[r] = __expf(mr[r] - mn);
      mr[r] = mn;
    }
#pragma unroll
    for (int ni = 0; ni < 4; ni++)
#pragma unroll
      for (int r = 0; r < 4; r++) s[ni][r] = __expf(s[ni][r] - mr[r]);
#pragma unroll
    for (int r = 0; r < 4; r++)
      ps[r] = (s[0][r] + s[1][r]) + (s[2][r] + s[3][r]);
#pragma unroll
    for (int msk = 1; msk < 16; msk <<= 1)
#pragma unroll
      for (int r = 0; r < 4; r++) ps[r] += __shfl_xor(ps[r], msk);
#pragma unroll
    for (int r = 0; r < 4; r++) ls[r] = ls[r] * al[r] + ps[r];
#pragma unroll
    for (int ni = 0; ni < 3; ni++)
#pragma unroll
      for (int r = 0; r < 4; r++) oa[ni][r] *= al[r];

    // ---- P -> LDS (bf16), per-wave region, swizzled
#pragma unroll
    for (int ni = 0; ni < 4; ni++)
#pragma unroll
      for (int r = 0; r < 4; r++) {
        const int row = g * 4 + r, col = ni * 16 + li;
        const int byte = (row * 128 + col * 2) ^ ((row & 7) << 4);
        *(short*)((char*)PwW + byte) = f2b(s[ni][r]);
      }
    asm volatile("s_waitcnt lgkmcnt(0)" ::: "memory");
    __builtin_amdgcn_sched_barrier(0);

    // ---- O += P V  (2 k-chunks of 32 kv each)
    bf16x8 pa[2];
#pragma unroll
    for (int ks = 0; ks < 2; ks++)
      pa[ks] = *(const bf16x8*)((char*)PwW + ((li * 128 + (ks * 32 + g * 8) * 2) ^ ((li & 7) << 4)));
    __builtin_amdgcn_s_setprio(1);
#pragma unroll
    for (int ni = 0; ni < 3; ni++) {
      const int vrow = ni * 16 + li;
#pragma unroll
      for (int ks = 0; ks < 2; ks++) {
        bf16x8 vb = *(const bf16x8*)((char*)Vt + ((vrow * 128 + (ks * 32 + g * 8) * 2) ^ ((vrow & 7) << 4)));
        oa[ni] = __builtin_amdgcn_mfma_f32_16x16x32_bf16(pa[ks], vb, oa[ni], 0, 0, 0);
      }
    }
    __builtin_amdgcn_s_setprio(0);
  }

#pragma unroll
  for (int ni = 0; ni < 3; ni++)
#pragma unroll
    for (int r = 0; r < 4; r++) {
      const int n = q0 + w * 16 + g * 4 + r;
      if (n < CN)
        o[(bbase + n) * CC + h * CD + ni * 16 + li] = f2b(oa[ni][r] / ls[r]);
    }
}

// ---------------------------------------------------------------------------
// K5: global_attn = mean over heads of softmax(q0 . k)[1:]. grid = B*H blocks.
// ---------------------------------------------------------------------------
__global__ __launch_bounds__(256) void k_gattn(const short* __restrict__ qkv,
                                               float* __restrict__ ga) {
  const int b = blockIdx.x >> 3, h = blockIdx.x & 7;
  __shared__ float red[4];
  const int t = threadIdx.x;
  const size_t bbase = (size_t)b * CN;
  const short* q0 = qkv + bbase * C3 + h * CD;
  float qv[CD];
#pragma unroll
  for (int i = 0; i < CD; i++) qv[i] = b2f(q0[i]);
  float lg[4], ev[4];
  float lmax = -1e30f;
#pragma unroll
  for (int j = 0; j < 4; j++) {
    const int m = t + j * 256;
    if (m < CN) {
      const short* kr = qkv + (bbase + m) * C3 + CC + h * CD;
      float acc = 0.f;
#pragma unroll
      for (int i = 0; i < CD; i++) acc += qv[i] * b2f(kr[i]);
      lg[j] = acc * 0.14433756729740643f;
      lmax = fmaxf(lmax, lg[j]);
    } else lg[j] = -1e30f;
  }
  for (int msk = 1; msk < 64; msk <<= 1) lmax = fmaxf(lmax, __shfl_xor(lmax, msk));
  if ((t & 63) == 0) red[t >> 6] = lmax;
  __syncthreads();
  lmax = fmaxf(fmaxf(red[0], red[1]), fmaxf(red[2], red[3]));
  __syncthreads();
  float es = 0.f;
#pragma unroll
  for (int j = 0; j < 4; j++) {
    ev[j] = (t + j * 256 < CN) ? __expf(lg[j] - lmax) : 0.f;
    es += ev[j];
  }
  for (int msk = 1; msk < 64; msk <<= 1) es += __shfl_xor(es, msk);
  if ((t & 63) == 0) red[t >> 6] = es;
  __syncthreads();
  es = red[0] + red[1] + red[2] + red[3];
  const float inv = 0.125f / es;
#pragma unroll
  for (int j = 0; j < 4; j++) {
    const int m = t + j * 256;
    if (m >= 1 && m < CN) atomicAdd(&ga[b * HW + m - 1], ev[j] * inv);
  }
}

// ---------------------------------------------------------------------------
// K6: output: x_out via LDS-tiled transpose (both sides coalesced) + cls_out
// ---------------------------------------------------------------------------
__global__ __launch_bounds__(256) void k_out(const float* __restrict__ xc,
                                             float* __restrict__ outp) {
  const int b = blockIdx.y, tile = blockIdx.x, t = threadIdx.x;
  if (tile == 78) {
    for (int i = t; i < CC; i += 256)
      outp[b * CC + i] = xc[((size_t)b * CN) * CC + i];
    return;
  }
  __shared__ float T[64][65];
  const int ct = tile / 13, ht = tile % 13;
  const int c0 = ct * 64, hw0 = ht * 64;
  const int ci = t & 63, hb = t >> 6;
  for (int j = 0; j < 16; j++) {
    const int hwl = hb + j * 4;
    if (hw0 + hwl < HW)
      T[ci][hwl] = xc[((size_t)b * CN + 1 + hw0 + hwl) * CC + c0 + ci];
  }
  __syncthreads();
  const int hi = t & 63, cb2 = t >> 6;
  float* xo = outp + CB * CC;
  for (int j = 0; j < 16; j++) {
    const int cl = cb2 + j * 4;
    if (hw0 + hi < HW)
      xo[((size_t)(b * CC + c0 + cl)) * HW + hw0 + hi] = T[cl][hi];
  }
}

// ---------------------------------------------------------------------------
extern "C" void kernel_launch(void* const* d_in, const int* in_sizes, int n_in,
                              void* d_out, int out_size, void* d_ws, size_t ws_size,
                              hipStream_t stream) {
  const float* cls    = (const float*)d_in[0];
  const float* x      = (const float*)d_in[1];
  const float* conv_w = (const float*)d_in[2];
  const float* conv_b = (const float*)d_in[3];
  const float* ln1_g  = (const float*)d_in[4];
  const float* ln1_b  = (const float*)d_in[5];
  const float* qkv_w  = (const float*)d_in[6];
  const float* proj_w = (const float*)d_in[7];
  const float* proj_b = (const float*)d_in[8];
  const float* ln2_g  = (const float*)d_in[9];
  const float* ln2_b  = (const float*)d_in[10];
  const float* fc1_w  = (const float*)d_in[11];
  const float* fc1_b  = (const float*)d_in[12];
  const float* fc2_w  = (const float*)d_in[13];
  const float* fc2_b  = (const float*)d_in[14];

  float* outf = (float*)d_out;
  float* ga = outf + (size_t)CB * CC + (size_t)CB * CC * HW;

  char* ws = (char*)d_ws;
  float* xc   = (float*)ws;
  short* y    = (short*)(ws + 19292160ULL);
  short* qkvb = (short*)(ws + 28938240ULL);
  short* o    = (short*)(ws + 57876480ULL);
  short* m1   = (short*)(ws + 28938240ULL);
  short* wbuf = (short*)(ws + 67522560ULL);
  short* qkv_wb = wbuf;
  short* proj_wb = wbuf + 442368;
  short* fc1_wb  = wbuf + 589824;
  short* fc2_wb  = wbuf + 1179648;

  const int thr = 256;
  k_misc<<<49, thr, 0, stream>>>(cls, xc, ga);
  k_wconv<<<1728, thr, 0, stream>>>(qkv_w, proj_w, fc1_w, fc2_w, wbuf);
  k_conv_t<<<dim3(13, 6, CB), thr, 0, stream>>>(x, conv_w, conv_b, xc);
  k_ln<<<CM / 4, thr, 0, stream>>>(xc, ln1_g, ln1_b, y, CM);
  k_gemm<0, 0, 0, 1><<<dim3(99, C3 / 128), thr, 0, stream>>>(
      y, qkv_wb, nullptr, nullptr, qkvb, CM, C3, CC);
  k_attn<<<1664, thr, 0, stream>>>(qkvb, o);
  k_gattn<<<CB * 8, thr, 0, stream>>>(qkvb, ga);
  k_gemm<0, 1, 1, 0><<<dim3(99, CC / 128), thr, 0, stream>>>(
      o, proj_wb, proj_b, xc, xc, CM, CC, CC);
  k_ln<<<CM / 4, thr, 0, stream>>>(xc, ln2_g, ln2_b, y, CM);
  k_gemm<1, 0, 1, 1><<<dim3(99, CF / 128), thr, 0, stream>>>(
      y, fc1_wb, fc1_b, nullptr, m1, CM, CF, CC);
  k_gemm<0, 1, 1, 0><<<dim3(99, CC / 128), thr, 0, stream>>>(
      m1, fc2_wb, fc2_b, xc, xc, CM, CC, CF);
  k_out<<<dim3(79, CB), thr, 0, stream>>>(xc, outf);
}

// Round 8
// 398.043 us; speedup vs baseline: 1.9096x; 1.1823x over previous
//
#include <hip/hip_runtime.h>
#include <hip/hip_bf16.h>

#define DI __device__ __forceinline__

typedef __attribute__((ext_vector_type(4))) float f32x4;
typedef __attribute__((ext_vector_type(8))) short bf16x8;
typedef __attribute__((ext_vector_type(4))) short bf16x4;

static constexpr int CB = 16;        // batch
static constexpr int CC = 384;       // channels
static constexpr int CH = 28, CW = 28;
static constexpr int CD = 48;        // head dim
static constexpr int CN = 785;       // 1 + 28*28
static constexpr int CM = CB * CN;   // 12560 rows
static constexpr int C3 = 3 * CC;    // 1152
static constexpr int CF = 4 * CC;    // 1536
static constexpr int HW = CH * CW;   // 784
static constexpr int NP = 832;       // padded seq for vt

DI short f2b(float f) {
  __hip_bfloat16 h = __float2bfloat16(f);
  return *reinterpret_cast<short*>(&h);
}
DI float b2f(short s) {
  union { unsigned u; float f; } x;
  x.u = ((unsigned)(unsigned short)s) << 16;
  return x.f;
}

DI void gload16(const short* g, short* l) {
  __builtin_amdgcn_global_load_lds((const __attribute__((address_space(1))) void*)g,
                                   (__attribute__((address_space(3))) void*)l, 16, 0, 0);
}

// ---------------------------------------------------------------------------
// K0: zero global_attn, write cls row of xc
// ---------------------------------------------------------------------------
__global__ void k_misc(const float* __restrict__ cls, float* __restrict__ xc,
                       float* __restrict__ ga) {
  const int gid = blockIdx.x * 256 + threadIdx.x;
  if (gid < CB * HW) ga[gid] = 0.f;
  if (gid < CB * CC) {
    const int b = gid / CC, c = gid % CC;
    xc[((size_t)b * CN) * CC + c] = cls[gid];
  }
}

// ---------------------------------------------------------------------------
// K0b: convert the four weight matrices fp32 -> bf16 (contiguous in wbuf)
// ---------------------------------------------------------------------------
__global__ void k_wconv(const float* __restrict__ s0, const float* __restrict__ s1,
                        const float* __restrict__ s2, const float* __restrict__ s3,
                        short* __restrict__ dst) {
  const int gid = (blockIdx.x * 256 + threadIdx.x) * 4;
  if (gid >= 1769472) return;
  const float* s; int off;
  if (gid < 442368)       { s = s0; off = gid; }
  else if (gid < 589824)  { s = s1; off = gid - 442368; }
  else if (gid < 1179648) { s = s2; off = gid - 589824; }
  else                    { s = s3; off = gid - 1179648; }
  f32x4 v = *(const f32x4*)(s + off);
  bf16x4 o;
#pragma unroll
  for (int i = 0; i < 4; i++) o[i] = f2b(v[i]);
  *(bf16x4*)(dst + gid) = o;
}

// ---------------------------------------------------------------------------
// K1: depthwise conv3x3 + residual, coalesced along hw, LDS-transposed write.
//     grid (13 hw-tiles, 6 c-chunks, B) = 1248 blocks.
// ---------------------------------------------------------------------------
__global__ __launch_bounds__(256) void k_conv_t(const float* __restrict__ x,
                                                const float* __restrict__ cw,
                                                const float* __restrict__ cb,
                                                float* __restrict__ xc) {
  __shared__ float T[64][65];
  __shared__ float Wc[64 * 9];
  __shared__ float Cbs[64];
  const int b = blockIdx.z;
  const int cc = blockIdx.y * 64;
  const int hw0 = blockIdx.x * 64;
  const int t = threadIdx.x;
  const int hwi = t & 63, ci0 = t >> 6;
  const int hw = hw0 + hwi;
  const int yy = hw / CW, xx = hw % CW;
  const int ci2 = t & 63, hb2 = t >> 6;

  for (int i = t; i < 64 * 9; i += 256) Wc[i] = cw[cc * 9 + i];
  if (t < 64) Cbs[t] = cb[cc + t];
  __syncthreads();
  if (hw < HW) {
#pragma unroll
    for (int j = 0; j < 16; j++) {
      const int cl = ci0 * 16 + j;
      const float* xp = x + ((size_t)(b * CC + cc + cl)) * HW;
      float acc = Cbs[cl];
      const float center = xp[yy * CW + xx];
#pragma unroll
      for (int ky = 0; ky < 3; ky++) {
        const int iy = yy + ky - 1;
        if (iy < 0 || iy >= CH) continue;
#pragma unroll
        for (int kx = 0; kx < 3; kx++) {
          const int ix = xx + kx - 1;
          if (ix < 0 || ix >= CW) continue;
          acc += Wc[cl * 9 + ky * 3 + kx] * xp[iy * CW + ix];
        }
      }
      T[cl][hwi] = center + acc;
    }
  }
  __syncthreads();
#pragma unroll
  for (int j = 0; j < 16; j++) {
    const int hwl = hb2 + j * 4;
    if (hw0 + hwl < HW)
      xc[((size_t)b * CN + 1 + hw0 + hwl) * CC + cc + ci2] = T[ci2][hwl];
  }
}

// ---------------------------------------------------------------------------
// K2: LayerNorm over last dim (384), fp32 in -> bf16 out. 1 wave per row.
// ---------------------------------------------------------------------------
__global__ __launch_bounds__(256) void k_ln(const float* __restrict__ xin,
                                            const float* __restrict__ g,
                                            const float* __restrict__ bta,
                                            short* __restrict__ y, int Mtot) {
  const int row = blockIdx.x * 4 + (threadIdx.x >> 6);
  const int l = threadIdx.x & 63;
  if (row >= Mtot) return;
  const float* xr = xin + (size_t)row * CC;
  float v[6], s = 0.f, ss = 0.f;
#pragma unroll
  for (int i = 0; i < 6; i++) {
    v[i] = xr[l + i * 64];
    s += v[i];
    ss += v[i] * v[i];
  }
#pragma unroll
  for (int m = 1; m < 64; m <<= 1) { s += __shfl_xor(s, m); ss += __shfl_xor(ss, m); }
  const float mu = s * (1.f / CC);
  const float var = ss * (1.f / CC) - mu * mu;
  const float r = rsqrtf(var + 1e-5f);
#pragma unroll
  for (int i = 0; i < 6; i++) {
    const int c = l + i * 64;
    y[(size_t)row * CC + c] = f2b((v[i] - mu) * r * g[c] + bta[c]);
  }
}

// ---------------------------------------------------------------------------
// K3: GEMM  C[M,N] = A[M,K] @ W[N,K]^T (+bias)(+gelu)(+resid)
//     m97 structure: 128x128 tile, 4 waves, BK=32, global_load_lds width 16.
// ---------------------------------------------------------------------------
template <int DOGELU, int DORES, int DOBIAS, int OUTBF>
__global__ __launch_bounds__(256) void k_gemm(const short* __restrict__ A,
                                              const short* __restrict__ W,
                                              const float* __restrict__ bias,
                                              const float* __restrict__ resid,
                                              void* __restrict__ out_,
                                              int M, int N, int K) {
  __shared__ short As[128 * 32];
  __shared__ short Bs[128 * 32];
  const int bm = blockIdx.x * 128, bn = blockIdx.y * 128;
  const int t = threadIdx.x, w = t >> 6, l = t & 63, g = l >> 4, li = l & 15;
  const int wm = (w >> 1) * 64, wn = (w & 1) * 64;

  const int srow = l >> 2;
  const int scol = (l & 3) * 8;
  const short* aSrc[2]; const short* bSrc[2];
  short* aDst[2]; short* bDst[2];
#pragma unroll
  for (int j = 0; j < 2; j++) {
    int arow = bm + w * 32 + j * 16 + srow; if (arow > M - 1) arow = M - 1;
    aSrc[j] = A + (size_t)arow * K + scol;
    aDst[j] = &As[(w * 32 + j * 16) * 32];
    const int brow = bn + w * 32 + j * 16 + srow;
    bSrc[j] = W + (size_t)brow * K + scol;
    bDst[j] = &Bs[(w * 32 + j * 16) * 32];
  }

  f32x4 acc[4][4] = {};
  const int nkt = K / 32;
  for (int kt = 0; kt < nkt; kt++) {
#pragma unroll
    for (int j = 0; j < 2; j++) {
      gload16(aSrc[j], aDst[j]);
      gload16(bSrc[j], bDst[j]);
      aSrc[j] += 32; bSrc[j] += 32;
    }
    __syncthreads();
    bf16x8 af[4], bf[4];
#pragma unroll
    for (int mi = 0; mi < 4; mi++)
      af[mi] = *(const bf16x8*)&As[(wm + mi * 16 + li) * 32 + g * 8];
#pragma unroll
    for (int ni = 0; ni < 4; ni++)
      bf[ni] = *(const bf16x8*)&Bs[(wn + ni * 16 + li) * 32 + g * 8];
#pragma unroll
    for (int mi = 0; mi < 4; mi++)
#pragma unroll
      for (int ni = 0; ni < 4; ni++)
        acc[mi][ni] = __builtin_amdgcn_mfma_f32_16x16x32_bf16(af[mi], bf[ni], acc[mi][ni], 0, 0, 0);
    __syncthreads();
  }

#pragma unroll
  for (int mi = 0; mi < 4; mi++)
#pragma unroll
    for (int ni = 0; ni < 4; ni++) {
      const int col = bn + wn + ni * 16 + li;
      float bv = 0.f;
      if constexpr (DOBIAS) bv = bias[col];
#pragma unroll
      for (int r = 0; r < 4; r++) {
        const int row = bm + wm + mi * 16 + g * 4 + r;
        if (row < M) {
          float v = acc[mi][ni][r] + bv;
          if constexpr (DOGELU) v = 0.5f * v * (1.f + erff(v * 0.7071067811865475f));
          if constexpr (DORES) v += resid[(size_t)row * N + col];
          if constexpr (OUTBF)
            ((short*)out_)[(size_t)row * N + col] = f2b(v);
          else
            ((float*)out_)[(size_t)row * N + col] = v;
        }
      }
    }
}

// ---------------------------------------------------------------------------
// K3b: pre-transpose V: qkvb[b][n][768 + h*48 + d] -> vt[bh][d][NP=832]
//      (zero-pad n>=785).  grid (13 n-tiles, 128 bh).
// ---------------------------------------------------------------------------
__global__ __launch_bounds__(256) void k_vt(const short* __restrict__ qkv,
                                            short* __restrict__ vt) {
  __shared__ short Tl[48 * 71];   // [d][n] stride 71 (142B) to spread banks
  const int n0 = blockIdx.x * 64;
  const int bh = blockIdx.y;
  const int b = bh >> 3, h = bh & 7;
  const int t = threadIdx.x;
  const size_t bbase = (size_t)b * CN;
#pragma unroll
  for (int it = 0; it < 2; it++) {
    const int gi = t + it * 256;
    if (gi < 384) {
      const int nrel = gi / 6, dg = gi % 6;
      const int n = n0 + nrel;
      bf16x8 val = {};
      if (n < CN)
        val = *(const bf16x8*)(qkv + (bbase + n) * C3 + 2 * CC + h * CD + dg * 8);
#pragma unroll
      for (int i = 0; i < 8; i++) Tl[(dg * 8 + i) * 71 + nrel] = val[i];
    }
  }
  __syncthreads();
#pragma unroll
  for (int it = 0; it < 2; it++) {
    const int gj = t + it * 256;
    if (gj < 384) {
      const int d = gj >> 3, ng = gj & 7;
      bf16x8 v;
#pragma unroll
      for (int i = 0; i < 8; i++) v[i] = Tl[d * 71 + ng * 8 + i];
      *(bf16x8*)(vt + ((size_t)bh * CD + d) * NP + n0 + ng * 8) = v;
    }
  }
}

// ---------------------------------------------------------------------------
// K4: flash attention v2 — swapped QK^T (mfma(K,Q)): each lane owns one q-row,
//     softmax = 2 shfl_xor, P stays in registers (no P LDS). V comes from the
//     pre-transposed vt via [d][kv] swizzled LDS; kv-permutation sigma shared
//     by in-register P pack and the two ds_read_b64 V reads.
//     K/V global loads issued one tile ahead (reg-staged).  12KB LDS.
// ---------------------------------------------------------------------------
__global__ __launch_bounds__(256) void k_attn(const short* __restrict__ qkv,
                                              const short* __restrict__ vt,
                                              short* __restrict__ o) {
  __shared__ short Ks[64 * 48];   // [kv][d] rows 96B, XOR-swizzled
  __shared__ short Vs[48 * 64];   // [d][kv] rows 128B, XOR-swizzled
  const int f = blockIdx.x;
  const int xslot = f & 7, grp = f >> 3;
  const int bh = xslot + 8 * (grp & 15);
  const int qt = grp >> 4;                 // 0..12
  const int b = bh >> 3, h = bh & 7;
  const int q0 = qt * 64;
  const int t = threadIdx.x, w = t >> 6, l = t & 63, g = l >> 4, li = l & 15;
  const size_t bbase = (size_t)b * CN;

  // Q fragment (B-operand): col=li -> q = q0+w*16+li ; k=g*8+i -> d
  const int qrow = q0 + w * 16 + li;
  const int qr = qrow > CN - 1 ? CN - 1 : qrow;
  const short* qb = qkv + (bbase + qr) * C3 + h * CD;
  bf16x8 qf0 = *(const bf16x8*)(qb + g * 8);
  bf16x8 qf1 = {};
  if (g < 2) qf1 = *(const bf16x8*)(qb + 32 + g * 8);

  float mr = -1e30f, ls = 0.f;
  f32x4 oa[3] = {};
  const float scale = 0.14433756729740643f; // 1/sqrt(48)

  // staging split: 384 granules each (K: row*6+cg ; V: d*8+kvg); thread t and t+256
  const int krow0 = t / 6, kcg0 = t % 6;
  const int krow1 = (t + 256) / 6, kcg1 = (t + 256) % 6;   // valid when t<128
  const int vd0 = t >> 3, vkvg0 = t & 7;
  const int vd1 = (t + 256) >> 3, vkvg1 = (t + 256) & 7;   // valid when t<128
  const short* kbase = qkv + bbase * C3 + CC + h * CD;
  const short* vbase = vt + (size_t)bh * CD * NP;

  bf16x8 kr0 = {}, kr1 = {}, vr0 = {}, vr1 = {};
  kr0 = *(const bf16x8*)(kbase + (size_t)min(krow0, CN - 1) * C3 + kcg0 * 8);
  vr0 = *(const bf16x8*)(vbase + vd0 * NP + vkvg0 * 8);
  if (t < 128) {
    kr1 = *(const bf16x8*)(kbase + (size_t)min(krow1, CN - 1) * C3 + kcg1 * 8);
    vr1 = *(const bf16x8*)(vbase + vd1 * NP + vkvg1 * 8);
  }

  for (int kt = 0; kt < 13; kt++) {
    const int kv0 = kt * 64;
    __syncthreads();   // previous compute done; LDS free
    *(bf16x8*)((char*)Ks + ((krow0 * 96 + kcg0 * 16) ^ ((krow0 & 7) << 4))) = kr0;
    *(bf16x8*)((char*)Vs + ((vd0 * 128 + vkvg0 * 16) ^ ((vd0 & 7) << 4))) = vr0;
    if (t < 128) {
      *(bf16x8*)((char*)Ks + ((krow1 * 96 + kcg1 * 16) ^ ((krow1 & 7) << 4))) = kr1;
      *(bf16x8*)((char*)Vs + ((vd1 * 128 + vkvg1 * 16) ^ ((vd1 & 7) << 4))) = vr1;
    }
    __syncthreads();   // LDS ready
    if (kt < 12) {     // issue next-tile loads early; latency hides under MFMA
      const int kn = kv0 + 64;
      kr0 = *(const bf16x8*)(kbase + (size_t)min(kn + krow0, CN - 1) * C3 + kcg0 * 8);
      vr0 = *(const bf16x8*)(vbase + vd0 * NP + kn + vkvg0 * 8);
      if (t < 128) {
        kr1 = *(const bf16x8*)(kbase + (size_t)min(kn + krow1, CN - 1) * C3 + kcg1 * 8);
        vr1 = *(const bf16x8*)(vbase + vd1 * NP + kn + vkvg1 * 8);
      }
    }

    // ---- S = K Q^T : lane (g,li): s[ni][r] = S[kv=kv0+ni*16+g*4+r][q=qrow]
    f32x4 s[4];
    __builtin_amdgcn_s_setprio(1);
#pragma unroll
    for (int ni = 0; ni < 4; ni++) {
      const int krw = ni * 16 + li;
      const int sw = (krw & 7) << 4;
      bf16x8 kf0 = *(const bf16x8*)((char*)Ks + ((krw * 96 + g * 16) ^ sw));
      bf16x8 kf1 = {};
      if (g < 2) kf1 = *(const bf16x8*)((char*)Ks + ((krw * 96 + 64 + g * 16) ^ sw));
      f32x4 acc = {};
      acc = __builtin_amdgcn_mfma_f32_16x16x32_bf16(kf0, qf0, acc, 0, 0, 0);
      acc = __builtin_amdgcn_mfma_f32_16x16x32_bf16(kf1, qf1, acc, 0, 0, 0);
      s[ni] = acc;
    }
    __builtin_amdgcn_s_setprio(0);

    // ---- online softmax: one q per lane; reduce across g via 2 shfl_xor
    float mt = -1e30f;
#pragma unroll
    for (int ni = 0; ni < 4; ni++)
#pragma unroll
      for (int r = 0; r < 4; r++) {
        const int kva = kv0 + ni * 16 + g * 4 + r;
        const float v = (kva < CN) ? s[ni][r] * scale : -1e30f;
        s[ni][r] = v;
        mt = fmaxf(mt, v);
      }
    mt = fmaxf(mt, __shfl_xor(mt, 16));
    mt = fmaxf(mt, __shfl_xor(mt, 32));
    const float mn = fmaxf(mr, mt);
    const float al = __expf(mr - mn);
    mr = mn;
    float ps = 0.f;
#pragma unroll
    for (int ni = 0; ni < 4; ni++)
#pragma unroll
      for (int r = 0; r < 4; r++) {
        const float p = __expf(s[ni][r] - mn);
        s[ni][r] = p;
        ps += p;
      }
    ps += __shfl_xor(ps, 16);
    ps += __shfl_xor(ps, 32);
    ls = ls * al + ps;

    // rescale O: need al at q = g*4+r -> shfl from lane (same group, li=g*4+r)
    const int sb = (l & 48) + ((l & 48) >> 2);
    float ar[4];
#pragma unroll
    for (int r = 0; r < 4; r++) ar[r] = __shfl(al, sb + r);
#pragma unroll
    for (int d = 0; d < 3; d++)
#pragma unroll
      for (int r = 0; r < 4; r++) oa[d][r] *= ar[r];

    // ---- pack P in-register per sigma: k=g*8+i -> kv = ks*32 + (i<4 ? g*4+i : 16+g*4+i-4)
    bf16x8 pa[2];
#pragma unroll
    for (int ks = 0; ks < 2; ks++)
#pragma unroll
      for (int i = 0; i < 8; i++)
        pa[ks][i] = f2b(i < 4 ? s[2 * ks][i] : s[2 * ks + 1][i - 4]);

    // ---- O += P V : V B-frag via two ds_read_b64 per chunk (same sigma)
    __builtin_amdgcn_s_setprio(1);
#pragma unroll
    for (int d = 0; d < 3; d++) {
      const int drow = d * 16 + li;
      const int sw = (drow & 7) << 4;
#pragma unroll
      for (int ks = 0; ks < 2; ks++) {
        bf16x4 lo = *(const bf16x4*)((char*)Vs + ((drow * 128 + ks * 64 + g * 8) ^ sw));
        bf16x4 hi = *(const bf16x4*)((char*)Vs + ((drow * 128 + ks * 64 + 32 + g * 8) ^ sw));
        bf16x8 vb;
#pragma unroll
        for (int i = 0; i < 4; i++) { vb[i] = lo[i]; vb[4 + i] = hi[i]; }
        oa[d] = __builtin_amdgcn_mfma_f32_16x16x32_bf16(pa[ks], vb, oa[d], 0, 0, 0);
      }
    }
    __builtin_amdgcn_s_setprio(0);
  }

  // epilogue: O[q=g*4+r][d=dblk*16+li]; ls lives at lane li=q -> shfl
  const int sb = (l & 48) + ((l & 48) >> 2);
  float lr[4];
#pragma unroll
  for (int r = 0; r < 4; r++) lr[r] = __shfl(ls, sb + r);
#pragma unroll
  for (int d = 0; d < 3; d++)
#pragma unroll
    for (int r = 0; r < 4; r++) {
      const int n = q0 + w * 16 + g * 4 + r;
      if (n < CN)
        o[(bbase + n) * CC + h * CD + d * 16 + li] = f2b(oa[d][r] / lr[r]);
    }
}

// ---------------------------------------------------------------------------
// K5: global_attn = mean over heads of softmax(q0 . k)[1:]. grid = B*H blocks.
// ---------------------------------------------------------------------------
__global__ __launch_bounds__(256) void k_gattn(const short* __restrict__ qkv,
                                               float* __restrict__ ga) {
  const int b = blockIdx.x >> 3, h = blockIdx.x & 7;
  __shared__ float red[4];
  const int t = threadIdx.x;
  const size_t bbase = (size_t)b * CN;
  const short* q0 = qkv + bbase * C3 + h * CD;
  float qv[CD];
#pragma unroll
  for (int i = 0; i < CD; i++) qv[i] = b2f(q0[i]);
  float lg[4], ev[4];
  float lmax = -1e30f;
#pragma unroll
  for (int j = 0; j < 4; j++) {
    const int m = t + j * 256;
    if (m < CN) {
      const short* kr = qkv + (bbase + m) * C3 + CC + h * CD;
      float acc = 0.f;
#pragma unroll
      for (int i = 0; i < CD; i++) acc += qv[i] * b2f(kr[i]);
      lg[j] = acc * 0.14433756729740643f;
      lmax = fmaxf(lmax, lg[j]);
    } else lg[j] = -1e30f;
  }
  for (int msk = 1; msk < 64; msk <<= 1) lmax = fmaxf(lmax, __shfl_xor(lmax, msk));
  if ((t & 63) == 0) red[t >> 6] = lmax;
  __syncthreads();
  lmax = fmaxf(fmaxf(red[0], red[1]), fmaxf(red[2], red[3]));
  __syncthreads();
  float es = 0.f;
#pragma unroll
  for (int j = 0; j < 4; j++) {
    ev[j] = (t + j * 256 < CN) ? __expf(lg[j] - lmax) : 0.f;
    es += ev[j];
  }
  for (int msk = 1; msk < 64; msk <<= 1) es += __shfl_xor(es, msk);
  if ((t & 63) == 0) red[t >> 6] = es;
  __syncthreads();
  es = red[0] + red[1] + red[2] + red[3];
  const float inv = 0.125f / es;
#pragma unroll
  for (int j = 0; j < 4; j++) {
    const int m = t + j * 256;
    if (m >= 1 && m < CN) atomicAdd(&ga[b * HW + m - 1], ev[j] * inv);
  }
}

// ---------------------------------------------------------------------------
// K6: output: x_out via LDS-tiled transpose (both sides coalesced) + cls_out
// ---------------------------------------------------------------------------
__global__ __launch_bounds__(256) void k_out(const float* __restrict__ xc,
                                             float* __restrict__ outp) {
  const int b = blockIdx.y, tile = blockIdx.x, t = threadIdx.x;
  if (tile == 78) {
    for (int i = t; i < CC; i += 256)
      outp[b * CC + i] = xc[((size_t)b * CN) * CC + i];
    return;
  }
  __shared__ float T[64][65];
  const int ct = tile / 13, ht = tile % 13;
  const int c0 = ct * 64, hw0 = ht * 64;
  const int ci = t & 63, hb = t >> 6;
  for (int j = 0; j < 16; j++) {
    const int hwl = hb + j * 4;
    if (hw0 + hwl < HW)
      T[ci][hwl] = xc[((size_t)b * CN + 1 + hw0 + hwl) * CC + c0 + ci];
  }
  __syncthreads();
  const int hi = t & 63, cb2 = t >> 6;
  float* xo = outp + CB * CC;
  for (int j = 0; j < 16; j++) {
    const int cl = cb2 + j * 4;
    if (hw0 + hi < HW)
      xo[((size_t)(b * CC + c0 + cl)) * HW + hw0 + hi] = T[cl][hi];
  }
}

// ---------------------------------------------------------------------------
extern "C" void kernel_launch(void* const* d_in, const int* in_sizes, int n_in,
                              void* d_out, int out_size, void* d_ws, size_t ws_size,
                              hipStream_t stream) {
  const float* cls    = (const float*)d_in[0];
  const float* x      = (const float*)d_in[1];
  const float* conv_w = (const float*)d_in[2];
  const float* conv_b = (const float*)d_in[3];
  const float* ln1_g  = (const float*)d_in[4];
  const float* ln1_b  = (const float*)d_in[5];
  const float* qkv_w  = (const float*)d_in[6];
  const float* proj_w = (const float*)d_in[7];
  const float* proj_b = (const float*)d_in[8];
  const float* ln2_g  = (const float*)d_in[9];
  const float* ln2_b  = (const float*)d_in[10];
  const float* fc1_w  = (const float*)d_in[11];
  const float* fc1_b  = (const float*)d_in[12];
  const float* fc2_w  = (const float*)d_in[13];
  const float* fc2_b  = (const float*)d_in[14];

  float* outf = (float*)d_out;
  float* ga = outf + (size_t)CB * CC + (size_t)CB * CC * HW;
  // vt scratch lives in the (not-yet-written) x_out region of d_out:
  // floats [6144, 6144+2,457,600) — disjoint from cls (0..6144) and ga (4,823,040..)
  short* vtb = (short*)(outf + CB * CC);

  char* ws = (char*)d_ws;
  float* xc   = (float*)ws;
  short* y    = (short*)(ws + 19292160ULL);
  short* qkvb = (short*)(ws + 28938240ULL);
  short* o    = (short*)(ws + 57876480ULL);
  short* m1   = (short*)(ws + 28938240ULL);
  short* wbuf = (short*)(ws + 67522560ULL);
  short* qkv_wb = wbuf;
  short* proj_wb = wbuf + 442368;
  short* fc1_wb  = wbuf + 589824;
  short* fc2_wb  = wbuf + 1179648;

  const int thr = 256;
  k_misc<<<49, thr, 0, stream>>>(cls, xc, ga);
  k_wconv<<<1728, thr, 0, stream>>>(qkv_w, proj_w, fc1_w, fc2_w, wbuf);
  k_conv_t<<<dim3(13, 6, CB), thr, 0, stream>>>(x, conv_w, conv_b, xc);
  k_ln<<<CM / 4, thr, 0, stream>>>(xc, ln1_g, ln1_b, y, CM);
  k_gemm<0, 0, 0, 1><<<dim3(99, C3 / 128), thr, 0, stream>>>(
      y, qkv_wb, nullptr, nullptr, qkvb, CM, C3, CC);
  k_vt<<<dim3(13, CB * 8), thr, 0, stream>>>(qkvb, vtb);
  k_attn<<<1664, thr, 0, stream>>>(qkvb, vtb, o);
  k_gattn<<<CB * 8, thr, 0, stream>>>(qkvb, ga);
  k_gemm<0, 1, 1, 0><<<dim3(99, CC / 128), thr, 0, stream>>>(
      o, proj_wb, proj_b, xc, xc, CM, CC, CC);
  k_ln<<<CM / 4, thr, 0, stream>>>(xc, ln2_g, ln2_b, y, CM);
  k_gemm<1, 0, 1, 1><<<dim3(99, CF / 128), thr, 0, stream>>>(
      y, fc1_wb, fc1_b, nullptr, m1, CM, CF, CC);
  k_gemm<0, 1, 1, 0><<<dim3(99, CC / 128), thr, 0, stream>>>(
      m1, fc2_wb, fc2_b, xc, xc, CM, CC, CF);
  k_out<<<dim3(79, CB), thr, 0, stream>>>(xc, outf);
}

// Round 9
// 370.228 us; speedup vs baseline: 2.0530x; 1.0751x over previous
//
#include <hip/hip_runtime.h>
#include <hip/hip_bf16.h>

#define DI __device__ __forceinline__

typedef __attribute__((ext_vector_type(4))) float f32x4;
typedef __attribute__((ext_vector_type(8))) short bf16x8;
typedef __attribute__((ext_vector_type(4))) short bf16x4;

static constexpr int CB = 16;        // batch
static constexpr int CC = 384;       // channels
static constexpr int CH = 28, CW = 28;
static constexpr int CD = 48;        // head dim
static constexpr int CN = 785;       // 1 + 28*28
static constexpr int CM = CB * CN;   // 12560 rows
static constexpr int C3 = 3 * CC;    // 1152
static constexpr int CF = 4 * CC;    // 1536
static constexpr int HW = CH * CW;   // 784
static constexpr int NP = 832;       // padded seq for vt

DI short f2b(float f) {
  __hip_bfloat16 h = __float2bfloat16(f);
  return *reinterpret_cast<short*>(&h);
}
DI float b2f(short s) {
  union { unsigned u; float f; } x;
  x.u = ((unsigned)(unsigned short)s) << 16;
  return x.f;
}

DI void gload16(const short* g, short* l) {
  __builtin_amdgcn_global_load_lds((const __attribute__((address_space(1))) void*)g,
                                   (__attribute__((address_space(3))) void*)l, 16, 0, 0);
}

// ---------------------------------------------------------------------------
// K0: zero global_attn, write cls row of xc
// ---------------------------------------------------------------------------
__global__ void k_misc(const float* __restrict__ cls, float* __restrict__ xc,
                       float* __restrict__ ga) {
  const int gid = blockIdx.x * 256 + threadIdx.x;
  if (gid < CB * HW) ga[gid] = 0.f;
  if (gid < CB * CC) {
    const int b = gid / CC, c = gid % CC;
    xc[((size_t)b * CN) * CC + c] = cls[gid];
  }
}

// ---------------------------------------------------------------------------
// K0b: convert the four weight matrices fp32 -> bf16 (contiguous in wbuf)
// ---------------------------------------------------------------------------
__global__ void k_wconv(const float* __restrict__ s0, const float* __restrict__ s1,
                        const float* __restrict__ s2, const float* __restrict__ s3,
                        short* __restrict__ dst) {
  const int gid = (blockIdx.x * 256 + threadIdx.x) * 4;
  if (gid >= 1769472) return;
  const float* s; int off;
  if (gid < 442368)       { s = s0; off = gid; }
  else if (gid < 589824)  { s = s1; off = gid - 442368; }
  else if (gid < 1179648) { s = s2; off = gid - 589824; }
  else                    { s = s3; off = gid - 1179648; }
  f32x4 v = *(const f32x4*)(s + off);
  bf16x4 o;
#pragma unroll
  for (int i = 0; i < 4; i++) o[i] = f2b(v[i]);
  *(bf16x4*)(dst + gid) = o;
}

// ---------------------------------------------------------------------------
// K1: depthwise conv3x3 + residual, coalesced along hw, LDS-transposed write.
//     grid (13 hw-tiles, 6 c-chunks, B) = 1248 blocks.
// ---------------------------------------------------------------------------
__global__ __launch_bounds__(256) void k_conv_t(const float* __restrict__ x,
                                                const float* __restrict__ cw,
                                                const float* __restrict__ cb,
                                                float* __restrict__ xc) {
  __shared__ float T[64][65];
  __shared__ float Wc[64 * 9];
  __shared__ float Cbs[64];
  const int b = blockIdx.z;
  const int cc = blockIdx.y * 64;
  const int hw0 = blockIdx.x * 64;
  const int t = threadIdx.x;
  const int hwi = t & 63, ci0 = t >> 6;
  const int hw = hw0 + hwi;
  const int yy = hw / CW, xx = hw % CW;
  const int ci2 = t & 63, hb2 = t >> 6;

  for (int i = t; i < 64 * 9; i += 256) Wc[i] = cw[cc * 9 + i];
  if (t < 64) Cbs[t] = cb[cc + t];
  __syncthreads();
  if (hw < HW) {
#pragma unroll
    for (int j = 0; j < 16; j++) {
      const int cl = ci0 * 16 + j;
      const float* xp = x + ((size_t)(b * CC + cc + cl)) * HW;
      float acc = Cbs[cl];
      const float center = xp[yy * CW + xx];
#pragma unroll
      for (int ky = 0; ky < 3; ky++) {
        const int iy = yy + ky - 1;
        if (iy < 0 || iy >= CH) continue;
#pragma unroll
        for (int kx = 0; kx < 3; kx++) {
          const int ix = xx + kx - 1;
          if (ix < 0 || ix >= CW) continue;
          acc += Wc[cl * 9 + ky * 3 + kx] * xp[iy * CW + ix];
        }
      }
      T[cl][hwi] = center + acc;
    }
  }
  __syncthreads();
#pragma unroll
  for (int j = 0; j < 16; j++) {
    const int hwl = hb2 + j * 4;
    if (hw0 + hwl < HW)
      xc[((size_t)b * CN + 1 + hw0 + hwl) * CC + cc + ci2] = T[ci2][hwl];
  }
}

// ---------------------------------------------------------------------------
// K2: LayerNorm over last dim (384), fp32 in -> bf16 out. 1 wave per row.
// ---------------------------------------------------------------------------
__global__ __launch_bounds__(256) void k_ln(const float* __restrict__ xin,
                                            const float* __restrict__ g,
                                            const float* __restrict__ bta,
                                            short* __restrict__ y, int Mtot) {
  const int row = blockIdx.x * 4 + (threadIdx.x >> 6);
  const int l = threadIdx.x & 63;
  if (row >= Mtot) return;
  const float* xr = xin + (size_t)row * CC;
  float v[6], s = 0.f, ss = 0.f;
#pragma unroll
  for (int i = 0; i < 6; i++) {
    v[i] = xr[l + i * 64];
    s += v[i];
    ss += v[i] * v[i];
  }
#pragma unroll
  for (int m = 1; m < 64; m <<= 1) { s += __shfl_xor(s, m); ss += __shfl_xor(ss, m); }
  const float mu = s * (1.f / CC);
  const float var = ss * (1.f / CC) - mu * mu;
  const float r = rsqrtf(var + 1e-5f);
#pragma unroll
  for (int i = 0; i < 6; i++) {
    const int c = l + i * 64;
    y[(size_t)row * CC + c] = f2b((v[i] - mu) * r * g[c] + bta[c]);
  }
}

// ---------------------------------------------------------------------------
// K3: GEMM  C[M,N] = A[M,K] @ W[N,K]^T (+bias)(+gelu)(+resid)
//     2-phase pipelined: double-buffered LDS, stage(next) issued BEFORE
//     compute(cur), single barrier per K-step (T3-minimum recipe).
//     BM templated: 128 (qkv/fc1) or 64 (proj/fc2 -> 2x grid).
// ---------------------------------------------------------------------------
template <int BM, int DOGELU, int DORES, int DOBIAS, int OUTBF>
__global__ __launch_bounds__(256) void k_gemm(const short* __restrict__ A,
                                              const short* __restrict__ W,
                                              const float* __restrict__ bias,
                                              const float* __restrict__ resid,
                                              void* __restrict__ out_,
                                              int M, int N, int K) {
  constexpr int MI = BM / 32;       // acc row-frags per wave (4 or 2)
  constexpr int ACALLS = BM / 64;   // A staging calls per thread (2 or 1)
  __shared__ short As[2 * BM * 32];
  __shared__ short Bs[2 * 128 * 32];
  const int bm = blockIdx.x * BM, bn = blockIdx.y * 128;
  const int t = threadIdx.x, w = t >> 6, l = t & 63, g = l >> 4, li = l & 15;
  const int wm = (w >> 1) * (BM / 2), wn = (w & 1) * 64;

  const int srow = l >> 2;          // row within 16-row staging group
  const int scol = (l & 3) * 8;     // col offset (16B granules)
  const short* aSrc[ACALLS]; int aOff[ACALLS];
#pragma unroll
  for (int j = 0; j < ACALLS; j++) {
    int arow = bm + w * (BM / 4) + j * 16 + srow; if (arow > M - 1) arow = M - 1;
    aSrc[j] = A + (size_t)arow * K + scol;
    aOff[j] = (w * (BM / 4) + j * 16) * 32;
  }
  const short* bSrc[2]; int bOff[2];
#pragma unroll
  for (int j = 0; j < 2; j++) {
    const int brow = bn + w * 32 + j * 16 + srow;
    bSrc[j] = W + (size_t)brow * K + scol;
    bOff[j] = (w * 32 + j * 16) * 32;
  }

  auto stage = [&](int buf, int kt) {
    const int ko = kt * 32;
#pragma unroll
    for (int j = 0; j < ACALLS; j++)
      gload16(aSrc[j] + ko, &As[buf * (BM * 32)] + aOff[j]);
#pragma unroll
    for (int j = 0; j < 2; j++)
      gload16(bSrc[j] + ko, &Bs[buf * (128 * 32)] + bOff[j]);
  };

  f32x4 acc[MI][4] = {};
  const int nkt = K / 32;
  stage(0, 0);
  __syncthreads();                    // prologue: tile 0 landed
  int cur = 0;
  for (int kt = 0; kt < nkt; kt++) {
    if (kt + 1 < nkt) stage(cur ^ 1, kt + 1);   // prefetch in flight under compute
    const short* Ab = &As[cur * (BM * 32)];
    const short* Bb = &Bs[cur * (128 * 32)];
    bf16x8 af[MI], bf[4];
#pragma unroll
    for (int mi = 0; mi < MI; mi++)
      af[mi] = *(const bf16x8*)&Ab[(wm + mi * 16 + li) * 32 + g * 8];
#pragma unroll
    for (int ni = 0; ni < 4; ni++)
      bf[ni] = *(const bf16x8*)&Bb[(wn + ni * 16 + li) * 32 + g * 8];
#pragma unroll
    for (int mi = 0; mi < MI; mi++)
#pragma unroll
      for (int ni = 0; ni < 4; ni++)
        acc[mi][ni] = __builtin_amdgcn_mfma_f32_16x16x32_bf16(af[mi], bf[ni], acc[mi][ni], 0, 0, 0);
    __syncthreads();                  // drains prefetch vmcnt + readers done
    cur ^= 1;
  }

#pragma unroll
  for (int mi = 0; mi < MI; mi++)
#pragma unroll
    for (int ni = 0; ni < 4; ni++) {
      const int col = bn + wn + ni * 16 + li;
      float bv = 0.f;
      if constexpr (DOBIAS) bv = bias[col];
#pragma unroll
      for (int r = 0; r < 4; r++) {
        const int row = bm + wm + mi * 16 + g * 4 + r;
        if (row < M) {
          float v = acc[mi][ni][r] + bv;
          if constexpr (DOGELU) v = 0.5f * v * (1.f + erff(v * 0.7071067811865475f));
          if constexpr (DORES) v += resid[(size_t)row * N + col];
          if constexpr (OUTBF)
            ((short*)out_)[(size_t)row * N + col] = f2b(v);
          else
            ((float*)out_)[(size_t)row * N + col] = v;
        }
      }
    }
}

// ---------------------------------------------------------------------------
// K3b: pre-transpose V: qkvb[b][n][768 + h*48 + d] -> vt[bh][d][NP=832]
//      (zero-pad n>=785).  grid (13 n-tiles, 128 bh).
// ---------------------------------------------------------------------------
__global__ __launch_bounds__(256) void k_vt(const short* __restrict__ qkv,
                                            short* __restrict__ vt) {
  __shared__ short Tl[48 * 71];   // [d][n] stride 71 (142B) to spread banks
  const int n0 = blockIdx.x * 64;
  const int bh = blockIdx.y;
  const int b = bh >> 3, h = bh & 7;
  const int t = threadIdx.x;
  const size_t bbase = (size_t)b * CN;
#pragma unroll
  for (int it = 0; it < 2; it++) {
    const int gi = t + it * 256;
    if (gi < 384) {
      const int nrel = gi / 6, dg = gi % 6;
      const int n = n0 + nrel;
      bf16x8 val = {};
      if (n < CN)
        val = *(const bf16x8*)(qkv + (bbase + n) * C3 + 2 * CC + h * CD + dg * 8);
#pragma unroll
      for (int i = 0; i < 8; i++) Tl[(dg * 8 + i) * 71 + nrel] = val[i];
    }
  }
  __syncthreads();
#pragma unroll
  for (int it = 0; it < 2; it++) {
    const int gj = t + it * 256;
    if (gj < 384) {
      const int d = gj >> 3, ng = gj & 7;
      bf16x8 v;
#pragma unroll
      for (int i = 0; i < 8; i++) v[i] = Tl[d * 71 + ng * 8 + i];
      *(bf16x8*)(vt + ((size_t)bh * CD + d) * NP + n0 + ng * 8) = v;
    }
  }
}

// ---------------------------------------------------------------------------
// K4: flash attention v2 — swapped QK^T (mfma(K,Q)): each lane owns one q-row,
//     softmax = 2 shfl_xor, P stays in registers (no P LDS). V comes from the
//     pre-transposed vt via [d][kv] swizzled LDS; kv-permutation sigma shared
//     by in-register P pack and the two ds_read_b64 V reads.
//     K/V global loads issued one tile ahead (reg-staged).  12KB LDS.
// ---------------------------------------------------------------------------
__global__ __launch_bounds__(256) void k_attn(const short* __restrict__ qkv,
                                              const short* __restrict__ vt,
                                              short* __restrict__ o) {
  __shared__ short Ks[64 * 48];   // [kv][d] rows 96B, XOR-swizzled
  __shared__ short Vs[48 * 64];   // [d][kv] rows 128B, XOR-swizzled
  const int f = blockIdx.x;
  const int xslot = f & 7, grp = f >> 3;
  const int bh = xslot + 8 * (grp & 15);
  const int qt = grp >> 4;                 // 0..12
  const int b = bh >> 3, h = bh & 7;
  const int q0 = qt * 64;
  const int t = threadIdx.x, w = t >> 6, l = t & 63, g = l >> 4, li = l & 15;
  const size_t bbase = (size_t)b * CN;

  // Q fragment (B-operand): col=li -> q = q0+w*16+li ; k=g*8+i -> d
  const int qrow = q0 + w * 16 + li;
  const int qr = qrow > CN - 1 ? CN - 1 : qrow;
  const short* qb = qkv + (bbase + qr) * C3 + h * CD;
  bf16x8 qf0 = *(const bf16x8*)(qb + g * 8);
  bf16x8 qf1 = {};
  if (g < 2) qf1 = *(const bf16x8*)(qb + 32 + g * 8);

  float mr = -1e30f, ls = 0.f;
  f32x4 oa[3] = {};
  const float scale = 0.14433756729740643f; // 1/sqrt(48)

  // staging split: 384 granules each (K: row*6+cg ; V: d*8+kvg); thread t and t+256
  const int krow0 = t / 6, kcg0 = t % 6;
  const int krow1 = (t + 256) / 6, kcg1 = (t + 256) % 6;   // valid when t<128
  const int vd0 = t >> 3, vkvg0 = t & 7;
  const int vd1 = (t + 256) >> 3, vkvg1 = (t + 256) & 7;   // valid when t<128
  const short* kbase = qkv + bbase * C3 + CC + h * CD;
  const short* vbase = vt + (size_t)bh * CD * NP;

  bf16x8 kr0 = {}, kr1 = {}, vr0 = {}, vr1 = {};
  kr0 = *(const bf16x8*)(kbase + (size_t)min(krow0, CN - 1) * C3 + kcg0 * 8);
  vr0 = *(const bf16x8*)(vbase + vd0 * NP + vkvg0 * 8);
  if (t < 128) {
    kr1 = *(const bf16x8*)(kbase + (size_t)min(krow1, CN - 1) * C3 + kcg1 * 8);
    vr1 = *(const bf16x8*)(vbase + vd1 * NP + vkvg1 * 8);
  }

  for (int kt = 0; kt < 13; kt++) {
    const int kv0 = kt * 64;
    __syncthreads();   // previous compute done; LDS free
    *(bf16x8*)((char*)Ks + ((krow0 * 96 + kcg0 * 16) ^ ((krow0 & 7) << 4))) = kr0;
    *(bf16x8*)((char*)Vs + ((vd0 * 128 + vkvg0 * 16) ^ ((vd0 & 7) << 4))) = vr0;
    if (t < 128) {
      *(bf16x8*)((char*)Ks + ((krow1 * 96 + kcg1 * 16) ^ ((krow1 & 7) << 4))) = kr1;
      *(bf16x8*)((char*)Vs + ((vd1 * 128 + vkvg1 * 16) ^ ((vd1 & 7) << 4))) = vr1;
    }
    __syncthreads();   // LDS ready
    if (kt < 12) {     // issue next-tile loads early; latency hides under MFMA
      const int kn = kv0 + 64;
      kr0 = *(const bf16x8*)(kbase + (size_t)min(kn + krow0, CN - 1) * C3 + kcg0 * 8);
      vr0 = *(const bf16x8*)(vbase + vd0 * NP + kn + vkvg0 * 8);
      if (t < 128) {
        kr1 = *(const bf16x8*)(kbase + (size_t)min(kn + krow1, CN - 1) * C3 + kcg1 * 8);
        vr1 = *(const bf16x8*)(vbase + vd1 * NP + kn + vkvg1 * 8);
      }
    }

    // ---- S = K Q^T : lane (g,li): s[ni][r] = S[kv=kv0+ni*16+g*4+r][q=qrow]
    f32x4 s[4];
    __builtin_amdgcn_s_setprio(1);
#pragma unroll
    for (int ni = 0; ni < 4; ni++) {
      const int krw = ni * 16 + li;
      const int sw = (krw & 7) << 4;
      bf16x8 kf0 = *(const bf16x8*)((char*)Ks + ((krw * 96 + g * 16) ^ sw));
      bf16x8 kf1 = {};
      if (g < 2) kf1 = *(const bf16x8*)((char*)Ks + ((krw * 96 + 64 + g * 16) ^ sw));
      f32x4 acc = {};
      acc = __builtin_amdgcn_mfma_f32_16x16x32_bf16(kf0, qf0, acc, 0, 0, 0);
      acc = __builtin_amdgcn_mfma_f32_16x16x32_bf16(kf1, qf1, acc, 0, 0, 0);
      s[ni] = acc;
    }
    __builtin_amdgcn_s_setprio(0);

    // ---- online softmax: one q per lane; reduce across g via 2 shfl_xor
    float mt = -1e30f;
#pragma unroll
    for (int ni = 0; ni < 4; ni++)
#pragma unroll
      for (int r = 0; r < 4; r++) {
        const int kva = kv0 + ni * 16 + g * 4 + r;
        const float v = (kva < CN) ? s[ni][r] * scale : -1e30f;
        s[ni][r] = v;
        mt = fmaxf(mt, v);
      }
    mt = fmaxf(mt, __shfl_xor(mt, 16));
    mt = fmaxf(mt, __shfl_xor(mt, 32));
    const float mn = fmaxf(mr, mt);
    const float al = __expf(mr - mn);
    mr = mn;
    float ps = 0.f;
#pragma unroll
    for (int ni = 0; ni < 4; ni++)
#pragma unroll
      for (int r = 0; r < 4; r++) {
        const float p = __expf(s[ni][r] - mn);
        s[ni][r] = p;
        ps += p;
      }
    ps += __shfl_xor(ps, 16);
    ps += __shfl_xor(ps, 32);
    ls = ls * al + ps;

    // rescale O: need al at q = g*4+r -> shfl from lane (same group, li=g*4+r)
    const int sb = (l & 48) + ((l & 48) >> 2);
    float ar[4];
#pragma unroll
    for (int r = 0; r < 4; r++) ar[r] = __shfl(al, sb + r);
#pragma unroll
    for (int d = 0; d < 3; d++)
#pragma unroll
      for (int r = 0; r < 4; r++) oa[d][r] *= ar[r];

    // ---- pack P in-register per sigma: k=g*8+i -> kv = ks*32 + (i<4 ? g*4+i : 16+g*4+i-4)
    bf16x8 pa[2];
#pragma unroll
    for (int ks = 0; ks < 2; ks++)
#pragma unroll
      for (int i = 0; i < 8; i++)
        pa[ks][i] = f2b(i < 4 ? s[2 * ks][i] : s[2 * ks + 1][i - 4]);

    // ---- O += P V : V B-frag via two ds_read_b64 per chunk (same sigma)
    __builtin_amdgcn_s_setprio(1);
#pragma unroll
    for (int d = 0; d < 3; d++) {
      const int drow = d * 16 + li;
      const int sw = (drow & 7) << 4;
#pragma unroll
      for (int ks = 0; ks < 2; ks++) {
        bf16x4 lo = *(const bf16x4*)((char*)Vs + ((drow * 128 + ks * 64 + g * 8) ^ sw));
        bf16x4 hi = *(const bf16x4*)((char*)Vs + ((drow * 128 + ks * 64 + 32 + g * 8) ^ sw));
        bf16x8 vb;
#pragma unroll
        for (int i = 0; i < 4; i++) { vb[i] = lo[i]; vb[4 + i] = hi[i]; }
        oa[d] = __builtin_amdgcn_mfma_f32_16x16x32_bf16(pa[ks], vb, oa[d], 0, 0, 0);
      }
    }
    __builtin_amdgcn_s_setprio(0);
  }

  // epilogue: O[q=g*4+r][d=dblk*16+li]; ls lives at lane li=q -> shfl
  const int sb = (l & 48) + ((l & 48) >> 2);
  float lr[4];
#pragma unroll
  for (int r = 0; r < 4; r++) lr[r] = __shfl(ls, sb + r);
#pragma unroll
  for (int d = 0; d < 3; d++)
#pragma unroll
    for (int r = 0; r < 4; r++) {
      const int n = q0 + w * 16 + g * 4 + r;
      if (n < CN)
        o[(bbase + n) * CC + h * CD + d * 16 + li] = f2b(oa[d][r] / lr[r]);
    }
}

// ---------------------------------------------------------------------------
// K5: global_attn = mean over heads of softmax(q0 . k)[1:]. grid = B*H blocks.
// ---------------------------------------------------------------------------
__global__ __launch_bounds__(256) void k_gattn(const short* __restrict__ qkv,
                                               float* __restrict__ ga) {
  const int b = blockIdx.x >> 3, h = blockIdx.x & 7;
  __shared__ float red[4];
  const int t = threadIdx.x;
  const size_t bbase = (size_t)b * CN;
  const short* q0 = qkv + bbase * C3 + h * CD;
  float qv[CD];
#pragma unroll
  for (int i = 0; i < CD; i++) qv[i] = b2f(q0[i]);
  float lg[4], ev[4];
  float lmax = -1e30f;
#pragma unroll
  for (int j = 0; j < 4; j++) {
    const int m = t + j * 256;
    if (m < CN) {
      const short* kr = qkv + (bbase + m) * C3 + CC + h * CD;
      float acc = 0.f;
#pragma unroll
      for (int i = 0; i < CD; i++) acc += qv[i] * b2f(kr[i]);
      lg[j] = acc * 0.14433756729740643f;
      lmax = fmaxf(lmax, lg[j]);
    } else lg[j] = -1e30f;
  }
  for (int msk = 1; msk < 64; msk <<= 1) lmax = fmaxf(lmax, __shfl_xor(lmax, msk));
  if ((t & 63) == 0) red[t >> 6] = lmax;
  __syncthreads();
  lmax = fmaxf(fmaxf(red[0], red[1]), fmaxf(red[2], red[3]));
  __syncthreads();
  float es = 0.f;
#pragma unroll
  for (int j = 0; j < 4; j++) {
    ev[j] = (t + j * 256 < CN) ? __expf(lg[j] - lmax) : 0.f;
    es += ev[j];
  }
  for (int msk = 1; msk < 64; msk <<= 1) es += __shfl_xor(es, msk);
  if ((t & 63) == 0) red[t >> 6] = es;
  __syncthreads();
  es = red[0] + red[1] + red[2] + red[3];
  const float inv = 0.125f / es;
#pragma unroll
  for (int j = 0; j < 4; j++) {
    const int m = t + j * 256;
    if (m >= 1 && m < CN) atomicAdd(&ga[b * HW + m - 1], ev[j] * inv);
  }
}

// ---------------------------------------------------------------------------
// K6: output: x_out via LDS-tiled transpose (both sides coalesced) + cls_out
// ---------------------------------------------------------------------------
__global__ __launch_bounds__(256) void k_out(const float* __restrict__ xc,
                                             float* __restrict__ outp) {
  const int b = blockIdx.y, tile = blockIdx.x, t = threadIdx.x;
  if (tile == 78) {
    for (int i = t; i < CC; i += 256)
      outp[b * CC + i] = xc[((size_t)b * CN) * CC + i];
    return;
  }
  __shared__ float T[64][65];
  const int ct = tile / 13, ht = tile % 13;
  const int c0 = ct * 64, hw0 = ht * 64;
  const int ci = t & 63, hb = t >> 6;
  for (int j = 0; j < 16; j++) {
    const int hwl = hb + j * 4;
    if (hw0 + hwl < HW)
      T[ci][hwl] = xc[((size_t)b * CN + 1 + hw0 + hwl) * CC + c0 + ci];
  }
  __syncthreads();
  const int hi = t & 63, cb2 = t >> 6;
  float* xo = outp + CB * CC;
  for (int j = 0; j < 16; j++) {
    const int cl = cb2 + j * 4;
    if (hw0 + hi < HW)
      xo[((size_t)(b * CC + c0 + cl)) * HW + hw0 + hi] = T[cl][hi];
  }
}

// ---------------------------------------------------------------------------
extern "C" void kernel_launch(void* const* d_in, const int* in_sizes, int n_in,
                              void* d_out, int out_size, void* d_ws, size_t ws_size,
                              hipStream_t stream) {
  const float* cls    = (const float*)d_in[0];
  const float* x      = (const float*)d_in[1];
  const float* conv_w = (const float*)d_in[2];
  const float* conv_b = (const float*)d_in[3];
  const float* ln1_g  = (const float*)d_in[4];
  const float* ln1_b  = (const float*)d_in[5];
  const float* qkv_w  = (const float*)d_in[6];
  const float* proj_w = (const float*)d_in[7];
  const float* proj_b = (const float*)d_in[8];
  const float* ln2_g  = (const float*)d_in[9];
  const float* ln2_b  = (const float*)d_in[10];
  const float* fc1_w  = (const float*)d_in[11];
  const float* fc1_b  = (const float*)d_in[12];
  const float* fc2_w  = (const float*)d_in[13];
  const float* fc2_b  = (const float*)d_in[14];

  float* outf = (float*)d_out;
  float* ga = outf + (size_t)CB * CC + (size_t)CB * CC * HW;
  // vt scratch lives in the (not-yet-written) x_out region of d_out:
  // floats [6144, 6144+2,457,600) — disjoint from cls (0..6144) and ga (4,823,040..)
  short* vtb = (short*)(outf + CB * CC);

  char* ws = (char*)d_ws;
  float* xc   = (float*)ws;
  short* y    = (short*)(ws + 19292160ULL);
  short* qkvb = (short*)(ws + 28938240ULL);
  short* o    = (short*)(ws + 57876480ULL);
  short* m1   = (short*)(ws + 28938240ULL);
  short* wbuf = (short*)(ws + 67522560ULL);
  short* qkv_wb = wbuf;
  short* proj_wb = wbuf + 442368;
  short* fc1_wb  = wbuf + 589824;
  short* fc2_wb  = wbuf + 1179648;

  const int thr = 256;
  k_misc<<<49, thr, 0, stream>>>(cls, xc, ga);
  k_wconv<<<1728, thr, 0, stream>>>(qkv_w, proj_w, fc1_w, fc2_w, wbuf);
  k_conv_t<<<dim3(13, 6, CB), thr, 0, stream>>>(x, conv_w, conv_b, xc);
  k_ln<<<CM / 4, thr, 0, stream>>>(xc, ln1_g, ln1_b, y, CM);
  k_gemm<128, 0, 0, 0, 1><<<dim3(99, C3 / 128), thr, 0, stream>>>(
      y, qkv_wb, nullptr, nullptr, qkvb, CM, C3, CC);
  k_vt<<<dim3(13, CB * 8), thr, 0, stream>>>(qkvb, vtb);
  k_attn<<<1664, thr, 0, stream>>>(qkvb, vtb, o);
  k_gattn<<<CB * 8, thr, 0, stream>>>(qkvb, ga);
  k_gemm<64, 0, 1, 1, 0><<<dim3(197, CC / 128), thr, 0, stream>>>(
      o, proj_wb, proj_b, xc, xc, CM, CC, CC);
  k_ln<<<CM / 4, thr, 0, stream>>>(xc, ln2_g, ln2_b, y, CM);
  k_gemm<128, 1, 0, 1, 1><<<dim3(99, CF / 128), thr, 0, stream>>>(
      y, fc1_wb, fc1_b, nullptr, m1, CM, CF, CC);
  k_gemm<64, 0, 1, 1, 0><<<dim3(197, CC / 128), thr, 0, stream>>>(
      m1, fc2_wb, fc2_b, xc, xc, CM, CC, CF);
  k_out<<<dim3(79, CB), thr, 0, stream>>>(xc, outf);
}

// Round 10
// 351.016 us; speedup vs baseline: 2.1654x; 1.0547x over previous
//
#include <hip/hip_runtime.h>
#include <hip/hip_bf16.h>

#define DI __device__ __forceinline__

typedef __attribute__((ext_vector_type(4))) float f32x4;
typedef __attribute__((ext_vector_type(8))) short bf16x8;
typedef __attribute__((ext_vector_type(4))) short bf16x4;

static constexpr int CB = 16;        // batch
static constexpr int CC = 384;       // channels
static constexpr int CH = 28, CW = 28;
static constexpr int CD = 48;        // head dim
static constexpr int CN = 785;       // 1 + 28*28
static constexpr int CM = CB * CN;   // 12560 rows
static constexpr int C3 = 3 * CC;    // 1152
static constexpr int CF = 4 * CC;    // 1536
static constexpr int HW = CH * CW;   // 784
static constexpr int NP = 832;       // padded seq for vt

DI short f2b(float f) {
  __hip_bfloat16 h = __float2bfloat16(f);
  return *reinterpret_cast<short*>(&h);
}
DI float b2f(short s) {
  union { unsigned u; float f; } x;
  x.u = ((unsigned)(unsigned short)s) << 16;
  return x.f;
}

DI void gload16(const short* g, short* l) {
  __builtin_amdgcn_global_load_lds((const __attribute__((address_space(1))) void*)g,
                                   (__attribute__((address_space(3))) void*)l, 16, 0, 0);
}

// ---------------------------------------------------------------------------
// K0: zero global_attn, write cls row of xc
// ---------------------------------------------------------------------------
__global__ void k_misc(const float* __restrict__ cls, float* __restrict__ xc,
                       float* __restrict__ ga) {
  const int gid = blockIdx.x * 256 + threadIdx.x;
  if (gid < CB * HW) ga[gid] = 0.f;
  if (gid < CB * CC) {
    const int b = gid / CC, c = gid % CC;
    xc[((size_t)b * CN) * CC + c] = cls[gid];
  }
}

// ---------------------------------------------------------------------------
// K0b: convert the four weight matrices fp32 -> bf16 (contiguous in wbuf)
// ---------------------------------------------------------------------------
__global__ void k_wconv(const float* __restrict__ s0, const float* __restrict__ s1,
                        const float* __restrict__ s2, const float* __restrict__ s3,
                        short* __restrict__ dst) {
  const int gid = (blockIdx.x * 256 + threadIdx.x) * 4;
  if (gid >= 1769472) return;
  const float* s; int off;
  if (gid < 442368)       { s = s0; off = gid; }
  else if (gid < 589824)  { s = s1; off = gid - 442368; }
  else if (gid < 1179648) { s = s2; off = gid - 589824; }
  else                    { s = s3; off = gid - 1179648; }
  f32x4 v = *(const f32x4*)(s + off);
  bf16x4 o;
#pragma unroll
  for (int i = 0; i < 4; i++) o[i] = f2b(v[i]);
  *(bf16x4*)(dst + gid) = o;
}

// ---------------------------------------------------------------------------
// K1: depthwise conv3x3 + residual, coalesced along hw, LDS-transposed write.
//     ILP rewrite: branchless taps (clamped addr + x0 mask), loads batched
//     per channel-pair ahead of FMAs (prev: VGPR=12, serialized loads, 59us).
// ---------------------------------------------------------------------------
__global__ __launch_bounds__(256) void k_conv_t(const float* __restrict__ x,
                                                const float* __restrict__ cw,
                                                const float* __restrict__ cb,
                                                float* __restrict__ xc) {
  __shared__ float T[64][65];
  __shared__ float Wc[64 * 9];
  __shared__ float Cbs[64];
  const int b = blockIdx.z;
  const int cc = blockIdx.y * 64;
  const int hw0 = blockIdx.x * 64;
  const int t = threadIdx.x;
  const int hwi = t & 63, ci0 = t >> 6;
  const int hw = hw0 + hwi;
  const int yy = hw / CW, xx = hw % CW;
  const int ci2 = t & 63, hb2 = t >> 6;

  for (int i = t; i < 64 * 9; i += 256) Wc[i] = cw[cc * 9 + i];
  if (t < 64) Cbs[t] = cb[cc + t];
  __syncthreads();
  if (hw < HW) {
    const int ctr = yy * CW + xx;
    int off9[9]; float mk9[9];
#pragma unroll
    for (int ky = 0; ky < 3; ky++)
#pragma unroll
      for (int kx = 0; kx < 3; kx++) {
        const int iy = yy + ky - 1, ix = xx + kx - 1;
        const bool v = (iy >= 0 && iy < CH && ix >= 0 && ix < CW);
        off9[ky * 3 + kx] = v ? iy * CW + ix : ctr;
        mk9[ky * 3 + kx] = v ? 1.f : 0.f;
      }
#pragma unroll
    for (int j = 0; j < 16; j += 2) {
      const int cl0 = ci0 * 16 + j;
      const float* xp0 = x + ((size_t)(b * CC + cc + cl0)) * HW;
      const float* xp1 = xp0 + HW;
      float t0[9], t1[9];
#pragma unroll
      for (int q = 0; q < 9; q++) { t0[q] = xp0[off9[q]]; t1[q] = xp1[off9[q]]; }
      const float c0 = xp0[ctr], c1 = xp1[ctr];
      float a0 = Cbs[cl0], a1 = Cbs[cl0 + 1];
#pragma unroll
      for (int q = 0; q < 9; q++) {
        a0 += Wc[cl0 * 9 + q] * (t0[q] * mk9[q]);
        a1 += Wc[(cl0 + 1) * 9 + q] * (t1[q] * mk9[q]);
      }
      T[cl0][hwi] = c0 + a0;
      T[cl0 + 1][hwi] = c1 + a1;
    }
  }
  __syncthreads();
#pragma unroll
  for (int j = 0; j < 16; j++) {
    const int hwl = hb2 + j * 4;
    if (hw0 + hwl < HW)
      xc[((size_t)b * CN + 1 + hw0 + hwl) * CC + cc + ci2] = T[ci2][hwl];
  }
}

// ---------------------------------------------------------------------------
// K2: LayerNorm over last dim (384), fp32 in -> bf16 out. 1 wave per row.
// ---------------------------------------------------------------------------
__global__ __launch_bounds__(256) void k_ln(const float* __restrict__ xin,
                                            const float* __restrict__ g,
                                            const float* __restrict__ bta,
                                            short* __restrict__ y, int Mtot) {
  const int row = blockIdx.x * 4 + (threadIdx.x >> 6);
  const int l = threadIdx.x & 63;
  if (row >= Mtot) return;
  const float* xr = xin + (size_t)row * CC;
  float v[6], s = 0.f, ss = 0.f;
#pragma unroll
  for (int i = 0; i < 6; i++) {
    v[i] = xr[l + i * 64];
    s += v[i];
    ss += v[i] * v[i];
  }
#pragma unroll
  for (int m = 1; m < 64; m <<= 1) { s += __shfl_xor(s, m); ss += __shfl_xor(ss, m); }
  const float mu = s * (1.f / CC);
  const float var = ss * (1.f / CC) - mu * mu;
  const float r = rsqrtf(var + 1e-5f);
#pragma unroll
  for (int i = 0; i < 6; i++) {
    const int c = l + i * 64;
    y[(size_t)row * CC + c] = f2b((v[i] - mu) * r * g[c] + bta[c]);
  }
}

// ---------------------------------------------------------------------------
// K3: GEMM  C[M,N] = A[M,K] @ W[N,K]^T (+bias)(+gelu)(+resid)
//     3-buffer depth-2 pipeline with counted vmcnt (T4): stage(k+2) issued,
//     s_waitcnt vmcnt(2S) keeps 2 younger stages in flight (never drains),
//     raw s_barrier pair per K-step. S = loads/stage = BM/64 + 2.
// ---------------------------------------------------------------------------
template <int BM, int DOGELU, int DORES, int DOBIAS, int OUTBF>
__global__ __launch_bounds__(256) void k_gemm(const short* __restrict__ A,
                                              const short* __restrict__ W,
                                              const float* __restrict__ bias,
                                              const float* __restrict__ resid,
                                              void* __restrict__ out_,
                                              int M, int N, int K) {
  constexpr int MI = BM / 32;       // acc row-frags per wave (4 or 2)
  constexpr int ACALLS = BM / 64;   // A staging calls per thread (2 or 1)
  constexpr int ASZ = BM * 32, BSZ = 128 * 32;
  __shared__ short As[3 * ASZ];
  __shared__ short Bs[3 * BSZ];
  const int bm = blockIdx.x * BM, bn = blockIdx.y * 128;
  const int t = threadIdx.x, w = t >> 6, l = t & 63, g = l >> 4, li = l & 15;
  const int wm = (w >> 1) * (BM / 2), wn = (w & 1) * 64;

  const int srow = l >> 2;          // row within 16-row staging group
  const int scol = (l & 3) * 8;     // col offset (16B granules)
  const short* aSrc[ACALLS]; int aOff[ACALLS];
#pragma unroll
  for (int j = 0; j < ACALLS; j++) {
    int arow = bm + w * (BM / 4) + j * 16 + srow; if (arow > M - 1) arow = M - 1;
    aSrc[j] = A + (size_t)arow * K + scol;
    aOff[j] = (w * (BM / 4) + j * 16) * 32;
  }
  const short* bSrc[2]; int bOff[2];
#pragma unroll
  for (int j = 0; j < 2; j++) {
    const int brow = bn + w * 32 + j * 16 + srow;
    bSrc[j] = W + (size_t)brow * K + scol;
    bOff[j] = (w * 32 + j * 16) * 32;
  }

  auto stage = [&](int buf, int kt) {
    const int ko = kt * 32;
#pragma unroll
    for (int j = 0; j < ACALLS; j++)
      gload16(aSrc[j] + ko, &As[buf * ASZ] + aOff[j]);
#pragma unroll
    for (int j = 0; j < 2; j++)
      gload16(bSrc[j] + ko, &Bs[buf * BSZ] + bOff[j]);
  };

  f32x4 acc[MI][4] = {};
  const int nkt = K / 32;           // >= 12 always
  stage(0, 0);
  stage(1, 1);
  int cur = 0;
  for (int kt = 0; kt < nkt; kt++) {
    if (kt + 2 < nkt) {
      int nb = cur + 2; if (nb >= 3) nb -= 3;
      stage(nb, kt + 2);
      // wait oldest stage (k) done; keep k+1,k+2 in flight
      if constexpr (BM == 128) asm volatile("s_waitcnt vmcnt(8)" ::: "memory");
      else                     asm volatile("s_waitcnt vmcnt(6)" ::: "memory");
    } else if (kt + 2 == nkt) {
      if constexpr (BM == 128) asm volatile("s_waitcnt vmcnt(4)" ::: "memory");
      else                     asm volatile("s_waitcnt vmcnt(3)" ::: "memory");
    } else {
      asm volatile("s_waitcnt vmcnt(0)" ::: "memory");
    }
    __builtin_amdgcn_sched_barrier(0);
    __builtin_amdgcn_s_barrier();          // all waves' stage-k loads landed

    const short* Ab = &As[cur * ASZ];
    const short* Bb = &Bs[cur * BSZ];
    bf16x8 af[MI], bf[4];
#pragma unroll
    for (int mi = 0; mi < MI; mi++)
      af[mi] = *(const bf16x8*)&Ab[(wm + mi * 16 + li) * 32 + g * 8];
#pragma unroll
    for (int ni = 0; ni < 4; ni++)
      bf[ni] = *(const bf16x8*)&Bb[(wn + ni * 16 + li) * 32 + g * 8];
#pragma unroll
    for (int mi = 0; mi < MI; mi++)
#pragma unroll
      for (int ni = 0; ni < 4; ni++)
        acc[mi][ni] = __builtin_amdgcn_mfma_f32_16x16x32_bf16(af[mi], bf[ni], acc[mi][ni], 0, 0, 0);

    asm volatile("s_waitcnt lgkmcnt(0)" ::: "memory");
    __builtin_amdgcn_sched_barrier(0);
    __builtin_amdgcn_s_barrier();          // readers done; buf reusable
    cur = (cur == 2) ? 0 : cur + 1;
  }

#pragma unroll
  for (int mi = 0; mi < MI; mi++)
#pragma unroll
    for (int ni = 0; ni < 4; ni++) {
      const int col = bn + wn + ni * 16 + li;
      float bv = 0.f;
      if constexpr (DOBIAS) bv = bias[col];
#pragma unroll
      for (int r = 0; r < 4; r++) {
        const int row = bm + wm + mi * 16 + g * 4 + r;
        if (row < M) {
          float v = acc[mi][ni][r] + bv;
          if constexpr (DOGELU) v = 0.5f * v * (1.f + erff(v * 0.7071067811865475f));
          if constexpr (DORES) v += resid[(size_t)row * N + col];
          if constexpr (OUTBF)
            ((short*)out_)[(size_t)row * N + col] = f2b(v);
          else
            ((float*)out_)[(size_t)row * N + col] = v;
        }
      }
    }
}

// ---------------------------------------------------------------------------
// K3b: pre-transpose V: qkvb[b][n][768 + h*48 + d] -> vt[bh][d][NP=832]
//      (zero-pad n>=785).  grid (13 n-tiles, 128 bh).
// ---------------------------------------------------------------------------
__global__ __launch_bounds__(256) void k_vt(const short* __restrict__ qkv,
                                            short* __restrict__ vt) {
  __shared__ short Tl[48 * 71];   // [d][n] stride 71 (142B) to spread banks
  const int n0 = blockIdx.x * 64;
  const int bh = blockIdx.y;
  const int b = bh >> 3, h = bh & 7;
  const int t = threadIdx.x;
  const size_t bbase = (size_t)b * CN;
#pragma unroll
  for (int it = 0; it < 2; it++) {
    const int gi = t + it * 256;
    if (gi < 384) {
      const int nrel = gi / 6, dg = gi % 6;
      const int n = n0 + nrel;
      bf16x8 val = {};
      if (n < CN)
        val = *(const bf16x8*)(qkv + (bbase + n) * C3 + 2 * CC + h * CD + dg * 8);
#pragma unroll
      for (int i = 0; i < 8; i++) Tl[(dg * 8 + i) * 71 + nrel] = val[i];
    }
  }
  __syncthreads();
#pragma unroll
  for (int it = 0; it < 2; it++) {
    const int gj = t + it * 256;
    if (gj < 384) {
      const int d = gj >> 3, ng = gj & 7;
      bf16x8 v;
#pragma unroll
      for (int i = 0; i < 8; i++) v[i] = Tl[d * 71 + ng * 8 + i];
      *(bf16x8*)(vt + ((size_t)bh * CD + d) * NP + n0 + ng * 8) = v;
    }
  }
}

// ---------------------------------------------------------------------------
// K4: flash attention v2 — swapped QK^T (mfma(K,Q)): each lane owns one q-row,
//     softmax = 2 shfl_xor, P stays in registers (no P LDS). V comes from the
//     pre-transposed vt via [d][kv] swizzled LDS; kv-permutation sigma shared
//     by in-register P pack and the two ds_read_b64 V reads.
//     K/V global loads issued one tile ahead (reg-staged).  12KB LDS.
// ---------------------------------------------------------------------------
__global__ __launch_bounds__(256) void k_attn(const short* __restrict__ qkv,
                                              const short* __restrict__ vt,
                                              short* __restrict__ o) {
  __shared__ short Ks[64 * 48];   // [kv][d] rows 96B, XOR-swizzled
  __shared__ short Vs[48 * 64];   // [d][kv] rows 128B, XOR-swizzled
  const int f = blockIdx.x;
  const int xslot = f & 7, grp = f >> 3;
  const int bh = xslot + 8 * (grp & 15);
  const int qt = grp >> 4;                 // 0..12
  const int b = bh >> 3, h = bh & 7;
  const int q0 = qt * 64;
  const int t = threadIdx.x, w = t >> 6, l = t & 63, g = l >> 4, li = l & 15;
  const size_t bbase = (size_t)b * CN;

  // Q fragment (B-operand): col=li -> q = q0+w*16+li ; k=g*8+i -> d
  const int qrow = q0 + w * 16 + li;
  const int qr = qrow > CN - 1 ? CN - 1 : qrow;
  const short* qb = qkv + (bbase + qr) * C3 + h * CD;
  bf16x8 qf0 = *(const bf16x8*)(qb + g * 8);
  bf16x8 qf1 = {};
  if (g < 2) qf1 = *(const bf16x8*)(qb + 32 + g * 8);

  float mr = -1e30f, ls = 0.f;
  f32x4 oa[3] = {};
  const float scale = 0.14433756729740643f; // 1/sqrt(48)

  // staging split: 384 granules each (K: row*6+cg ; V: d*8+kvg); thread t and t+256
  const int krow0 = t / 6, kcg0 = t % 6;
  const int krow1 = (t + 256) / 6, kcg1 = (t + 256) % 6;   // valid when t<128
  const int vd0 = t >> 3, vkvg0 = t & 7;
  const int vd1 = (t + 256) >> 3, vkvg1 = (t + 256) & 7;   // valid when t<128
  const short* kbase = qkv + bbase * C3 + CC + h * CD;
  const short* vbase = vt + (size_t)bh * CD * NP;

  bf16x8 kr0 = {}, kr1 = {}, vr0 = {}, vr1 = {};
  kr0 = *(const bf16x8*)(kbase + (size_t)min(krow0, CN - 1) * C3 + kcg0 * 8);
  vr0 = *(const bf16x8*)(vbase + vd0 * NP + vkvg0 * 8);
  if (t < 128) {
    kr1 = *(const bf16x8*)(kbase + (size_t)min(krow1, CN - 1) * C3 + kcg1 * 8);
    vr1 = *(const bf16x8*)(vbase + vd1 * NP + vkvg1 * 8);
  }

  for (int kt = 0; kt < 13; kt++) {
    const int kv0 = kt * 64;
    __syncthreads();   // previous compute done; LDS free
    *(bf16x8*)((char*)Ks + ((krow0 * 96 + kcg0 * 16) ^ ((krow0 & 7) << 4))) = kr0;
    *(bf16x8*)((char*)Vs + ((vd0 * 128 + vkvg0 * 16) ^ ((vd0 & 7) << 4))) = vr0;
    if (t < 128) {
      *(bf16x8*)((char*)Ks + ((krow1 * 96 + kcg1 * 16) ^ ((krow1 & 7) << 4))) = kr1;
      *(bf16x8*)((char*)Vs + ((vd1 * 128 + vkvg1 * 16) ^ ((vd1 & 7) << 4))) = vr1;
    }
    __syncthreads();   // LDS ready
    if (kt < 12) {     // issue next-tile loads early; latency hides under MFMA
      const int kn = kv0 + 64;
      kr0 = *(const bf16x8*)(kbase + (size_t)min(kn + krow0, CN - 1) * C3 + kcg0 * 8);
      vr0 = *(const bf16x8*)(vbase + vd0 * NP + kn + vkvg0 * 8);
      if (t < 128) {
        kr1 = *(const bf16x8*)(kbase + (size_t)min(kn + krow1, CN - 1) * C3 + kcg1 * 8);
        vr1 = *(const bf16x8*)(vbase + vd1 * NP + kn + vkvg1 * 8);
      }
    }

    // ---- S = K Q^T : lane (g,li): s[ni][r] = S[kv=kv0+ni*16+g*4+r][q=qrow]
    f32x4 s[4];
    __builtin_amdgcn_s_setprio(1);
#pragma unroll
    for (int ni = 0; ni < 4; ni++) {
      const int krw = ni * 16 + li;
      const int sw = (krw & 7) << 4;
      bf16x8 kf0 = *(const bf16x8*)((char*)Ks + ((krw * 96 + g * 16) ^ sw));
      bf16x8 kf1 = {};
      if (g < 2) kf1 = *(const bf16x8*)((char*)Ks + ((krw * 96 + 64 + g * 16) ^ sw));
      f32x4 acc = {};
      acc = __builtin_amdgcn_mfma_f32_16x16x32_bf16(kf0, qf0, acc, 0, 0, 0);
      acc = __builtin_amdgcn_mfma_f32_16x16x32_bf16(kf1, qf1, acc, 0, 0, 0);
      s[ni] = acc;
    }
    __builtin_amdgcn_s_setprio(0);

    // ---- online softmax: one q per lane; reduce across g via 2 shfl_xor
    float mt = -1e30f;
#pragma unroll
    for (int ni = 0; ni < 4; ni++)
#pragma unroll
      for (int r = 0; r < 4; r++) {
        const int kva = kv0 + ni * 16 + g * 4 + r;
        const float v = (kva < CN) ? s[ni][r] * scale : -1e30f;
        s[ni][r] = v;
        mt = fmaxf(mt, v);
      }
    mt = fmaxf(mt, __shfl_xor(mt, 16));
    mt = fmaxf(mt, __shfl_xor(mt, 32));
    const float mn = fmaxf(mr, mt);
    const float al = __expf(mr - mn);
    mr = mn;
    float ps = 0.f;
#pragma unroll
    for (int ni = 0; ni < 4; ni++)
#pragma unroll
      for (int r = 0; r < 4; r++) {
        const float p = __expf(s[ni][r] - mn);
        s[ni][r] = p;
        ps += p;
      }
    ps += __shfl_xor(ps, 16);
    ps += __shfl_xor(ps, 32);
    ls = ls * al + ps;

    // rescale O: need al at q = g*4+r -> shfl from lane (same group, li=g*4+r)
    const int sb = (l & 48) + ((l & 48) >> 2);
    float ar[4];
#pragma unroll
    for (int r = 0; r < 4; r++) ar[r] = __shfl(al, sb + r);
#pragma unroll
    for (int d = 0; d < 3; d++)
#pragma unroll
      for (int r = 0; r < 4; r++) oa[d][r] *= ar[r];

    // ---- pack P in-register per sigma: k=g*8+i -> kv = ks*32 + (i<4 ? g*4+i : 16+g*4+i-4)
    bf16x8 pa[2];
#pragma unroll
    for (int ks = 0; ks < 2; ks++)
#pragma unroll
      for (int i = 0; i < 8; i++)
        pa[ks][i] = f2b(i < 4 ? s[2 * ks][i] : s[2 * ks + 1][i - 4]);

    // ---- O += P V : V B-frag via two ds_read_b64 per chunk (same sigma)
    __builtin_amdgcn_s_setprio(1);
#pragma unroll
    for (int d = 0; d < 3; d++) {
      const int drow = d * 16 + li;
      const int sw = (drow & 7) << 4;
#pragma unroll
      for (int ks = 0; ks < 2; ks++) {
        bf16x4 lo = *(const bf16x4*)((char*)Vs + ((drow * 128 + ks * 64 + g * 8) ^ sw));
        bf16x4 hi = *(const bf16x4*)((char*)Vs + ((drow * 128 + ks * 64 + 32 + g * 8) ^ sw));
        bf16x8 vb;
#pragma unroll
        for (int i = 0; i < 4; i++) { vb[i] = lo[i]; vb[4 + i] = hi[i]; }
        oa[d] = __builtin_amdgcn_mfma_f32_16x16x32_bf16(pa[ks], vb, oa[d], 0, 0, 0);
      }
    }
    __builtin_amdgcn_s_setprio(0);
  }

  // epilogue: O[q=g*4+r][d=dblk*16+li]; ls lives at lane li=q -> shfl
  const int sb = (l & 48) + ((l & 48) >> 2);
  float lr[4];
#pragma unroll
  for (int r = 0; r < 4; r++) lr[r] = __shfl(ls, sb + r);
#pragma unroll
  for (int d = 0; d < 3; d++)
#pragma unroll
    for (int r = 0; r < 4; r++) {
      const int n = q0 + w * 16 + g * 4 + r;
      if (n < CN)
        o[(bbase + n) * CC + h * CD + d * 16 + li] = f2b(oa[d][r] / lr[r]);
    }
}

// ---------------------------------------------------------------------------
// K5: global_attn = mean over heads of softmax(q0 . k)[1:]. grid = B*H blocks.
// ---------------------------------------------------------------------------
__global__ __launch_bounds__(256) void k_gattn(const short* __restrict__ qkv,
                                               float* __restrict__ ga) {
  const int b = blockIdx.x >> 3, h = blockIdx.x & 7;
  __shared__ float red[4];
  const int t = threadIdx.x;
  const size_t bbase = (size_t)b * CN;
  const short* q0 = qkv + bbase * C3 + h * CD;
  float qv[CD];
#pragma unroll
  for (int i = 0; i < CD; i++) qv[i] = b2f(q0[i]);
  float lg[4], ev[4];
  float lmax = -1e30f;
#pragma unroll
  for (int j = 0; j < 4; j++) {
    const int m = t + j * 256;
    if (m < CN) {
      const short* kr = qkv + (bbase + m) * C3 + CC + h * CD;
      float acc = 0.f;
#pragma unroll
      for (int i = 0; i < CD; i++) acc += qv[i] * b2f(kr[i]);
      lg[j] = acc * 0.14433756729740643f;
      lmax = fmaxf(lmax, lg[j]);
    } else lg[j] = -1e30f;
  }
  for (int msk = 1; msk < 64; msk <<= 1) lmax = fmaxf(lmax, __shfl_xor(lmax, msk));
  if ((t & 63) == 0) red[t >> 6] = lmax;
  __syncthreads();
  lmax = fmaxf(fmaxf(red[0], red[1]), fmaxf(red[2], red[3]));
  __syncthreads();
  float es = 0.f;
#pragma unroll
  for (int j = 0; j < 4; j++) {
    ev[j] = (t + j * 256 < CN) ? __expf(lg[j] - lmax) : 0.f;
    es += ev[j];
  }
  for (int msk = 1; msk < 64; msk <<= 1) es += __shfl_xor(es, msk);
  if ((t & 63) == 0) red[t >> 6] = es;
  __syncthreads();
  es = red[0] + red[1] + red[2] + red[3];
  const float inv = 0.125f / es;
#pragma unroll
  for (int j = 0; j < 4; j++) {
    const int m = t + j * 256;
    if (m >= 1 && m < CN) atomicAdd(&ga[b * HW + m - 1], ev[j] * inv);
  }
}

// ---------------------------------------------------------------------------
// K6: output: x_out via LDS-tiled transpose (both sides coalesced) + cls_out
// ---------------------------------------------------------------------------
__global__ __launch_bounds__(256) void k_out(const float* __restrict__ xc,
                                             float* __restrict__ outp) {
  const int b = blockIdx.y, tile = blockIdx.x, t = threadIdx.x;
  if (tile == 78) {
    for (int i = t; i < CC; i += 256)
      outp[b * CC + i] = xc[((size_t)b * CN) * CC + i];
    return;
  }
  __shared__ float T[64][65];
  const int ct = tile / 13, ht = tile % 13;
  const int c0 = ct * 64, hw0 = ht * 64;
  const int ci = t & 63, hb = t >> 6;
  for (int j = 0; j < 16; j++) {
    const int hwl = hb + j * 4;
    if (hw0 + hwl < HW)
      T[ci][hwl] = xc[((size_t)b * CN + 1 + hw0 + hwl) * CC + c0 + ci];
  }
  __syncthreads();
  const int hi = t & 63, cb2 = t >> 6;
  float* xo = outp + CB * CC;
  for (int j = 0; j < 16; j++) {
    const int cl = cb2 + j * 4;
    if (hw0 + hi < HW)
      xo[((size_t)(b * CC + c0 + cl)) * HW + hw0 + hi] = T[cl][hi];
  }
}

// ---------------------------------------------------------------------------
extern "C" void kernel_launch(void* const* d_in, const int* in_sizes, int n_in,
                              void* d_out, int out_size, void* d_ws, size_t ws_size,
                              hipStream_t stream) {
  const float* cls    = (const float*)d_in[0];
  const float* x      = (const float*)d_in[1];
  const float* conv_w = (const float*)d_in[2];
  const float* conv_b = (const float*)d_in[3];
  const float* ln1_g  = (const float*)d_in[4];
  const float* ln1_b  = (const float*)d_in[5];
  const float* qkv_w  = (const float*)d_in[6];
  const float* proj_w = (const float*)d_in[7];
  const float* proj_b = (const float*)d_in[8];
  const float* ln2_g  = (const float*)d_in[9];
  const float* ln2_b  = (const float*)d_in[10];
  const float* fc1_w  = (const float*)d_in[11];
  const float* fc1_b  = (const float*)d_in[12];
  const float* fc2_w  = (const float*)d_in[13];
  const float* fc2_b  = (const float*)d_in[14];

  float* outf = (float*)d_out;
  float* ga = outf + (size_t)CB * CC + (size_t)CB * CC * HW;
  // vt scratch lives in the (not-yet-written) x_out region of d_out:
  // floats [6144, 6144+2,457,600) — disjoint from cls (0..6144) and ga (4,823,040..)
  short* vtb = (short*)(outf + CB * CC);

  char* ws = (char*)d_ws;
  float* xc   = (float*)ws;
  short* y    = (short*)(ws + 19292160ULL);
  short* qkvb = (short*)(ws + 28938240ULL);
  short* o    = (short*)(ws + 57876480ULL);
  short* m1   = (short*)(ws + 28938240ULL);
  short* wbuf = (short*)(ws + 67522560ULL);
  short* qkv_wb = wbuf;
  short* proj_wb = wbuf + 442368;
  short* fc1_wb  = wbuf + 589824;
  short* fc2_wb  = wbuf + 1179648;

  const int thr = 256;
  k_misc<<<49, thr, 0, stream>>>(cls, xc, ga);
  k_wconv<<<1728, thr, 0, stream>>>(qkv_w, proj_w, fc1_w, fc2_w, wbuf);
  k_conv_t<<<dim3(13, 6, CB), thr, 0, stream>>>(x, conv_w, conv_b, xc);
  k_ln<<<CM / 4, thr, 0, stream>>>(xc, ln1_g, ln1_b, y, CM);
  k_gemm<128, 0, 0, 0, 1><<<dim3(99, C3 / 128), thr, 0, stream>>>(
      y, qkv_wb, nullptr, nullptr, qkvb, CM, C3, CC);
  k_vt<<<dim3(13, CB * 8), thr, 0, stream>>>(qkvb, vtb);
  k_attn<<<1664, thr, 0, stream>>>(qkvb, vtb, o);
  k_gattn<<<CB * 8, thr, 0, stream>>>(qkvb, ga);
  k_gemm<64, 0, 1, 1, 0><<<dim3(197, CC / 128), thr, 0, stream>>>(
      o, proj_wb, proj_b, xc, xc, CM, CC, CC);
  k_ln<<<CM / 4, thr, 0, stream>>>(xc, ln2_g, ln2_b, y, CM);
  k_gemm<128, 1, 0, 1, 1><<<dim3(99, CF / 128), thr, 0, stream>>>(
      y, fc1_wb, fc1_b, nullptr, m1, CM, CF, CC);
  k_gemm<64, 0, 1, 1, 0><<<dim3(197, CC / 128), thr, 0, stream>>>(
      m1, fc2_wb, fc2_b, xc, xc, CM, CC, CF);
  k_out<<<dim3(79, CB), thr, 0, stream>>>(xc, outf);
}

// Round 12
// 325.915 us; speedup vs baseline: 2.3322x; 1.0770x over previous
//
#include <hip/hip_runtime.h>
#include <hip/hip_bf16.h>

#define DI __device__ __forceinline__

typedef __attribute__((ext_vector_type(4))) float f32x4;
typedef __attribute__((ext_vector_type(8))) short bf16x8;
typedef __attribute__((ext_vector_type(4))) short bf16x4;

static constexpr int CB = 16;        // batch
static constexpr int CC = 384;       // channels
static constexpr int CH = 28, CW = 28;
static constexpr int CD = 48;        // head dim
static constexpr int CN = 785;       // 1 + 28*28
static constexpr int CM = CB * CN;   // 12560 rows
static constexpr int C3 = 3 * CC;    // 1152
static constexpr int CF = 4 * CC;    // 1536
static constexpr int HW = CH * CW;   // 784
static constexpr int NP = 832;       // padded seq for vt

DI short f2b(float f) {
  __hip_bfloat16 h = __float2bfloat16(f);
  return *reinterpret_cast<short*>(&h);
}
DI float b2f(short s) {
  union { unsigned u; float f; } x;
  x.u = ((unsigned)(unsigned short)s) << 16;
  return x.f;
}

DI void gload16(const short* g, short* l) {
  __builtin_amdgcn_global_load_lds((const __attribute__((address_space(1))) void*)g,
                                   (__attribute__((address_space(3))) void*)l, 16, 0, 0);
}

// ---------------------------------------------------------------------------
// K0: zero global_attn, write cls row of xc
// ---------------------------------------------------------------------------
__global__ void k_misc(const float* __restrict__ cls, float* __restrict__ xc,
                       float* __restrict__ ga) {
  const int gid = blockIdx.x * 256 + threadIdx.x;
  if (gid < CB * HW) ga[gid] = 0.f;
  if (gid < CB * CC) {
    const int b = gid / CC, c = gid % CC;
    xc[((size_t)b * CN) * CC + c] = cls[gid];
  }
}

// ---------------------------------------------------------------------------
// K0b: convert the four weight matrices fp32 -> bf16 (contiguous in wbuf)
// ---------------------------------------------------------------------------
__global__ void k_wconv(const float* __restrict__ s0, const float* __restrict__ s1,
                        const float* __restrict__ s2, const float* __restrict__ s3,
                        short* __restrict__ dst) {
  const int gid = (blockIdx.x * 256 + threadIdx.x) * 4;
  if (gid >= 1769472) return;
  const float* s; int off;
  if (gid < 442368)       { s = s0; off = gid; }
  else if (gid < 589824)  { s = s1; off = gid - 442368; }
  else if (gid < 1179648) { s = s2; off = gid - 589824; }
  else                    { s = s3; off = gid - 1179648; }
  f32x4 v = *(const f32x4*)(s + off);
  bf16x4 o;
#pragma unroll
  for (int i = 0; i < 4; i++) o[i] = f2b(v[i]);
  *(bf16x4*)(dst + gid) = o;
}

// ---------------------------------------------------------------------------
// K1: depthwise conv3x3 + residual, coalesced along hw, LDS-transposed write.
//     ILP: branchless taps (clamped addr + x0 mask), loads batched per pair.
// ---------------------------------------------------------------------------
__global__ __launch_bounds__(256) void k_conv_t(const float* __restrict__ x,
                                                const float* __restrict__ cw,
                                                const float* __restrict__ cb,
                                                float* __restrict__ xc) {
  __shared__ float T[64][65];
  __shared__ float Wc[64 * 9];
  __shared__ float Cbs[64];
  const int b = blockIdx.z;
  const int cc = blockIdx.y * 64;
  const int hw0 = blockIdx.x * 64;
  const int t = threadIdx.x;
  const int hwi = t & 63, ci0 = t >> 6;
  const int hw = hw0 + hwi;
  const int yy = hw / CW, xx = hw % CW;
  const int ci2 = t & 63, hb2 = t >> 6;

  for (int i = t; i < 64 * 9; i += 256) Wc[i] = cw[cc * 9 + i];
  if (t < 64) Cbs[t] = cb[cc + t];
  __syncthreads();
  if (hw < HW) {
    const int ctr = yy * CW + xx;
    int off9[9]; float mk9[9];
#pragma unroll
    for (int ky = 0; ky < 3; ky++)
#pragma unroll
      for (int kx = 0; kx < 3; kx++) {
        const int iy = yy + ky - 1, ix = xx + kx - 1;
        const bool v = (iy >= 0 && iy < CH && ix >= 0 && ix < CW);
        off9[ky * 3 + kx] = v ? iy * CW + ix : ctr;
        mk9[ky * 3 + kx] = v ? 1.f : 0.f;
      }
#pragma unroll
    for (int j = 0; j < 16; j += 2) {
      const int cl0 = ci0 * 16 + j;
      const float* xp0 = x + ((size_t)(b * CC + cc + cl0)) * HW;
      const float* xp1 = xp0 + HW;
      float t0[9], t1[9];
#pragma unroll
      for (int q = 0; q < 9; q++) { t0[q] = xp0[off9[q]]; t1[q] = xp1[off9[q]]; }
      const float c0 = xp0[ctr], c1 = xp1[ctr];
      float a0 = Cbs[cl0], a1 = Cbs[cl0 + 1];
#pragma unroll
      for (int q = 0; q < 9; q++) {
        a0 += Wc[cl0 * 9 + q] * (t0[q] * mk9[q]);
        a1 += Wc[(cl0 + 1) * 9 + q] * (t1[q] * mk9[q]);
      }
      T[cl0][hwi] = c0 + a0;
      T[cl0 + 1][hwi] = c1 + a1;
    }
  }
  __syncthreads();
#pragma unroll
  for (int j = 0; j < 16; j++) {
    const int hwl = hb2 + j * 4;
    if (hw0 + hwl < HW)
      xc[((size_t)b * CN + 1 + hw0 + hwl) * CC + cc + ci2] = T[ci2][hwl];
  }
}

// ---------------------------------------------------------------------------
// K2: LayerNorm over last dim (384), fp32 in -> bf16 out. 1 wave per row.
// ---------------------------------------------------------------------------
__global__ __launch_bounds__(256) void k_ln(const float* __restrict__ xin,
                                            const float* __restrict__ g,
                                            const float* __restrict__ bta,
                                            short* __restrict__ y, int Mtot) {
  const int row = blockIdx.x * 4 + (threadIdx.x >> 6);
  const int l = threadIdx.x & 63;
  if (row >= Mtot) return;
  const float* xr = xin + (size_t)row * CC;
  float v[6], s = 0.f, ss = 0.f;
#pragma unroll
  for (int i = 0; i < 6; i++) {
    v[i] = xr[l + i * 64];
    s += v[i];
    ss += v[i] * v[i];
  }
#pragma unroll
  for (int m = 1; m < 64; m <<= 1) { s += __shfl_xor(s, m); ss += __shfl_xor(ss, m); }
  const float mu = s * (1.f / CC);
  const float var = ss * (1.f / CC) - mu * mu;
  const float r = rsqrtf(var + 1e-5f);
#pragma unroll
  for (int i = 0; i < 6; i++) {
    const int c = l + i * 64;
    y[(size_t)row * CC + c] = f2b((v[i] - mu) * r * g[c] + bta[c]);
  }
}

// ---------------------------------------------------------------------------
// K3: GEMM  C[M,N] = A[M,K] @ W[N,K]^T (+bias)(+gelu)(+resid)
//     2-buffer pipelined (round-8 best variant) + XCD-chunked N-fastest
//     grid swizzle: flat grid, XCD x owns a contiguous wgid chunk, within it
//     bn varies fastest -> A-panel and full W stay L2-resident per XCD.
//     (round-9 PMC: FETCH 62MB vs 11MB of inputs = A refetched ~6x; this
//     was the real GEMM bound, not pipeline depth.)
// ---------------------------------------------------------------------------
template <int BM, int DOGELU, int DORES, int DOBIAS, int OUTBF>
__global__ __launch_bounds__(256) void k_gemm(const short* __restrict__ A,
                                              const short* __restrict__ W,
                                              const float* __restrict__ bias,
                                              const float* __restrict__ resid,
                                              void* __restrict__ out_,
                                              int M, int N, int K, int NN) {
  constexpr int MI = BM / 32;       // acc row-frags per wave (4 or 2)
  constexpr int ACALLS = BM / 64;   // A staging calls per thread (2 or 1)
  constexpr int ASZ = BM * 32, BSZ = 128 * 32;
  __shared__ short As[2 * ASZ];
  __shared__ short Bs[2 * BSZ];

  // bijective XCD-chunk swizzle (m204): f = j*8 + x -> wgid = base(x) + j
  const int nwg = gridDim.x;
  const int q = nwg >> 3, r = nwg & 7;
  const int x = blockIdx.x & 7, j = blockIdx.x >> 3;
  const int base = (x < r) ? x * (q + 1) : r * (q + 1) + (x - r) * q;
  const int wgid = base + j;
  const int bm = (wgid / NN) * BM, bn = (wgid % NN) * 128;

  const int t = threadIdx.x, w = t >> 6, l = t & 63, g = l >> 4, li = l & 15;
  const int wm = (w >> 1) * (BM / 2), wn = (w & 1) * 64;

  const int srow = l >> 2;          // row within 16-row staging group
  const int scol = (l & 3) * 8;     // col offset (16B granules)
  const short* aSrc[ACALLS]; int aOff[ACALLS];
#pragma unroll
  for (int jj = 0; jj < ACALLS; jj++) {
    int arow = bm + w * (BM / 4) + jj * 16 + srow; if (arow > M - 1) arow = M - 1;
    aSrc[jj] = A + (size_t)arow * K + scol;
    aOff[jj] = (w * (BM / 4) + jj * 16) * 32;
  }
  const short* bSrc[2]; int bOff[2];
#pragma unroll
  for (int jj = 0; jj < 2; jj++) {
    const int brow = bn + w * 32 + jj * 16 + srow;
    bSrc[jj] = W + (size_t)brow * K + scol;
    bOff[jj] = (w * 32 + jj * 16) * 32;
  }

  auto stage = [&](int buf, int kt) {
    const int ko = kt * 32;
#pragma unroll
    for (int jj = 0; jj < ACALLS; jj++)
      gload16(aSrc[jj] + ko, &As[buf * ASZ] + aOff[jj]);
#pragma unroll
    for (int jj = 0; jj < 2; jj++)
      gload16(bSrc[jj] + ko, &Bs[buf * BSZ] + bOff[jj]);
  };

  f32x4 acc[MI][4] = {};
  const int nkt = K / 32;
  stage(0, 0);
  __syncthreads();                    // prologue: tile 0 landed
  int cur = 0;
  for (int kt = 0; kt < nkt; kt++) {
    if (kt + 1 < nkt) stage(cur ^ 1, kt + 1);   // prefetch under compute
    const short* Ab = &As[cur * ASZ];
    const short* Bb = &Bs[cur * BSZ];
    bf16x8 af[MI], bf[4];
#pragma unroll
    for (int mi = 0; mi < MI; mi++)
      af[mi] = *(const bf16x8*)&Ab[(wm + mi * 16 + li) * 32 + g * 8];
#pragma unroll
    for (int ni = 0; ni < 4; ni++)
      bf[ni] = *(const bf16x8*)&Bb[(wn + ni * 16 + li) * 32 + g * 8];
#pragma unroll
    for (int mi = 0; mi < MI; mi++)
#pragma unroll
      for (int ni = 0; ni < 4; ni++)
        acc[mi][ni] = __builtin_amdgcn_mfma_f32_16x16x32_bf16(af[mi], bf[ni], acc[mi][ni], 0, 0, 0);
    __syncthreads();                  // drains prefetch vmcnt + readers done
    cur ^= 1;
  }

#pragma unroll
  for (int mi = 0; mi < MI; mi++)
#pragma unroll
    for (int ni = 0; ni < 4; ni++) {
      const int col = bn + wn + ni * 16 + li;
      float bv = 0.f;
      if constexpr (DOBIAS) bv = bias[col];
#pragma unroll
      for (int rr = 0; rr < 4; rr++) {
        const int row = bm + wm + mi * 16 + g * 4 + rr;
        if (row < M) {
          float v = acc[mi][ni][rr] + bv;
          if constexpr (DOGELU) v = 0.5f * v * (1.f + erff(v * 0.7071067811865475f));
          if constexpr (DORES) v += resid[(size_t)row * N + col];
          if constexpr (OUTBF)
            ((short*)out_)[(size_t)row * N + col] = f2b(v);
          else
            ((float*)out_)[(size_t)row * N + col] = v;
        }
      }
    }
}

// ---------------------------------------------------------------------------
// K3b: pre-transpose V: qkvb[b][n][768 + h*48 + d] -> vt[bh][d][NP=832]
//      (zero-pad n>=785).  grid (13 n-tiles, 128 bh).
// ---------------------------------------------------------------------------
__global__ __launch_bounds__(256) void k_vt(const short* __restrict__ qkv,
                                            short* __restrict__ vt) {
  __shared__ short Tl[48 * 71];   // [d][n] stride 71 (142B) to spread banks
  const int n0 = blockIdx.x * 64;
  const int bh = blockIdx.y;
  const int b = bh >> 3, h = bh & 7;
  const int t = threadIdx.x;
  const size_t bbase = (size_t)b * CN;
#pragma unroll
  for (int it = 0; it < 2; it++) {
    const int gi = t + it * 256;
    if (gi < 384) {
      const int nrel = gi / 6, dg = gi % 6;
      const int n = n0 + nrel;
      bf16x8 val = {};
      if (n < CN)
        val = *(const bf16x8*)(qkv + (bbase + n) * C3 + 2 * CC + h * CD + dg * 8);
#pragma unroll
      for (int i = 0; i < 8; i++) Tl[(dg * 8 + i) * 71 + nrel] = val[i];
    }
  }
  __syncthreads();
#pragma unroll
  for (int it = 0; it < 2; it++) {
    const int gj = t + it * 256;
    if (gj < 384) {
      const int d = gj >> 3, ng = gj & 7;
      bf16x8 v;
#pragma unroll
      for (int i = 0; i < 8; i++) v[i] = Tl[d * 71 + ng * 8 + i];
      *(bf16x8*)(vt + ((size_t)bh * CD + d) * NP + n0 + ng * 8) = v;
    }
  }
}

// ---------------------------------------------------------------------------
// K4: flash attention v2 — swapped QK^T (mfma(K,Q)): each lane owns one q-row,
//     softmax = 2 shfl_xor, P stays in registers. V from pre-transposed vt via
//     [d][kv] swizzled LDS; K/V global loads issued one tile ahead. 12KB LDS.
// ---------------------------------------------------------------------------
__global__ __launch_bounds__(256) void k_attn(const short* __restrict__ qkv,
                                              const short* __restrict__ vt,
                                              short* __restrict__ o) {
  __shared__ short Ks[64 * 48];   // [kv][d] rows 96B, XOR-swizzled
  __shared__ short Vs[48 * 64];   // [d][kv] rows 128B, XOR-swizzled
  const int f = blockIdx.x;
  const int xslot = f & 7, grp = f >> 3;
  const int bh = xslot + 8 * (grp & 15);
  const int qt = grp >> 4;                 // 0..12
  const int b = bh >> 3, h = bh & 7;
  const int q0 = qt * 64;
  const int t = threadIdx.x, w = t >> 6, l = t & 63, g = l >> 4, li = l & 15;
  const size_t bbase = (size_t)b * CN;

  // Q fragment (B-operand): col=li -> q = q0+w*16+li ; k=g*8+i -> d
  const int qrow = q0 + w * 16 + li;
  const int qr = qrow > CN - 1 ? CN - 1 : qrow;
  const short* qb = qkv + (bbase + qr) * C3 + h * CD;
  bf16x8 qf0 = *(const bf16x8*)(qb + g * 8);
  bf16x8 qf1 = {};
  if (g < 2) qf1 = *(const bf16x8*)(qb + 32 + g * 8);

  float mr = -1e30f, ls = 0.f;
  f32x4 oa[3] = {};
  const float scale = 0.14433756729740643f; // 1/sqrt(48)

  const int krow0 = t / 6, kcg0 = t % 6;
  const int krow1 = (t + 256) / 6, kcg1 = (t + 256) % 6;   // valid when t<128
  const int vd0 = t >> 3, vkvg0 = t & 7;
  const int vd1 = (t + 256) >> 3, vkvg1 = (t + 256) & 7;   // valid when t<128
  const short* kbase = qkv + bbase * C3 + CC + h * CD;
  const short* vbase = vt + (size_t)bh * CD * NP;

  bf16x8 kr0 = {}, kr1 = {}, vr0 = {}, vr1 = {};
  kr0 = *(const bf16x8*)(kbase + (size_t)min(krow0, CN - 1) * C3 + kcg0 * 8);
  vr0 = *(const bf16x8*)(vbase + vd0 * NP + vkvg0 * 8);
  if (t < 128) {
    kr1 = *(const bf16x8*)(kbase + (size_t)min(krow1, CN - 1) * C3 + kcg1 * 8);
    vr1 = *(const bf16x8*)(vbase + vd1 * NP + vkvg1 * 8);
  }

  for (int kt = 0; kt < 13; kt++) {
    const int kv0 = kt * 64;
    __syncthreads();   // previous compute done; LDS free
    *(bf16x8*)((char*)Ks + ((krow0 * 96 + kcg0 * 16) ^ ((krow0 & 7) << 4))) = kr0;
    *(bf16x8*)((char*)Vs + ((vd0 * 128 + vkvg0 * 16) ^ ((vd0 & 7) << 4))) = vr0;
    if (t < 128) {
      *(bf16x8*)((char*)Ks + ((krow1 * 96 + kcg1 * 16) ^ ((krow1 & 7) << 4))) = kr1;
      *(bf16x8*)((char*)Vs + ((vd1 * 128 + vkvg1 * 16) ^ ((vd1 & 7) << 4))) = vr1;
    }
    __syncthreads();   // LDS ready
    if (kt < 12) {     // issue next-tile loads early; latency hides under MFMA
      const int kn = kv0 + 64;
      kr0 = *(const bf16x8*)(kbase + (size_t)min(kn + krow0, CN - 1) * C3 + kcg0 * 8);
      vr0 = *(const bf16x8*)(vbase + vd0 * NP + kn + vkvg0 * 8);
      if (t < 128) {
        kr1 = *(const bf16x8*)(kbase + (size_t)min(kn + krow1, CN - 1) * C3 + kcg1 * 8);
        vr1 = *(const bf16x8*)(vbase + vd1 * NP + kn + vkvg1 * 8);
      }
    }

    // ---- S = K Q^T : lane (g,li): s[ni][r] = S[kv=kv0+ni*16+g*4+r][q=qrow]
    f32x4 s[4];
    __builtin_amdgcn_s_setprio(1);
#pragma unroll
    for (int ni = 0; ni < 4; ni++) {
      const int krw = ni * 16 + li;
      const int sw = (krw & 7) << 4;
      bf16x8 kf0 = *(const bf16x8*)((char*)Ks + ((krw * 96 + g * 16) ^ sw));
      bf16x8 kf1 = {};
      if (g < 2) kf1 = *(const bf16x8*)((char*)Ks + ((krw * 96 + 64 + g * 16) ^ sw));
      f32x4 acc = {};
      acc = __builtin_amdgcn_mfma_f32_16x16x32_bf16(kf0, qf0, acc, 0, 0, 0);
      acc = __builtin_amdgcn_mfma_f32_16x16x32_bf16(kf1, qf1, acc, 0, 0, 0);
      s[ni] = acc;
    }
    __builtin_amdgcn_s_setprio(0);

    // ---- online softmax: one q per lane; reduce across g via 2 shfl_xor
    float mt = -1e30f;
#pragma unroll
    for (int ni = 0; ni < 4; ni++)
#pragma unroll
      for (int rr = 0; rr < 4; rr++) {
        const int kva = kv0 + ni * 16 + g * 4 + rr;
        const float v = (kva < CN) ? s[ni][rr] * scale : -1e30f;
        s[ni][rr] = v;
        mt = fmaxf(mt, v);
      }
    mt = fmaxf(mt, __shfl_xor(mt, 16));
    mt = fmaxf(mt, __shfl_xor(mt, 32));
    const float mn = fmaxf(mr, mt);
    const float al = __expf(mr - mn);
    mr = mn;
    float ps = 0.f;
#pragma unroll
    for (int ni = 0; ni < 4; ni++)
#pragma unroll
      for (int rr = 0; rr < 4; rr++) {
        const float p = __expf(s[ni][rr] - mn);
        s[ni][rr] = p;
        ps += p;
      }
    ps += __shfl_xor(ps, 16);
    ps += __shfl_xor(ps, 32);
    ls = ls * al + ps;

    // rescale O: need al at q = g*4+r -> shfl from lane (same group, li=g*4+r)
    const int sb = (l & 48) + ((l & 48) >> 2);
    float ar[4];
#pragma unroll
    for (int rr = 0; rr < 4; rr++) ar[rr] = __shfl(al, sb + rr);
#pragma unroll
    for (int d = 0; d < 3; d++)
#pragma unroll
      for (int rr = 0; rr < 4; rr++) oa[d][rr] *= ar[rr];

    // ---- pack P in-register per sigma: k=g*8+i -> kv = ks*32 + (i<4 ? g*4+i : 16+g*4+i-4)
    bf16x8 pa[2];
#pragma unroll
    for (int ks = 0; ks < 2; ks++)
#pragma unroll
      for (int i = 0; i < 8; i++)
        pa[ks][i] = f2b(i < 4 ? s[2 * ks][i] : s[2 * ks + 1][i - 4]);

    // ---- O += P V : V B-frag via two ds_read_b64 per chunk (same sigma)
    __builtin_amdgcn_s_setprio(1);
#pragma unroll
    for (int d = 0; d < 3; d++) {
      const int drow = d * 16 + li;
      const int sw = (drow & 7) << 4;
#pragma unroll
      for (int ks = 0; ks < 2; ks++) {
        bf16x4 lo = *(const bf16x4*)((char*)Vs + ((drow * 128 + ks * 64 + g * 8) ^ sw));
        bf16x4 hi = *(const bf16x4*)((char*)Vs + ((drow * 128 + ks * 64 + 32 + g * 8) ^ sw));
        bf16x8 vb;
#pragma unroll
        for (int i = 0; i < 4; i++) { vb[i] = lo[i]; vb[4 + i] = hi[i]; }
        oa[d] = __builtin_amdgcn_mfma_f32_16x16x32_bf16(pa[ks], vb, oa[d], 0, 0, 0);
      }
    }
    __builtin_amdgcn_s_setprio(0);
  }

  // epilogue: O[q=g*4+r][d=dblk*16+li]; ls lives at lane li=q -> shfl
  const int sb = (l & 48) + ((l & 48) >> 2);
  float lr[4];
#pragma unroll
  for (int rr = 0; rr < 4; rr++) lr[rr] = __shfl(ls, sb + rr);
#pragma unroll
  for (int d = 0; d < 3; d++)
#pragma unroll
    for (int rr = 0; rr < 4; rr++) {
      const int n = q0 + w * 16 + g * 4 + rr;
      if (n < CN)
        o[(bbase + n) * CC + h * CD + d * 16 + li] = f2b(oa[d][rr] / lr[rr]);
    }
}

// ---------------------------------------------------------------------------
// K5: global_attn = mean over heads of softmax(q0 . k)[1:]. grid = B*H blocks.
// ---------------------------------------------------------------------------
__global__ __launch_bounds__(256) void k_gattn(const short* __restrict__ qkv,
                                               float* __restrict__ ga) {
  const int b = blockIdx.x >> 3, h = blockIdx.x & 7;
  __shared__ float red[4];
  const int t = threadIdx.x;
  const size_t bbase = (size_t)b * CN;
  const short* q0 = qkv + bbase * C3 + h * CD;
  float qv[CD];
#pragma unroll
  for (int i = 0; i < CD; i++) qv[i] = b2f(q0[i]);
  float lg[4], ev[4];
  float lmax = -1e30f;
#pragma unroll
  for (int j = 0; j < 4; j++) {
    const int m = t + j * 256;
    if (m < CN) {
      const short* kr = qkv + (bbase + m) * C3 + CC + h * CD;
      float acc = 0.f;
#pragma unroll
      for (int i = 0; i < CD; i++) acc += qv[i] * b2f(kr[i]);
      lg[j] = acc * 0.14433756729740643f;
      lmax = fmaxf(lmax, lg[j]);
    } else lg[j] = -1e30f;
  }
  for (int msk = 1; msk < 64; msk <<= 1) lmax = fmaxf(lmax, __shfl_xor(lmax, msk));
  if ((t & 63) == 0) red[t >> 6] = lmax;
  __syncthreads();
  lmax = fmaxf(fmaxf(red[0], red[1]), fmaxf(red[2], red[3]));
  __syncthreads();
  float es = 0.f;
#pragma unroll
  for (int j = 0; j < 4; j++) {
    ev[j] = (t + j * 256 < CN) ? __expf(lg[j] - lmax) : 0.f;
    es += ev[j];
  }
  for (int msk = 1; msk < 64; msk <<= 1) es += __shfl_xor(es, msk);
  if ((t & 63) == 0) red[t >> 6] = es;
  __syncthreads();
  es = red[0] + red[1] + red[2] + red[3];
  const float inv = 0.125f / es;
#pragma unroll
  for (int j = 0; j < 4; j++) {
    const int m = t + j * 256;
    if (m >= 1 && m < CN) atomicAdd(&ga[b * HW + m - 1], ev[j] * inv);
  }
}

// ---------------------------------------------------------------------------
// K6: output: x_out via LDS-tiled transpose (both sides coalesced) + cls_out
// ---------------------------------------------------------------------------
__global__ __launch_bounds__(256) void k_out(const float* __restrict__ xc,
                                             float* __restrict__ outp) {
  const int b = blockIdx.y, tile = blockIdx.x, t = threadIdx.x;
  if (tile == 78) {
    for (int i = t; i < CC; i += 256)
      outp[b * CC + i] = xc[((size_t)b * CN) * CC + i];
    return;
  }
  __shared__ float T[64][65];
  const int ct = tile / 13, ht = tile % 13;
  const int c0 = ct * 64, hw0 = ht * 64;
  const int ci = t & 63, hb = t >> 6;
  for (int j = 0; j < 16; j++) {
    const int hwl = hb + j * 4;
    if (hw0 + hwl < HW)
      T[ci][hwl] = xc[((size_t)b * CN + 1 + hw0 + hwl) * CC + c0 + ci];
  }
  __syncthreads();
  const int hi = t & 63, cb2 = t >> 6;
  float* xo = outp + CB * CC;
  for (int j = 0; j < 16; j++) {
    const int cl = cb2 + j * 4;
    if (hw0 + hi < HW)
      xo[((size_t)(b * CC + c0 + cl)) * HW + hw0 + hi] = T[cl][hi];
  }
}

// ---------------------------------------------------------------------------
extern "C" void kernel_launch(void* const* d_in, const int* in_sizes, int n_in,
                              void* d_out, int out_size, void* d_ws, size_t ws_size,
                              hipStream_t stream) {
  const float* cls    = (const float*)d_in[0];
  const float* x      = (const float*)d_in[1];
  const float* conv_w = (const float*)d_in[2];
  const float* conv_b = (const float*)d_in[3];
  const float* ln1_g  = (const float*)d_in[4];
  const float* ln1_b  = (const float*)d_in[5];
  const float* qkv_w  = (const float*)d_in[6];
  const float* proj_w = (const float*)d_in[7];
  const float* proj_b = (const float*)d_in[8];
  const float* ln2_g  = (const float*)d_in[9];
  const float* ln2_b  = (const float*)d_in[10];
  const float* fc1_w  = (const float*)d_in[11];
  const float* fc1_b  = (const float*)d_in[12];
  const float* fc2_w  = (const float*)d_in[13];
  const float* fc2_b  = (const float*)d_in[14];

  float* outf = (float*)d_out;
  float* ga = outf + (size_t)CB * CC + (size_t)CB * CC * HW;
  // vt scratch lives in the (not-yet-written) x_out region of d_out
  short* vtb = (short*)(outf + CB * CC);

  char* ws = (char*)d_ws;
  float* xc   = (float*)ws;
  short* y    = (short*)(ws + 19292160ULL);
  short* qkvb = (short*)(ws + 28938240ULL);
  short* o    = (short*)(ws + 57876480ULL);
  short* m1   = (short*)(ws + 28938240ULL);
  short* wbuf = (short*)(ws + 67522560ULL);
  short* qkv_wb = wbuf;
  short* proj_wb = wbuf + 442368;
  short* fc1_wb  = wbuf + 589824;
  short* fc2_wb  = wbuf + 1179648;

  const int thr = 256;
  k_misc<<<49, thr, 0, stream>>>(cls, xc, ga);
  k_wconv<<<1728, thr, 0, stream>>>(qkv_w, proj_w, fc1_w, fc2_w, wbuf);
  k_conv_t<<<dim3(13, 6, CB), thr, 0, stream>>>(x, conv_w, conv_b, xc);
  k_ln<<<CM / 4, thr, 0, stream>>>(xc, ln1_g, ln1_b, y, CM);
  k_gemm<128, 0, 0, 0, 1><<<99 * 9, thr, 0, stream>>>(
      y, qkv_wb, nullptr, nullptr, qkvb, CM, C3, CC, 9);
  k_vt<<<dim3(13, CB * 8), thr, 0, stream>>>(qkvb, vtb);
  k_attn<<<1664, thr, 0, stream>>>(qkvb, vtb, o);
  k_gattn<<<CB * 8, thr, 0, stream>>>(qkvb, ga);
  k_gemm<64, 0, 1, 1, 0><<<197 * 3, thr, 0, stream>>>(
      o, proj_wb, proj_b, xc, xc, CM, CC, CC, 3);
  k_ln<<<CM / 4, thr, 0, stream>>>(xc, ln2_g, ln2_b, y, CM);
  k_gemm<128, 1, 0, 1, 1><<<99 * 12, thr, 0, stream>>>(
      y, fc1_wb, fc1_b, nullptr, m1, CM, CF, CC, 12);
  k_gemm<64, 0, 1, 1, 0><<<197 * 3, thr, 0, stream>>>(
      m1, fc2_wb, fc2_b, xc, xc, CM, CC, CF, 3);
  k_out<<<dim3(79, CB), thr, 0, stream>>>(xc, outf);
}